// Round 7
// baseline (856.082 us; speedup 1.0000x reference)
//
#include <hip/hip_runtime.h>
#include <stdint.h>

#define NN 50000
#define EE 1250000
#define BB 500
#define BN_EPS 1e-5f
#define LOG2E 1.44269504f
#define LN2 0.69314718f

// multisplit into 3125 buckets of exactly 16 nodes (3125*16 == 50000)
#define NBKT 3125
#define NPBSH 4
#define NB1 256       // binning blocks
#define BPB 4883      // edges per binning block (256*4883 >= EE)
#define SCCH 13       // bscanB elems/thread (256*13 >= NBKT+1)

// x-histogram for BN2 moments
#define HBLK 128
#define HEPB ((EE + HBLK - 1) / HBLK)   // 9766 edges per hist block

#define NTB 8192      // table intervals; 8193 knots
#define XLO (-12.0f)
#define XHI (12.0f)
#define XSC ((float)NTB / (XHI - XLO))
#define DXT ((XHI - XLO) / (float)NTB)
#define TPMAX 8191.999f

// fixed-point accumulator scale (log2-domain softplus terms, all >= 0)
#define FXS 262144.f          // 2^18
#define FXI (LN2 / 262144.f)  // back-convert + ln2

using u16 = unsigned short;
using u32 = unsigned int;

__device__ __forceinline__ u16 f2bf(float f) {
    u32 u = __float_as_uint(f);
    return (u16)((u + 0x7fffu + ((u >> 16) & 1u)) >> 16);
}
__device__ __forceinline__ u32 pk2(float a, float b) { return (u32)f2bf(a) | ((u32)f2bf(b) << 16); }
// softplus via native v_exp_f32 / v_log_f32
__device__ __forceinline__ float sp(float z) {
    float t = __builtin_amdgcn_exp2f(-fabsf(z) * LOG2E);
    float l = __builtin_amdgcn_logf(1.f + t) * LN2;
    return fmaxf(z, 0.f) + l;
}
// guaranteed v_readlane (VALU) — __shfl w/ literal lowers to ds_bpermute (LDS pipe)
__device__ __forceinline__ float rl(float v, int l) {
    return __uint_as_float(__builtin_amdgcn_readlane(__float_as_uint(v), l));
}

// ---------------- workspace layout (~57 MB) ----------------
constexpr size_t OFF_ESD  = 0;                                    // int4 [E] {src, et|ld<<7, i, f_bits}
constexpr size_t OFF_HA   = ((size_t)EE * 16 + 255) & ~(size_t)255;
constexpr size_t OFF_HB   = OFF_HA + (size_t)NN * 64 * 4;
// hpart (12.6 MB) aliases hB: live hist3..ytmom (before k_aggc0)
constexpr size_t OFF_ZB   = OFF_HB + (size_t)NN * 64 * 4;         // [N,32]
// sort scratch aliases zb (dead before k_o2): T[NB1][NBKT] (3.2MB), tot, bbase
constexpr size_t OFF_TMAT = OFF_ZB;
constexpr size_t OFF_TOT  = OFF_TMAT + (size_t)NB1 * NBKT * 4;
constexpr size_t OFF_BBASE= OFF_TOT + (size_t)NBKT * 4;
constexpr size_t OFF_YTAB = OFF_ZB + (size_t)NN * 32 * 4;         // f32 [NTB+1][64]
constexpr size_t OFF_PTAB = OFF_YTAB + (size_t)(NTB + 1) * 64 * 4;// u32 [NTB][64] bf16 (a, b-a) pairs
constexpr size_t OFF_W2T  = OFF_PTAB + (size_t)NTB * 64 * 4;      // w_d2 transposed f32 [64][64]
constexpr size_t OFF_B2F  = OFF_W2T + 4096 * 4;
constexpr size_t OFF_W1T  = OFF_B2F + 256;                        // f32 [128][64] (w_o1^T)
constexpr size_t OFF_W2O  = OFF_W1T + 8192 * 4;                   // f32 [64][32]  (w_o2^T)
constexpr size_t OFF_W3T  = OFF_W2O + 2048 * 4;                   // f32 [32][128] (w_o3^T)
constexpr size_t OFF_BPTR = OFF_W3T + 4096 * 4;                   // int [B+1]
// zero region (one memset): hg | xstat | sty | 5 stat slots
constexpr size_t OFF_HG   = (OFF_BPTR + (BB + 1) * 4 + 255) & ~(size_t)255;
constexpr size_t OFF_XSTAT= OFF_HG + (size_t)BB * 64 * 4;         // 2 doubles
constexpr size_t OFF_STY  = OFF_XSTAT + 16;                       // 128 doubles
constexpr size_t OFF_FST  = OFF_STY + 128 * 8;
constexpr size_t ZERO_END = OFF_FST + 5 * 128 * 8;
constexpr size_t ZERO_BYTES = ZERO_END - OFF_HG;

// ---------------- merged prep: w2prep | otprep | xstats | bptr | bincnt ----------------
// blocks [0,16) w2T/b2f  [16,72) w1T/w2T2/w3T  [72,584) xstats  [584,780) bptr  [780,1036) bincnt
__global__ void __launch_bounds__(256) k_prep0(
        const float* __restrict__ w2, const float* __restrict__ b2,
        const float* __restrict__ w1, const float* __restrict__ wo2, const float* __restrict__ w3,
        const float* __restrict__ x, const int* __restrict__ batch, const int* __restrict__ dstv,
        float* __restrict__ w2T, float* __restrict__ b2f,
        float* __restrict__ w1T, float* __restrict__ w2T2, float* __restrict__ w3T,
        double* __restrict__ xstat, int* __restrict__ bptr, int* __restrict__ T) {
    int bx = blockIdx.x, t = threadIdx.x;
    if (bx < 16) {
        int idx = bx * 256 + t;                          // 4096
        int hin = idx >> 6, ho = idx & 63;
        w2T[idx] = w2[ho * 64 + hin];
        if (idx < 64) b2f[idx] = b2[idx];
    } else if (bx < 72) {
        int idx = (bx - 16) * 256 + t;                   // 14336
        if (idx < 8192) {
            int j = idx >> 6, ho = idx & 63;
            w1T[idx] = w1[ho * 128 + j];
        } else if (idx < 8192 + 2048) {
            int q = idx - 8192;
            int j = q >> 5, ho = q & 31;
            w2T2[q] = wo2[ho * 64 + j];
        } else if (idx < 8192 + 2048 + 4096) {
            int q = idx - 8192 - 2048;
            int j = q >> 7, jo = q & 127;
            w3T[q] = w3[jo * 32 + j];
        }
    } else if (bx < 584) {
        __shared__ float ls[256], lq[256];
        float s = 0, q = 0;
        for (int i = (bx - 72) * 256 + t; i < EE; i += 512 * 256) {
            float v = x[i]; s += v; q += v * v;
        }
        ls[t] = s; lq[t] = q; __syncthreads();
        for (int off = 128; off > 0; off >>= 1) {
            if (t < off) { ls[t] += ls[t + off]; lq[t] += lq[t + off]; }
            __syncthreads();
        }
        if (t == 0) { atomicAdd(&xstat[0], (double)ls[0]); atomicAdd(&xstat[1], (double)lq[0]); }
    } else if (bx < 780) {
        int n = (bx - 584) * 256 + t;
        if (n >= NN) return;
        int b = batch[n];
        int pb = (n == 0) ? -1 : batch[n - 1];
        for (int k = pb + 1; k <= b; k++) bptr[k] = n;
        if (n == NN - 1) { for (int k = b + 1; k <= BB; k++) bptr[k] = NN; }
    } else {
        // bincnt: per-block LDS histogram over 3125 buckets
        __shared__ int hh[NBKT];
        for (int i = t; i < NBKT; i += 256) hh[i] = 0;
        __syncthreads();
        int bb = bx - 780;
        int e0 = bb * BPB;
        int e1 = e0 + BPB; if (e1 > EE) e1 = EE;
        for (int e = e0 + t; e < e1; e += 256)
            atomicAdd(&hh[dstv[e] >> NPBSH], 1);
        __syncthreads();
        for (int i = t; i < NBKT; i += 256)
            T[(size_t)bb * NBKT + i] = hh[i];
    }
}

// per-bucket exclusive scan over blocks (in-place), bucket totals out
__global__ void k_bscanA(int* __restrict__ T, int* __restrict__ tot) {
    __shared__ int ls[256];
    int b = blockIdx.x, t = threadIdx.x;
    int v = T[(size_t)t * NBKT + b];
    ls[t] = v; __syncthreads();
    for (int off = 1; off < 256; off <<= 1) {
        int a = ls[t]; int add = (t >= off) ? ls[t - off] : 0; __syncthreads();
        ls[t] = a + add; __syncthreads();
    }
    T[(size_t)t * NBKT + b] = ls[t] - v;
    if (t == 255) tot[b] = ls[255];
}

// exclusive scan of 3125 bucket totals -> bucket base offsets
__global__ void k_bscanB(const int* __restrict__ tot, int* __restrict__ bbase) {
    __shared__ int ls[256];
    int t = threadIdx.x;
    int v[SCCH]; int s = 0;
    #pragma unroll
    for (int i = 0; i < SCCH; i++) {
        int idx = t * SCCH + i;
        v[i] = s;
        s += (idx < NBKT) ? tot[idx] : 0;
    }
    ls[t] = s; __syncthreads();
    for (int off = 1; off < 256; off <<= 1) {
        int a = ls[t]; int add = (t >= off) ? ls[t - off] : 0; __syncthreads();
        ls[t] = a + add; __syncthreads();
    }
    int base = ls[t] - s;
    #pragma unroll
    for (int i = 0; i < SCCH; i++) {
        int idx = t * SCCH + i;
        if (idx < NBKT) bbase[idx] = base + v[i];
    }
    if (t == 255) bbase[NBKT] = EE;
}

// chunked scatter into bucket regions via LDS cursors (bucket-grouped, unsorted within)
__global__ void __launch_bounds__(1024) k_binscat(
        const float* __restrict__ x, const int* __restrict__ src,
        const int* __restrict__ dstv, const int* __restrict__ etv,
        const int* __restrict__ T, const int* __restrict__ bbase,
        int4* __restrict__ esd) {
    __shared__ int cur[NBKT];
    for (int i = threadIdx.x; i < NBKT; i += 1024)
        cur[i] = bbase[i] + T[(size_t)blockIdx.x * NBKT + i];
    __syncthreads();
    int e0 = blockIdx.x * BPB;
    int e1 = e0 + BPB; if (e1 > EE) e1 = EE;
    for (int e = e0 + (int)threadIdx.x; e < e1; e += 1024) {
        int d = dstv[e];
        int p = atomicAdd(&cur[d >> NPBSH], 1);
        float tp = fminf(fmaxf((x[e] - XLO) * XSC, 0.f), TPMAX);
        int i = (int)tp; float f = tp - (float)i;
        // local dst (4 bits) rides in spare bits of et (et < 128)
        int4 v; v.x = src[e]; v.y = etv[e] | ((d & 15) << 7); v.z = i; v.w = __float_as_int(f);
        esd[p] = v;
    }
}

// ---------------- x histogram for BN2 moments (feature-independent) ----------------
__global__ void __launch_bounds__(1024) k_hist3(const float* __restrict__ x, float* __restrict__ hpart) {
    __shared__ float cnt[NTB / 2], sf[NTB / 2], sf2[NTB / 2];
    int e0 = blockIdx.x * HEPB;
    int e1 = e0 + HEPB; if (e1 > EE) e1 = EE;
    float* outp = hpart + (size_t)blockIdx.x * 3 * NTB;
    for (int half = 0; half < 2; half++) {
        for (int i = threadIdx.x; i < NTB / 2; i += 1024) { cnt[i] = 0.f; sf[i] = 0.f; sf2[i] = 0.f; }
        __syncthreads();
        int lo = half * (NTB / 2);
        for (int e = e0 + (int)threadIdx.x; e < e1; e += 1024) {
            float tp = fminf(fmaxf((x[e] - XLO) * XSC, 0.f), TPMAX);
            int i = (int)tp;
            int li = i - lo;
            if ((unsigned)li < (unsigned)(NTB / 2)) {
                float f = tp - (float)i;
                atomicAdd(&cnt[li], 1.f);
                atomicAdd(&sf[li], f);
                atomicAdd(&sf2[li], f * f);
            }
        }
        __syncthreads();
        for (int i = threadIdx.x; i < NTB / 2; i += 1024) {
            outp[lo + i] = cnt[i];
            outp[NTB + lo + i] = sf[i];
            outp[2 * NTB + lo + i] = sf2[i];
        }
        __syncthreads();
    }
}

// ---------------- fused table build + BN2 moments ----------------
// block g computes knots [g*64, g*64+64] (65, LDS-staged), writes ytab, then reduces
// the hist partials for its 64 bins and does the moment math from LDS knots.
__global__ void __launch_bounds__(256) k_ytmom(
        const double* __restrict__ xstat, const float* __restrict__ w_d1,
        const float* __restrict__ g_d1, const float* __restrict__ be_d1,
        const float* __restrict__ w2T, const float* __restrict__ b2f,
        const float* __restrict__ hpart, float* __restrict__ ytab, double* __restrict__ sty) {
    __shared__ float kn[65][64];
    __shared__ float hs[192];
    int t = threadIdx.x;
    int lane = t & 63, w = t >> 6;
    int g = blockIdx.x;                                  // 0..127
    double inv = 1.0 / (double)EE;
    double mx = xstat[0] * inv;
    double vx = xstat[1] * inv - mx * mx; if (vx < 0) vx = 0;
    float wd = w_d1[lane];
    float Aw = wd * rsqrtf((float)vx * wd * wd + BN_EPS) * g_d1[lane];
    float Cw = be_d1[lane];
    for (int kk = w; kk < 65; kk += 4) {
        int idx = (g << 6) + kk;
        float xi = XLO + (float)idx * DXT;
        float tt = xi - (float)mx;
        float d1L = sp(fmaf(Aw, tt, Cw));
        float y = b2f[lane];
        #pragma unroll
        for (int hin = 0; hin < 64; hin++)
            y = fmaf(rl(d1L, hin), w2T[hin * 64 + lane], y);
        kn[kk][lane] = y;
        if (kk < 64 || g == 127) ytab[(idx << 6) | lane] = y;
    }
    if (t < 192) {                                       // hsum: c|f1|f2 for this block's 64 bins
        int slot = t >> 6, ii = t & 63;
        float s = 0.f;
        size_t off = (size_t)slot * NTB + (g << 6) + ii;
        for (int b = 0; b < HBLK; b++)
            s += hpart[(size_t)b * 3 * NTB + off];
        hs[t] = s;
    }
    __syncthreads();
    if (t >= 64) return;                                 // one wave: moment math
    double S = 0.0, Q = 0.0;
    float aprev = kn[0][lane];
    for (int ii = 0; ii < 64; ii++) {
        float c = hs[ii], f1 = hs[64 + ii], f2 = hs[128 + ii];
        float b = kn[ii + 1][lane];
        float a = aprev; aprev = b;
        float d = b - a;
        S += (double)(fmaf(c, a, d * f1));
        Q += (double)(fmaf(c * a, a, fmaf(2.f * a * d, f1, d * d * f2)));
    }
    atomicAdd(&sty[lane], S);
    atomicAdd(&sty[64 + lane], Q);
}

// pack bn2-affined table as bf16 (a, b-a) pairs, pre-scaled by LOG2E
__global__ void k_ypack(const float* __restrict__ ytab, const double* __restrict__ sty,
                        const float* __restrict__ g2, const float* __restrict__ be2,
                        u32* __restrict__ ptab) {
    int tid = blockIdx.x * 256 + threadIdx.x;            // NTB*64
    int f = tid & 63;
    double inv = 1.0 / (double)EE;
    double m = sty[f] * inv;
    double var = sty[64 + f] * inv - m * m; if (var < 0) var = 0;
    float rstd = rsqrtf((float)var + BN_EPS);
    float sc0 = rstd * g2[f];
    float sc = sc0 * LOG2E;
    float sh = (be2[f] - (float)m * sc0) * LOG2E;
    float a = fmaf(ytab[tid], sc, sh);
    float b = fmaf(ytab[tid + 64], sc, sh);
    ptab[tid] = pk2(a, b - a);
}

// ---------------- bucket-per-block aggregation, native int LDS atomics ----------------
// per-edge log2-domain softplus term accumulated in fixed point (x2^18, always >= 0).
// ds_add_u32 is native single-op (unlike f32 LDS atomic = CAS loop, the R4 failure).
__device__ __forceinline__ void edge_acc(int4 e, int lane, const float* __restrict__ h,
        const u32* __restrict__ ptab, const float* __restrict__ emb, int acc[16][64]) {
    float hv = h[(e.x << 6) | lane];
    u32 pr = ptab[(e.z << 6) | lane];
    float f_ = __int_as_float(e.w);
    float a_ = __uint_as_float(pr << 16);
    float d_ = __uint_as_float(pr & 0xffff0000u);
    float av = fmaf(f_, d_, a_) * emb[((e.y & 127) << 6) | lane];
    float z = fmaf(hv, LOG2E, av);
    float tt = __builtin_amdgcn_exp2f(-fabsf(z));
    float val = fmaxf(z, 0.f) + __builtin_amdgcn_logf(1.f + tt);
    atomicAdd(&acc[(e.y >> 7) & 15][lane], (int)(val * FXS));
}
__device__ __forceinline__ void edge_acc0(int4 e, int lane, const int* __restrict__ nt,
        const float* __restrict__ nemb, const u32* __restrict__ ptab,
        const float* __restrict__ emb, int acc[16][64]) {
    float hv = nemb[(nt[e.x] << 6) | lane];
    u32 pr = ptab[(e.z << 6) | lane];
    float f_ = __int_as_float(e.w);
    float a_ = __uint_as_float(pr << 16);
    float d_ = __uint_as_float(pr & 0xffff0000u);
    float av = fmaf(f_, d_, a_) * emb[((e.y & 127) << 6) | lane];
    float z = fmaf(hv, LOG2E, av);
    float tt = __builtin_amdgcn_exp2f(-fabsf(z));
    float val = fmaxf(z, 0.f) + __builtin_amdgcn_logf(1.f + tt);
    atomicAdd(&acc[(e.y >> 7) & 15][lane], (int)(val * FXS));
}

__global__ void __launch_bounds__(256) k_aggc(
        const float* __restrict__ h, const int4* __restrict__ esd, const int* __restrict__ bbase,
        const u32* __restrict__ ptab, const float* __restrict__ emb, float* __restrict__ hpre) {
    __shared__ int acc[16][64];                          // 4 KB; bank-conflict-free (2 lanes/bank)
    int lane = threadIdx.x & 63, w = threadIdx.x >> 6;
    int b = blockIdx.x;
    for (int i = threadIdx.x; i < 1024; i += 256) ((int*)acc)[i] = 0;
    int base = bbase[b], end = bbase[b + 1];
    int cnt = end - base;
    int p  = base + ((cnt * w) >> 2);
    int pe = base + ((cnt * (w + 1)) >> 2);
    __syncthreads();
    for (; p + 4 <= pe; p += 4) {
        int4 e0 = esd[p], e1 = esd[p + 1], e2 = esd[p + 2], e3 = esd[p + 3];
        edge_acc(e0, lane, h, ptab, emb, acc);
        edge_acc(e1, lane, h, ptab, emb, acc);
        edge_acc(e2, lane, h, ptab, emb, acc);
        edge_acc(e3, lane, h, ptab, emb, acc);
    }
    for (; p < pe; ++p) edge_acc(esd[p], lane, h, ptab, emb, acc);
    __syncthreads();
    int n0b = blockIdx.x << NPBSH;                       // 3125*16 == 50000: no guard needed
    #pragma unroll
    for (int k = 0; k < 4; k++) {
        int nd = (w << 2) + k;
        int o = ((n0b + nd) << 6) | lane;
        hpre[o] = fmaf((float)acc[nd][lane], FXI, h[o]);
    }
}

// gconv1 variant: h comes from node_emb[node_type] (L1-resident)
__global__ void __launch_bounds__(256) k_aggc0(
        const int* __restrict__ nt, const float* __restrict__ nemb, const int4* __restrict__ esd,
        const int* __restrict__ bbase, const u32* __restrict__ ptab,
        const float* __restrict__ emb, float* __restrict__ hpre) {
    __shared__ int acc[16][64];
    int lane = threadIdx.x & 63, w = threadIdx.x >> 6;
    int b = blockIdx.x;
    for (int i = threadIdx.x; i < 1024; i += 256) ((int*)acc)[i] = 0;
    int base = bbase[b], end = bbase[b + 1];
    int cnt = end - base;
    int p  = base + ((cnt * w) >> 2);
    int pe = base + ((cnt * (w + 1)) >> 2);
    __syncthreads();
    for (; p + 4 <= pe; p += 4) {
        int4 e0 = esd[p], e1 = esd[p + 1], e2 = esd[p + 2], e3 = esd[p + 3];
        edge_acc0(e0, lane, nt, nemb, ptab, emb, acc);
        edge_acc0(e1, lane, nt, nemb, ptab, emb, acc);
        edge_acc0(e2, lane, nt, nemb, ptab, emb, acc);
        edge_acc0(e3, lane, nt, nemb, ptab, emb, acc);
    }
    for (; p < pe; ++p) edge_acc0(esd[p], lane, nt, nemb, ptab, emb, acc);
    __syncthreads();
    int n0b = blockIdx.x << NPBSH;
    #pragma unroll
    for (int k = 0; k < 4; k++) {
        int nd = (w << 2) + k;
        int n = n0b + nd;
        hpre[(n << 6) | lane] = fmaf((float)acc[nd][lane], FXI, nemb[(nt[n] << 6) | lane]);
    }
}

// per-feature mean/var partials over [rows, C] (C = 1<<logC), f64 atomics
__global__ void k_fstats(const float* __restrict__ v, int rows, int logC, double* __restrict__ stat) {
    int C = 1 << logC;
    int f = threadIdx.x & (C - 1);
    int r0 = threadIdx.x >> logC;
    int rpb = 256 >> logC;
    float s = 0, q = 0;
    for (int r = blockIdx.x * rpb + r0; r < rows; r += gridDim.x * rpb) {
        float val = v[(size_t)r * C + f];
        s += val; q += val * val;
    }
    __shared__ float lsS[256], lsQ[256];
    lsS[threadIdx.x] = s; lsQ[threadIdx.x] = q; __syncthreads();
    if (threadIdx.x < C) {
        float ss = 0, qq = 0;
        for (int j = 0; j < rpb; j++) { ss += lsS[j * C + threadIdx.x]; qq += lsQ[j * C + threadIdx.x]; }
        atomicAdd(&stat[threadIdx.x], (double)ss);
        atomicAdd(&stat[C + threadIdx.x], (double)qq);
    }
}

// BN apply: per-block hoist of f32 scale/shift
__global__ void __launch_bounds__(256) k_bn(
        const float* __restrict__ in, float* __restrict__ out,
        const double* __restrict__ stat, const float* __restrict__ g,
        const float* __restrict__ be, int rows, int logC, int act) {
    int C = 1 << logC;
    __shared__ float scl[64], shl[64];
    int t = threadIdx.x;
    if (t < C) {
        double inv = 1.0 / (double)rows;
        float m = (float)(stat[t] * inv);
        float var = (float)(stat[C + t] * inv) - m * m; if (var < 0.f) var = 0.f;
        float rstd = rsqrtf(var + BN_EPS);
        float sc = rstd * g[t];
        scl[t] = sc; shl[t] = be[t] - m * sc;
    }
    __syncthreads();
    size_t total = (size_t)rows << logC;
    size_t i = (size_t)blockIdx.x * 256 + t;
    if (i >= total) return;
    int f = (int)(i & (C - 1));
    float val = fmaf(in[i], scl[f], shl[f]);
    out[i] = act ? sp(val) : val;
}

// global pooling: block-per-batch segment sum over sorted batch (no atomics)
__global__ void __launch_bounds__(256) k_hg2(
        const float* __restrict__ h, const int* __restrict__ bptr, float* __restrict__ hg) {
    int b = blockIdx.x;                                  // BB
    int lane = threadIdx.x & 63, w = threadIdx.x >> 6;
    int n0 = bptr[b], n1 = bptr[b + 1];
    float acc = 0.f;
    for (int n = n0 + w; n < n1; n += 4)
        acc += h[(n << 6) | lane];
    __shared__ float ls[256];
    ls[threadIdx.x] = acc; __syncthreads();
    if (threadIdx.x < 64)
        hg[(b << 6) | lane] = ls[lane] + ls[64 + lane] + ls[128 + lane] + ls[192 + lane];
}

// head GEMV 1: 4 nodes/wave, lane = output feature
#define O1NPW 4
__global__ void __launch_bounds__(256) k_o1(
        const float* __restrict__ h, const float* __restrict__ hg, const int* __restrict__ batch,
        const float* __restrict__ w1T, const float* __restrict__ b1, float* __restrict__ z1) {
    int lane = threadIdx.x & 63;
    int wv = (blockIdx.x * 256 + (int)threadIdx.x) >> 6;
    int n0 = __builtin_amdgcn_readfirstlane(wv * O1NPW);
    if (n0 >= NN) return;
    float hl[O1NPW], gl[O1NPW], acc[O1NPW];
    float bl = b1[lane];
    #pragma unroll
    for (int k = 0; k < O1NPW; k++) {
        int n = n0 + k;
        hl[k] = h[(n << 6) | lane];
        gl[k] = hg[(batch[n] << 6) | lane];
        acc[k] = bl;
    }
    #pragma unroll
    for (int j = 0; j < 64; j++) {
        float w = w1T[(j << 6) | lane];
        #pragma unroll
        for (int k = 0; k < O1NPW; k++)
            acc[k] = fmaf(rl(hl[k], j), w, acc[k]);
    }
    #pragma unroll
    for (int j = 0; j < 64; j++) {
        float w = w1T[((64 + j) << 6) | lane];
        #pragma unroll
        for (int k = 0; k < O1NPW; k++)
            acc[k] = fmaf(rl(gl[k], j), w, acc[k]);
    }
    #pragma unroll
    for (int k = 0; k < O1NPW; k++)
        z1[((n0 + k) << 6) | lane] = acc[k];
}

// head GEMV 2: 8 nodes/wave
__global__ void __launch_bounds__(256) k_o2(
        const float* __restrict__ o1v, const float* __restrict__ w2T2,
        const float* __restrict__ b2, float* __restrict__ z2) {
    int lane = threadIdx.x & 63;
    int ho = lane & 31;
    int wv = (blockIdx.x * 256 + (int)threadIdx.x) >> 6;
    int n0 = __builtin_amdgcn_readfirstlane(wv * 8);
    if (n0 >= NN) return;
    float xr[8], acc[4];
    #pragma unroll
    for (int k = 0; k < 8; k++) {
        int n = n0 + k; if (n >= NN) n = NN - 1;
        xr[k] = o1v[(n << 6) | lane];
    }
    float bl = b2[ho];
    #pragma unroll
    for (int k = 0; k < 4; k++) acc[k] = bl;
    #pragma unroll
    for (int j = 0; j < 64; j++) {
        float w = w2T2[(j << 5) | ho];
        #pragma unroll
        for (int k = 0; k < 4; k++) {
            float slo = rl(xr[k], j);
            float shi = rl(xr[4 + k], j);
            float v = (lane < 32) ? slo : shi;
            acc[k] = fmaf(v, w, acc[k]);
        }
    }
    int nbase = n0 + ((lane >> 5) << 2);
    #pragma unroll
    for (int k = 0; k < 4; k++)
        if (nbase + k < NN) z2[((nbase + k) << 5) | ho] = acc[k];
}

// head GEMV 3: 4 nodes per wave per jo-half
__global__ void __launch_bounds__(256) k_o3(
        const float* __restrict__ o2v, const float* __restrict__ w3T,
        const float* __restrict__ b3, float* __restrict__ outp) {
    int lane = threadIdx.x & 63;
    int wv = (blockIdx.x * 256 + (int)threadIdx.x) >> 6;
    int n0 = __builtin_amdgcn_readfirstlane((wv >> 1) << 2);
    int jo = (((wv & 1) << 6) + lane);
    if (n0 >= NN) return;
    float zl[4], acc[4];
    float bl = b3[jo];
    #pragma unroll
    for (int k = 0; k < 4; k++) {
        zl[k] = o2v[((n0 + k) << 5) | (lane & 31)];
        acc[k] = bl;
    }
    #pragma unroll
    for (int j = 0; j < 32; j++) {
        float w = w3T[(j << 7) | jo];
        #pragma unroll
        for (int k = 0; k < 4; k++)
            acc[k] = fmaf(rl(zl[k], j), w, acc[k]);
    }
    #pragma unroll
    for (int k = 0; k < 4; k++) {
        int n = n0 + k;
        size_t dsti = (jo < 64) ? ((size_t)(n << 6) + jo)
                                : ((size_t)NN * 64 + (size_t)(n << 6) + (jo - 64));
        outp[dsti] = acc[k];                             // f32 output
    }
}

extern "C" void kernel_launch(void* const* d_in, const int* in_sizes, int n_in,
                              void* d_out, int out_size, void* d_ws, size_t ws_size,
                              hipStream_t stream) {
    const float* x        = (const float*)d_in[0];
    const int* node_type  = (const int*)d_in[1];
    const int* edge_type  = (const int*)d_in[2];
    const int* edge_index = (const int*)d_in[3];
    const int* batch      = (const int*)d_in[4];
    const float* node_emb = (const float*)d_in[5];
    const float* edge_emb = (const float*)d_in[6];
    const float* w_d1 = (const float*)d_in[7];  const float* b_d1 = (const float*)d_in[8];
    const float* g_d1 = (const float*)d_in[9];  const float* be_d1 = (const float*)d_in[10];
    const float* w_d2 = (const float*)d_in[11]; const float* b_d2 = (const float*)d_in[12];
    const float* g_d2 = (const float*)d_in[13]; const float* be_d2 = (const float*)d_in[14];
    const float* g_c1 = (const float*)d_in[15]; const float* be_c1 = (const float*)d_in[16];
    const float* g_c2 = (const float*)d_in[17]; const float* be_c2 = (const float*)d_in[18];
    const float* g_c3 = (const float*)d_in[19]; const float* be_c3 = (const float*)d_in[20];
    const float* w_o1 = (const float*)d_in[21]; const float* b_o1 = (const float*)d_in[22];
    const float* g_o1 = (const float*)d_in[23]; const float* be_o1 = (const float*)d_in[24];
    const float* w_o2 = (const float*)d_in[25]; const float* b_o2 = (const float*)d_in[26];
    const float* g_o2 = (const float*)d_in[27]; const float* be_o2 = (const float*)d_in[28];
    const float* w_o3 = (const float*)d_in[29]; const float* b_o3 = (const float*)d_in[30];
    (void)b_d1;  // cancels inside BN1 (mean subtraction removes per-feature shift)
    const int* src  = edge_index;
    const int* dstv = edge_index + EE;

    char* ws = (char*)d_ws;
    int4*  esd  = (int4*)(ws + OFF_ESD);
    float* hA   = (float*)(ws + OFF_HA);
    float* hB   = (float*)(ws + OFF_HB);
    float* zb   = (float*)(ws + OFF_ZB);
    float* hpart = (float*)(ws + OFF_HB);    // aliases hB (live hist3..ytmom)
    int*   T    = (int*)(ws + OFF_TMAT);     // aliases zb (dead after binscat)
    int*   tot  = (int*)(ws + OFF_TOT);
    int*   bbase= (int*)(ws + OFF_BBASE);    // survives through aggs (zb written only at o2)
    float* ytab = (float*)(ws + OFF_YTAB);
    u32*   ptab = (u32*)(ws + OFF_PTAB);
    float* w2T  = (float*)(ws + OFF_W2T);
    float* b2f  = (float*)(ws + OFF_B2F);
    float* w1T  = (float*)(ws + OFF_W1T);
    float* w2T2 = (float*)(ws + OFF_W2O);
    float* w3T  = (float*)(ws + OFF_W3T);
    int*   bptr = (int*)(ws + OFF_BPTR);
    float* hg     = (float*)(ws + OFF_HG);
    double* xstat = (double*)(ws + OFF_XSTAT);
    double* sty   = (double*)(ws + OFF_STY);
    double* fst   = (double*)(ws + OFF_FST);
    double* st0 = fst;          double* st1 = fst + 128;  double* st2 = fst + 256;
    double* st3 = fst + 384;    double* st4 = fst + 512;

    hipMemsetAsync(ws + OFF_HG, 0, ZERO_BYTES, stream);

    // merged prep: weights transpose | xstats | bptr | bincnt
    k_prep0<<<1036, 256, 0, stream>>>(w_d2, b_d2, w_o1, w_o2, w_o3, x, batch, dstv,
                                      w2T, b2f, w1T, w2T2, w3T, xstat, bptr, T);
    k_bscanA<<<NBKT, 256, 0, stream>>>(T, tot);
    k_bscanB<<<1, 256, 0, stream>>>(tot, bbase);
    k_binscat<<<NB1, 1024, 0, stream>>>(x, src, dstv, edge_type, T, bbase, esd);
    k_hist3<<<HBLK, 1024, 0, stream>>>(x, hpart);
    // fused knot table + BN2 moments; then pack
    k_ytmom<<<128, 256, 0, stream>>>(xstat, w_d1, g_d1, be_d1, w2T, b2f, hpart, ytab, sty);
    k_ypack<<<NTB * 64 / 256, 256, 0, stream>>>(ytab, sty, g_d2, be_d2, ptab);
    // gconv 1 (h from node_emb[node_type], L1-resident)
    k_aggc0<<<NBKT, 256, 0, stream>>>(node_type, node_emb, esd, bbase, ptab, edge_emb, hB);
    k_fstats<<<1024, 256, 0, stream>>>(hB, NN, 6, st0);
    k_bn<<<12500, 256, 0, stream>>>(hB, hB, st0, g_c1, be_c1, NN, 6, 1);
    // gconv 2
    k_aggc<<<NBKT, 256, 0, stream>>>(hB, esd, bbase, ptab, edge_emb, hA);
    k_fstats<<<1024, 256, 0, stream>>>(hA, NN, 6, st1);
    k_bn<<<12500, 256, 0, stream>>>(hA, hA, st1, g_c2, be_c2, NN, 6, 1);
    // gconv 3 (no activation)
    k_aggc<<<NBKT, 256, 0, stream>>>(hA, esd, bbase, ptab, edge_emb, hB);
    k_fstats<<<1024, 256, 0, stream>>>(hB, NN, 6, st2);
    k_bn<<<12500, 256, 0, stream>>>(hB, hB, st2, g_c3, be_c3, NN, 6, 0);
    // global pool + head
    k_hg2<<<BB, 256, 0, stream>>>(hB, bptr, hg);
    k_o1<<<3125, 256, 0, stream>>>(hB, hg, batch, w1T, b_o1, hA);
    k_fstats<<<1024, 256, 0, stream>>>(hA, NN, 6, st3);
    k_bn<<<12500, 256, 0, stream>>>(hA, hA, st3, g_o1, be_o1, NN, 6, 1);
    k_o2<<<1563, 256, 0, stream>>>(hA, w2T2, b_o2, zb);
    k_fstats<<<1024, 256, 0, stream>>>(zb, NN, 5, st4);
    k_bn<<<6250, 256, 0, stream>>>(zb, zb, st4, g_o2, be_o2, NN, 5, 1);
    k_o3<<<6250, 256, 0, stream>>>(zb, w3T, b_o3, (float*)d_out);
    (void)in_sizes; (void)n_in; (void)out_size; (void)ws_size;
}

// Round 8
// 671.395 us; speedup vs baseline: 1.2751x; 1.2751x over previous
//
#include <hip/hip_runtime.h>
#include <stdint.h>

#define NN 50000
#define EE 1250000
#define BB 500
#define BN_EPS 1e-5f
#define LOG2E 1.44269504f
#define LN2 0.69314718f

// two-level multisplit: 391 buckets of 128 nodes + per-bucket local sort
#define NBKT 391
#define NPBSH 7
#define NB1 256       // binning blocks
#define BPB 4883      // edges per binning block (256*4883 >= EE)

// x-histogram for BN2 moments
#define HBLK 128
#define HEPB ((EE + HBLK - 1) / HBLK)   // 9766 edges per hist block
#define FHSC 65536.f                     // fixed-point scale for f, f^2 partials
#define FHIN (1.f / 65536.f)

#define NTB 8192      // table intervals; 8193 knots
#define XLO (-12.0f)
#define XHI (12.0f)
#define XSC ((float)NTB / (XHI - XLO))
#define DXT ((XHI - XLO) / (float)NTB)
#define TPMAX 8191.999f

using u16 = unsigned short;
using u32 = unsigned int;

__device__ __forceinline__ u16 f2bf(float f) {
    u32 u = __float_as_uint(f);
    return (u16)((u + 0x7fffu + ((u >> 16) & 1u)) >> 16);
}
__device__ __forceinline__ u32 pk2(float a, float b) { return (u32)f2bf(a) | ((u32)f2bf(b) << 16); }
// softplus via native v_exp_f32 / v_log_f32
__device__ __forceinline__ float sp(float z) {
    float t = __builtin_amdgcn_exp2f(-fabsf(z) * LOG2E);
    float l = __builtin_amdgcn_logf(1.f + t) * LN2;
    return fmaxf(z, 0.f) + l;
}
// guaranteed v_readlane (VALU) — __shfl w/ literal lowers to ds_bpermute (LDS pipe)
__device__ __forceinline__ float rl(float v, int l) {
    return __uint_as_float(__builtin_amdgcn_readlane(__float_as_uint(v), l));
}

// ---------------- workspace layout (~57 MB) ----------------
constexpr size_t OFF_ESD  = 0;                                    // int4 [E] {src, et, i, f_bits}
constexpr size_t OFF_ROWP = OFF_ESD + (size_t)EE * 16;            // row_ptr [N+1]
constexpr size_t OFF_HA   = (OFF_ROWP + (size_t)(NN + 1) * 4 + 255) & ~(size_t)255;
constexpr size_t OFF_HB   = OFF_HA + (size_t)NN * 64 * 4;
// esd_tmp (20 MB) aliases hA..hB: live only before k_locsort
// hpart (12.6 MB, int) aliases hB: live hist3..ytmom (after locsort, before k_agg0)
constexpr size_t OFF_ZB   = OFF_HB + (size_t)NN * 64 * 4;         // [N,32]
// sort scratch aliases zb (dead before k_o2): T[NB1][NBKT], tot, bbase
constexpr size_t OFF_TMAT = OFF_ZB;
constexpr size_t OFF_TOT  = OFF_TMAT + (size_t)NB1 * NBKT * 4;
constexpr size_t OFF_BBASE= OFF_TOT + (size_t)NBKT * 4;
constexpr size_t OFF_YTAB = OFF_ZB + (size_t)NN * 32 * 4;         // f32 [NTB+1][64]
constexpr size_t OFF_PTAB = OFF_YTAB + (size_t)(NTB + 1) * 64 * 4;// u32 [NTB][64] bf16 (a, b-a)
constexpr size_t OFF_W2T  = OFF_PTAB + (size_t)NTB * 64 * 4;      // w_d2 transposed f32 [64][64]
constexpr size_t OFF_B2F  = OFF_W2T + 4096 * 4;
constexpr size_t OFF_W1T  = OFF_B2F + 256;                        // f32 [128][64] (w_o1^T)
constexpr size_t OFF_W2O  = OFF_W1T + 8192 * 4;                   // f32 [64][32]  (w_o2^T)
constexpr size_t OFF_W3T  = OFF_W2O + 2048 * 4;                   // f32 [32][128] (w_o3^T)
constexpr size_t OFF_BPTR = OFF_W3T + 4096 * 4;                   // int [B+1]
// zero region (one memset): hg | xstat | sty | 5 stat slots
constexpr size_t OFF_HG   = (OFF_BPTR + (BB + 1) * 4 + 255) & ~(size_t)255;
constexpr size_t OFF_XSTAT= OFF_HG + (size_t)BB * 64 * 4;         // 2 doubles
constexpr size_t OFF_STY  = OFF_XSTAT + 16;                       // 128 doubles
constexpr size_t OFF_FST  = OFF_STY + 128 * 8;
constexpr size_t ZERO_END = OFF_FST + 5 * 128 * 8;
constexpr size_t ZERO_BYTES = ZERO_END - OFF_HG;

// ---------------- merged prep: w2prep | otprep | xstats | bptr | bincnt ----------------
// blocks [0,16) w2T/b2f  [16,72) w1T/w2T2/w3T  [72,584) xstats  [584,780) bptr  [780,1036) bincnt
__global__ void __launch_bounds__(256) k_prep0(
        const float* __restrict__ w2, const float* __restrict__ b2,
        const float* __restrict__ w1, const float* __restrict__ wo2, const float* __restrict__ w3,
        const float* __restrict__ x, const int* __restrict__ batch, const int* __restrict__ dstv,
        float* __restrict__ w2T, float* __restrict__ b2f,
        float* __restrict__ w1T, float* __restrict__ w2T2, float* __restrict__ w3T,
        double* __restrict__ xstat, int* __restrict__ bptr, int* __restrict__ T) {
    int bx = blockIdx.x, t = threadIdx.x;
    if (bx < 16) {
        int idx = bx * 256 + t;                          // 4096
        int hin = idx >> 6, ho = idx & 63;
        w2T[idx] = w2[ho * 64 + hin];
        if (idx < 64) b2f[idx] = b2[idx];
    } else if (bx < 72) {
        int idx = (bx - 16) * 256 + t;                   // 14336
        if (idx < 8192) {
            int j = idx >> 6, ho = idx & 63;
            w1T[idx] = w1[ho * 128 + j];
        } else if (idx < 8192 + 2048) {
            int q = idx - 8192;
            int j = q >> 5, ho = q & 31;
            w2T2[q] = wo2[ho * 64 + j];
        } else if (idx < 8192 + 2048 + 4096) {
            int q = idx - 8192 - 2048;
            int j = q >> 7, jo = q & 127;
            w3T[q] = w3[jo * 32 + j];
        }
    } else if (bx < 584) {
        __shared__ float ls[256], lq[256];
        float s = 0, q = 0;
        for (int i = (bx - 72) * 256 + t; i < EE; i += 512 * 256) {
            float v = x[i]; s += v; q += v * v;
        }
        ls[t] = s; lq[t] = q; __syncthreads();
        for (int off = 128; off > 0; off >>= 1) {
            if (t < off) { ls[t] += ls[t + off]; lq[t] += lq[t + off]; }
            __syncthreads();
        }
        if (t == 0) { atomicAdd(&xstat[0], (double)ls[0]); atomicAdd(&xstat[1], (double)lq[0]); }
    } else if (bx < 780) {
        int n = (bx - 584) * 256 + t;
        if (n >= NN) return;
        int b = batch[n];
        int pb = (n == 0) ? -1 : batch[n - 1];
        for (int k = pb + 1; k <= b; k++) bptr[k] = n;
        if (n == NN - 1) { for (int k = b + 1; k <= BB; k++) bptr[k] = NN; }
    } else {
        // bincnt: per-block LDS histogram over 391 coarse buckets
        __shared__ int hh[NBKT];
        for (int i = t; i < NBKT; i += 256) hh[i] = 0;
        __syncthreads();
        int bb = bx - 780;
        int e0 = bb * BPB;
        int e1 = e0 + BPB; if (e1 > EE) e1 = EE;
        for (int e = e0 + t; e < e1; e += 256)
            atomicAdd(&hh[dstv[e] >> NPBSH], 1);
        __syncthreads();
        for (int i = t; i < NBKT; i += 256)
            T[(size_t)bb * NBKT + i] = hh[i];
    }
}

// per-bucket exclusive scan over blocks (in-place), bucket totals out
__global__ void k_bscanA(int* __restrict__ T, int* __restrict__ tot) {
    __shared__ int ls[256];
    int b = blockIdx.x, t = threadIdx.x;
    int v = T[(size_t)t * NBKT + b];
    ls[t] = v; __syncthreads();
    for (int off = 1; off < 256; off <<= 1) {
        int a = ls[t]; int add = (t >= off) ? ls[t - off] : 0; __syncthreads();
        ls[t] = a + add; __syncthreads();
    }
    T[(size_t)t * NBKT + b] = ls[t] - v;
    if (t == 255) tot[b] = ls[255];
}

// exclusive scan of bucket totals -> bucket base offsets
__global__ void k_bscanB(const int* __restrict__ tot, int* __restrict__ bbase, int* __restrict__ row_ptr) {
    __shared__ int ls[256];
    int t = threadIdx.x;
    int i0 = 2 * t, i1 = 2 * t + 1;
    int v0 = (i0 < NBKT) ? tot[i0] : 0;
    int v1 = (i1 < NBKT) ? tot[i1] : 0;
    int s = v0 + v1;
    ls[t] = s; __syncthreads();
    for (int off = 1; off < 256; off <<= 1) {
        int a = ls[t]; int add = (t >= off) ? ls[t - off] : 0; __syncthreads();
        ls[t] = a + add; __syncthreads();
    }
    int base = ls[t] - s;
    if (i0 <= NBKT) bbase[i0] = base;
    if (i1 <= NBKT) bbase[i1] = base + v0;
    if (t == 0) row_ptr[NN] = EE;
}

// chunked scatter into bucket regions via LDS cursors (per-block reserved chunks)
__global__ void __launch_bounds__(1024) k_binscat(
        const float* __restrict__ x, const int* __restrict__ src,
        const int* __restrict__ dstv, const int* __restrict__ etv,
        const int* __restrict__ T, const int* __restrict__ bbase,
        int4* __restrict__ esd_tmp) {
    __shared__ int cur[NBKT];
    for (int i = threadIdx.x; i < NBKT; i += 1024)
        cur[i] = bbase[i] + T[(size_t)blockIdx.x * NBKT + i];
    __syncthreads();
    int e0 = blockIdx.x * BPB;
    int e1 = e0 + BPB; if (e1 > EE) e1 = EE;
    for (int e = e0 + (int)threadIdx.x; e < e1; e += 1024) {
        int d = dstv[e];
        int p = atomicAdd(&cur[d >> NPBSH], 1);
        float tp = fminf(fmaxf((x[e] - XLO) * XSC, 0.f), TPMAX);
        int i = (int)tp; float f = tp - (float)i;
        // local dst (7 bits) rides in spare bits of et (et < 128)
        int4 v; v.x = src[e]; v.y = etv[e] | ((d & 127) << 7); v.z = i; v.w = __float_as_int(f);
        esd_tmp[p] = v;
    }
}

// per-bucket local counting sort (L2-resident region); also emits row_ptr
__global__ void __launch_bounds__(256) k_locsort(
        const int4* __restrict__ esd_tmp, const int* __restrict__ bbase,
        int* __restrict__ row_ptr, int4* __restrict__ esd) {
    __shared__ int hist[128];
    __shared__ int ls[128];
    __shared__ int cur[128];
    int b = blockIdx.x;
    int t = threadIdx.x;
    int base = bbase[b], end = bbase[b + 1];
    if (t < 128) hist[t] = 0;
    __syncthreads();
    for (int p = base + t; p < end; p += 256)
        atomicAdd(&hist[(esd_tmp[p].y >> 7) & 127], 1);
    __syncthreads();
    int v = 0;
    if (t < 128) { v = hist[t]; ls[t] = v; }
    __syncthreads();
    for (int off = 1; off < 128; off <<= 1) {
        int a = 0;
        if (t < 128) { a = ls[t]; if (t >= off) a += ls[t - off]; }
        __syncthreads();
        if (t < 128) ls[t] = a;
        __syncthreads();
    }
    if (t < 128) {
        int exc = ls[t] - v;
        cur[t] = base + exc;
        int n = (b << NPBSH) + t;
        if (n < NN) row_ptr[n] = base + exc;
    }
    __syncthreads();
    for (int p = base + t; p < end; p += 256) {
        int4 r = esd_tmp[p];
        int ld = (r.y >> 7) & 127;
        r.y &= 127;
        esd[atomicAdd(&cur[ld], 1)] = r;
    }
}

// ---------------- x histogram for BN2 moments (feature-independent) ----------------
// per-bin {cnt, sum f, sum f^2} in INT fixed-point (x2^16) — native ds_add_u32
// (f32 LDS atomicAdd lowers to a CAS retry loop: the R4/R7 failure mechanism)
__global__ void __launch_bounds__(1024) k_hist3(const float* __restrict__ x, int* __restrict__ hpart) {
    __shared__ int cnt[NTB / 2], sf[NTB / 2], sf2[NTB / 2];
    int e0 = blockIdx.x * HEPB;
    int e1 = e0 + HEPB; if (e1 > EE) e1 = EE;
    int* outp = hpart + (size_t)blockIdx.x * 3 * NTB;
    for (int half = 0; half < 2; half++) {
        for (int i = threadIdx.x; i < NTB / 2; i += 1024) { cnt[i] = 0; sf[i] = 0; sf2[i] = 0; }
        __syncthreads();
        int lo = half * (NTB / 2);
        for (int e = e0 + (int)threadIdx.x; e < e1; e += 1024) {
            float tp = fminf(fmaxf((x[e] - XLO) * XSC, 0.f), TPMAX);
            int i = (int)tp;
            int li = i - lo;
            if ((unsigned)li < (unsigned)(NTB / 2)) {
                float f = tp - (float)i;
                atomicAdd(&cnt[li], 1);
                atomicAdd(&sf[li], (int)fmaf(f, FHSC, 0.5f));
                atomicAdd(&sf2[li], (int)fmaf(f * f, FHSC, 0.5f));
            }
        }
        __syncthreads();
        for (int i = threadIdx.x; i < NTB / 2; i += 1024) {
            outp[lo + i] = cnt[i];
            outp[NTB + lo + i] = sf[i];
            outp[2 * NTB + lo + i] = sf2[i];
        }
        __syncthreads();
    }
}

// ---------------- fused table build + BN2 moments ----------------
// block g computes knots [g*64, g*64+64] (65, LDS-staged), writes ytab, then reduces
// the int hist partials for its 64 bins and does the moment math from LDS knots.
__global__ void __launch_bounds__(256) k_ytmom(
        const double* __restrict__ xstat, const float* __restrict__ w_d1,
        const float* __restrict__ g_d1, const float* __restrict__ be_d1,
        const float* __restrict__ w2T, const float* __restrict__ b2f,
        const int* __restrict__ hpart, float* __restrict__ ytab, double* __restrict__ sty) {
    __shared__ float kn[65][64];
    __shared__ float hs[192];
    int t = threadIdx.x;
    int lane = t & 63, w = t >> 6;
    int g = blockIdx.x;                                  // 0..127
    double inv = 1.0 / (double)EE;
    double mx = xstat[0] * inv;
    double vx = xstat[1] * inv - mx * mx; if (vx < 0) vx = 0;
    float wd = w_d1[lane];
    float Aw = wd * rsqrtf((float)vx * wd * wd + BN_EPS) * g_d1[lane];
    float Cw = be_d1[lane];
    for (int kk = w; kk < 65; kk += 4) {
        int idx = (g << 6) + kk;
        float xi = XLO + (float)idx * DXT;
        float tt = xi - (float)mx;
        float d1L = sp(fmaf(Aw, tt, Cw));
        float y = b2f[lane];
        #pragma unroll
        for (int hin = 0; hin < 64; hin++)
            y = fmaf(rl(d1L, hin), w2T[hin * 64 + lane], y);
        kn[kk][lane] = y;
        if (kk < 64 || g == 127) ytab[(idx << 6) | lane] = y;
    }
    if (t < 192) {                                       // hsum: c|f1|f2 for this block's 64 bins
        int slot = t >> 6, ii = t & 63;
        float s = 0.f;
        size_t off = (size_t)slot * NTB + (g << 6) + ii;
        for (int b = 0; b < HBLK; b++)
            s += (float)hpart[(size_t)b * 3 * NTB + off];
        hs[t] = (slot == 0) ? s : s * FHIN;
    }
    __syncthreads();
    if (t >= 64) return;                                 // one wave: moment math
    double S = 0.0, Q = 0.0;
    float aprev = kn[0][lane];
    for (int ii = 0; ii < 64; ii++) {
        float c = hs[ii], f1 = hs[64 + ii], f2 = hs[128 + ii];
        float b = kn[ii + 1][lane];
        float a = aprev; aprev = b;
        float d = b - a;
        S += (double)(fmaf(c, a, d * f1));
        Q += (double)(fmaf(c * a, a, fmaf(2.f * a * d, f1, d * d * f2)));
    }
    atomicAdd(&sty[lane], S);
    atomicAdd(&sty[64 + lane], Q);
}

// pack bn2-affined table as bf16 (a, b-a) pairs
__global__ void k_ypack(const float* __restrict__ ytab, const double* __restrict__ sty,
                        const float* __restrict__ g2, const float* __restrict__ be2,
                        u32* __restrict__ ptab) {
    int tid = blockIdx.x * 256 + threadIdx.x;            // NTB*64
    int f = tid & 63;
    double inv = 1.0 / (double)EE;
    double m = sty[f] * inv;
    double var = sty[64 + f] * inv - m * m; if (var < 0) var = 0;
    float rstd = rsqrtf((float)var + BN_EPS);
    float sc = rstd * g2[f];
    float sh = be2[f] - (float)m * sc;
    float a = fmaf(ytab[tid], sc, sh);
    float b = fmaf(ytab[tid + 64], sc, sh);
    ptab[tid] = pk2(a, b - a);
}

// per-edge term: precomputed (i,f), bf16 (a,d) unpack -> one fmaf lerp
__device__ __forceinline__ float edge_term(int4 ed, int lane, const u32* __restrict__ ptab,
                                           const float* __restrict__ emb) {
    u32 pr = ptab[(ed.z << 6) | lane];
    float f = __int_as_float(ed.w);
    float a = __uint_as_float(pr << 16);
    float d = __uint_as_float(pr & 0xffff0000u);
    float y = fmaf(f, d, a);
    return y * emb[(ed.y << 6) | lane];
}

// wave-per-node aggregation, lane = feature; generic h input; unroll-4
__global__ void __launch_bounds__(256) k_agg(
        const float* __restrict__ h, const int4* __restrict__ esd, const int* __restrict__ row_ptr,
        const u32* __restrict__ ptab, const float* __restrict__ emb, float* __restrict__ hpre) {
    int lane = threadIdx.x & 63;
    int n = __builtin_amdgcn_readfirstlane((int)(blockIdx.x * 4 + (threadIdx.x >> 6)));
    if (n >= NN) return;
    int p0 = row_ptr[n], p1 = row_ptr[n + 1];
    float acc = 0.f;
    int p = p0;
    for (; p + 4 <= p1; p += 4) {
        int4 e0 = esd[p], e1 = esd[p + 1], e2 = esd[p + 2], e3 = esd[p + 3];
        float h0 = h[(e0.x << 6) | lane];
        float h1 = h[(e1.x << 6) | lane];
        float h2 = h[(e2.x << 6) | lane];
        float h3 = h[(e3.x << 6) | lane];
        float a0 = edge_term(e0, lane, ptab, emb);
        float a1 = edge_term(e1, lane, ptab, emb);
        float a2 = edge_term(e2, lane, ptab, emb);
        float a3 = edge_term(e3, lane, ptab, emb);
        acc += sp(h0 + a0) + sp(h1 + a1) + sp(h2 + a2) + sp(h3 + a3);
    }
    for (; p < p1; ++p) {
        int4 e0 = esd[p];
        float h0 = h[(e0.x << 6) | lane];
        acc += sp(h0 + edge_term(e0, lane, ptab, emb));
    }
    int o = (n << 6) | lane;
    hpre[o] = acc + h[o];
}

// gconv1 variant: h comes from node_emb[node_type] (L1-resident)
__global__ void __launch_bounds__(256) k_agg0(
        const int* __restrict__ nt, const float* __restrict__ nemb, const int4* __restrict__ esd,
        const int* __restrict__ row_ptr, const u32* __restrict__ ptab,
        const float* __restrict__ emb, float* __restrict__ hpre) {
    int lane = threadIdx.x & 63;
    int n = __builtin_amdgcn_readfirstlane((int)(blockIdx.x * 4 + (threadIdx.x >> 6)));
    if (n >= NN) return;
    int p0 = row_ptr[n], p1 = row_ptr[n + 1];
    float acc = 0.f;
    int p = p0;
    for (; p + 4 <= p1; p += 4) {
        int4 e0 = esd[p], e1 = esd[p + 1], e2 = esd[p + 2], e3 = esd[p + 3];
        float h0 = nemb[(nt[e0.x] << 6) | lane];
        float h1 = nemb[(nt[e1.x] << 6) | lane];
        float h2 = nemb[(nt[e2.x] << 6) | lane];
        float h3 = nemb[(nt[e3.x] << 6) | lane];
        float a0 = edge_term(e0, lane, ptab, emb);
        float a1 = edge_term(e1, lane, ptab, emb);
        float a2 = edge_term(e2, lane, ptab, emb);
        float a3 = edge_term(e3, lane, ptab, emb);
        acc += sp(h0 + a0) + sp(h1 + a1) + sp(h2 + a2) + sp(h3 + a3);
    }
    for (; p < p1; ++p) {
        int4 e0 = esd[p];
        float h0 = nemb[(nt[e0.x] << 6) | lane];
        acc += sp(h0 + edge_term(e0, lane, ptab, emb));
    }
    hpre[(n << 6) | lane] = acc + nemb[(nt[n] << 6) | lane];
}

// per-feature mean/var partials over [rows, C] (C = 1<<logC), f64 atomics
__global__ void k_fstats(const float* __restrict__ v, int rows, int logC, double* __restrict__ stat) {
    int C = 1 << logC;
    int f = threadIdx.x & (C - 1);
    int r0 = threadIdx.x >> logC;
    int rpb = 256 >> logC;
    float s = 0, q = 0;
    for (int r = blockIdx.x * rpb + r0; r < rows; r += gridDim.x * rpb) {
        float val = v[(size_t)r * C + f];
        s += val; q += val * val;
    }
    __shared__ float lsS[256], lsQ[256];
    lsS[threadIdx.x] = s; lsQ[threadIdx.x] = q; __syncthreads();
    if (threadIdx.x < C) {
        float ss = 0, qq = 0;
        for (int j = 0; j < rpb; j++) { ss += lsS[j * C + threadIdx.x]; qq += lsQ[j * C + threadIdx.x]; }
        atomicAdd(&stat[threadIdx.x], (double)ss);
        atomicAdd(&stat[C + threadIdx.x], (double)qq);
    }
}

// BN apply: per-block hoist of f32 scale/shift
__global__ void __launch_bounds__(256) k_bn(
        const float* __restrict__ in, float* __restrict__ out,
        const double* __restrict__ stat, const float* __restrict__ g,
        const float* __restrict__ be, int rows, int logC, int act) {
    int C = 1 << logC;
    __shared__ float scl[64], shl[64];
    int t = threadIdx.x;
    if (t < C) {
        double inv = 1.0 / (double)rows;
        float m = (float)(stat[t] * inv);
        float var = (float)(stat[C + t] * inv) - m * m; if (var < 0.f) var = 0.f;
        float rstd = rsqrtf(var + BN_EPS);
        float sc = rstd * g[t];
        scl[t] = sc; shl[t] = be[t] - m * sc;
    }
    __syncthreads();
    size_t total = (size_t)rows << logC;
    size_t i = (size_t)blockIdx.x * 256 + t;
    if (i >= total) return;
    int f = (int)(i & (C - 1));
    float val = fmaf(in[i], scl[f], shl[f]);
    out[i] = act ? sp(val) : val;
}

// global pooling: block-per-batch segment sum over sorted batch (no atomics)
__global__ void __launch_bounds__(256) k_hg2(
        const float* __restrict__ h, const int* __restrict__ bptr, float* __restrict__ hg) {
    int b = blockIdx.x;                                  // BB
    int lane = threadIdx.x & 63, w = threadIdx.x >> 6;
    int n0 = bptr[b], n1 = bptr[b + 1];
    float acc = 0.f;
    for (int n = n0 + w; n < n1; n += 4)
        acc += h[(n << 6) | lane];
    __shared__ float ls[256];
    ls[threadIdx.x] = acc; __syncthreads();
    if (threadIdx.x < 64)
        hg[(b << 6) | lane] = ls[lane] + ls[64 + lane] + ls[128 + lane] + ls[192 + lane];
}

// head GEMV 1: 4 nodes/wave, lane = output feature
#define O1NPW 4
__global__ void __launch_bounds__(256) k_o1(
        const float* __restrict__ h, const float* __restrict__ hg, const int* __restrict__ batch,
        const float* __restrict__ w1T, const float* __restrict__ b1, float* __restrict__ z1) {
    int lane = threadIdx.x & 63;
    int wv = (blockIdx.x * 256 + (int)threadIdx.x) >> 6;
    int n0 = __builtin_amdgcn_readfirstlane(wv * O1NPW);
    if (n0 >= NN) return;
    float hl[O1NPW], gl[O1NPW], acc[O1NPW];
    float bl = b1[lane];
    #pragma unroll
    for (int k = 0; k < O1NPW; k++) {
        int n = n0 + k;
        hl[k] = h[(n << 6) | lane];
        gl[k] = hg[(batch[n] << 6) | lane];
        acc[k] = bl;
    }
    #pragma unroll
    for (int j = 0; j < 64; j++) {
        float w = w1T[(j << 6) | lane];
        #pragma unroll
        for (int k = 0; k < O1NPW; k++)
            acc[k] = fmaf(rl(hl[k], j), w, acc[k]);
    }
    #pragma unroll
    for (int j = 0; j < 64; j++) {
        float w = w1T[((64 + j) << 6) | lane];
        #pragma unroll
        for (int k = 0; k < O1NPW; k++)
            acc[k] = fmaf(rl(gl[k], j), w, acc[k]);
    }
    #pragma unroll
    for (int k = 0; k < O1NPW; k++)
        z1[((n0 + k) << 6) | lane] = acc[k];
}

// head GEMV 2: 8 nodes/wave
__global__ void __launch_bounds__(256) k_o2(
        const float* __restrict__ o1v, const float* __restrict__ w2T2,
        const float* __restrict__ b2, float* __restrict__ z2) {
    int lane = threadIdx.x & 63;
    int ho = lane & 31;
    int wv = (blockIdx.x * 256 + (int)threadIdx.x) >> 6;
    int n0 = __builtin_amdgcn_readfirstlane(wv * 8);
    if (n0 >= NN) return;
    float xr[8], acc[4];
    #pragma unroll
    for (int k = 0; k < 8; k++) {
        int n = n0 + k; if (n >= NN) n = NN - 1;
        xr[k] = o1v[(n << 6) | lane];
    }
    float bl = b2[ho];
    #pragma unroll
    for (int k = 0; k < 4; k++) acc[k] = bl;
    #pragma unroll
    for (int j = 0; j < 64; j++) {
        float w = w2T2[(j << 5) | ho];
        #pragma unroll
        for (int k = 0; k < 4; k++) {
            float slo = rl(xr[k], j);
            float shi = rl(xr[4 + k], j);
            float v = (lane < 32) ? slo : shi;
            acc[k] = fmaf(v, w, acc[k]);
        }
    }
    int nbase = n0 + ((lane >> 5) << 2);
    #pragma unroll
    for (int k = 0; k < 4; k++)
        if (nbase + k < NN) z2[((nbase + k) << 5) | ho] = acc[k];
}

// head GEMV 3: 4 nodes per wave per jo-half
__global__ void __launch_bounds__(256) k_o3(
        const float* __restrict__ o2v, const float* __restrict__ w3T,
        const float* __restrict__ b3, float* __restrict__ outp) {
    int lane = threadIdx.x & 63;
    int wv = (blockIdx.x * 256 + (int)threadIdx.x) >> 6;
    int n0 = __builtin_amdgcn_readfirstlane((wv >> 1) << 2);
    int jo = (((wv & 1) << 6) + lane);
    if (n0 >= NN) return;
    float zl[4], acc[4];
    float bl = b3[jo];
    #pragma unroll
    for (int k = 0; k < 4; k++) {
        zl[k] = o2v[((n0 + k) << 5) | (lane & 31)];
        acc[k] = bl;
    }
    #pragma unroll
    for (int j = 0; j < 32; j++) {
        float w = w3T[(j << 7) | jo];
        #pragma unroll
        for (int k = 0; k < 4; k++)
            acc[k] = fmaf(rl(zl[k], j), w, acc[k]);
    }
    #pragma unroll
    for (int k = 0; k < 4; k++) {
        int n = n0 + k;
        size_t dsti = (jo < 64) ? ((size_t)(n << 6) + jo)
                                : ((size_t)NN * 64 + (size_t)(n << 6) + (jo - 64));
        outp[dsti] = acc[k];                             // f32 output
    }
}

extern "C" void kernel_launch(void* const* d_in, const int* in_sizes, int n_in,
                              void* d_out, int out_size, void* d_ws, size_t ws_size,
                              hipStream_t stream) {
    const float* x        = (const float*)d_in[0];
    const int* node_type  = (const int*)d_in[1];
    const int* edge_type  = (const int*)d_in[2];
    const int* edge_index = (const int*)d_in[3];
    const int* batch      = (const int*)d_in[4];
    const float* node_emb = (const float*)d_in[5];
    const float* edge_emb = (const float*)d_in[6];
    const float* w_d1 = (const float*)d_in[7];  const float* b_d1 = (const float*)d_in[8];
    const float* g_d1 = (const float*)d_in[9];  const float* be_d1 = (const float*)d_in[10];
    const float* w_d2 = (const float*)d_in[11]; const float* b_d2 = (const float*)d_in[12];
    const float* g_d2 = (const float*)d_in[13]; const float* be_d2 = (const float*)d_in[14];
    const float* g_c1 = (const float*)d_in[15]; const float* be_c1 = (const float*)d_in[16];
    const float* g_c2 = (const float*)d_in[17]; const float* be_c2 = (const float*)d_in[18];
    const float* g_c3 = (const float*)d_in[19]; const float* be_c3 = (const float*)d_in[20];
    const float* w_o1 = (const float*)d_in[21]; const float* b_o1 = (const float*)d_in[22];
    const float* g_o1 = (const float*)d_in[23]; const float* be_o1 = (const float*)d_in[24];
    const float* w_o2 = (const float*)d_in[25]; const float* b_o2 = (const float*)d_in[26];
    const float* g_o2 = (const float*)d_in[27]; const float* be_o2 = (const float*)d_in[28];
    const float* w_o3 = (const float*)d_in[29]; const float* b_o3 = (const float*)d_in[30];
    (void)b_d1;  // cancels inside BN1 (mean subtraction removes per-feature shift)
    const int* src  = edge_index;
    const int* dstv = edge_index + EE;

    char* ws = (char*)d_ws;
    int4*  esd     = (int4*)(ws + OFF_ESD);
    int*   row_ptr = (int*)(ws + OFF_ROWP);
    float* hA   = (float*)(ws + OFF_HA);
    float* hB   = (float*)(ws + OFF_HB);
    float* zb   = (float*)(ws + OFF_ZB);
    int4*  esd_tmp = (int4*)(ws + OFF_HA);   // aliases hA..hB (live only before k_locsort done)
    int*   hpart = (int*)(ws + OFF_HB);      // aliases hB (live hist3..ytmom)
    int*   T    = (int*)(ws + OFF_TMAT);     // aliases zb (live only before k_binscat done)
    int*   tot  = (int*)(ws + OFF_TOT);
    int*   bbase= (int*)(ws + OFF_BBASE);
    float* ytab = (float*)(ws + OFF_YTAB);
    u32*   ptab = (u32*)(ws + OFF_PTAB);
    float* w2T  = (float*)(ws + OFF_W2T);
    float* b2f  = (float*)(ws + OFF_B2F);
    float* w1T  = (float*)(ws + OFF_W1T);
    float* w2T2 = (float*)(ws + OFF_W2O);
    float* w3T  = (float*)(ws + OFF_W3T);
    int*   bptr = (int*)(ws + OFF_BPTR);
    float* hg     = (float*)(ws + OFF_HG);
    double* xstat = (double*)(ws + OFF_XSTAT);
    double* sty   = (double*)(ws + OFF_STY);
    double* fst   = (double*)(ws + OFF_FST);
    double* st0 = fst;          double* st1 = fst + 128;  double* st2 = fst + 256;
    double* st3 = fst + 384;    double* st4 = fst + 512;

    hipMemsetAsync(ws + OFF_HG, 0, ZERO_BYTES, stream);

    // merged prep: weights transpose | xstats | bptr | bincnt
    k_prep0<<<1036, 256, 0, stream>>>(w_d2, b_d2, w_o1, w_o2, w_o3, x, batch, dstv,
                                      w2T, b2f, w1T, w2T2, w3T, xstat, bptr, T);
    k_bscanA<<<NBKT, 256, 0, stream>>>(T, tot);
    k_bscanB<<<1, 256, 0, stream>>>(tot, bbase, row_ptr);
    k_binscat<<<NB1, 1024, 0, stream>>>(x, src, dstv, edge_type, T, bbase, esd_tmp);
    k_locsort<<<NBKT, 256, 0, stream>>>(esd_tmp, bbase, row_ptr, esd);
    // x histogram (after locsort: hpart aliases hB which overlapped esd_tmp)
    k_hist3<<<HBLK, 1024, 0, stream>>>(x, hpart);
    // fused knot table + BN2 moments; then pack
    k_ytmom<<<128, 256, 0, stream>>>(xstat, w_d1, g_d1, be_d1, w2T, b2f, hpart, ytab, sty);
    k_ypack<<<NTB * 64 / 256, 256, 0, stream>>>(ytab, sty, g_d2, be_d2, ptab);
    // gconv 1 (h from node_emb[node_type], L1-resident)
    k_agg0<<<12500, 256, 0, stream>>>(node_type, node_emb, esd, row_ptr, ptab, edge_emb, hB);
    k_fstats<<<1024, 256, 0, stream>>>(hB, NN, 6, st0);
    k_bn<<<12500, 256, 0, stream>>>(hB, hB, st0, g_c1, be_c1, NN, 6, 1);
    // gconv 2
    k_agg<<<12500, 256, 0, stream>>>(hB, esd, row_ptr, ptab, edge_emb, hA);
    k_fstats<<<1024, 256, 0, stream>>>(hA, NN, 6, st1);
    k_bn<<<12500, 256, 0, stream>>>(hA, hA, st1, g_c2, be_c2, NN, 6, 1);
    // gconv 3 (no activation)
    k_agg<<<12500, 256, 0, stream>>>(hA, esd, row_ptr, ptab, edge_emb, hB);
    k_fstats<<<1024, 256, 0, stream>>>(hB, NN, 6, st2);
    k_bn<<<12500, 256, 0, stream>>>(hB, hB, st2, g_c3, be_c3, NN, 6, 0);
    // global pool + head
    k_hg2<<<BB, 256, 0, stream>>>(hB, bptr, hg);
    k_o1<<<3125, 256, 0, stream>>>(hB, hg, batch, w1T, b_o1, hA);
    k_fstats<<<1024, 256, 0, stream>>>(hA, NN, 6, st3);
    k_bn<<<12500, 256, 0, stream>>>(hA, hA, st3, g_o1, be_o1, NN, 6, 1);
    k_o2<<<1563, 256, 0, stream>>>(hA, w2T2, b_o2, zb);
    k_fstats<<<1024, 256, 0, stream>>>(zb, NN, 5, st4);
    k_bn<<<6250, 256, 0, stream>>>(zb, zb, st4, g_o2, be_o2, NN, 5, 1);
    k_o3<<<6250, 256, 0, stream>>>(zb, w3T, b_o3, (float*)d_out);
    (void)in_sizes; (void)n_in; (void)out_size; (void)ws_size;
}

// Round 9
// 665.574 us; speedup vs baseline: 1.2862x; 1.0087x over previous
//
#include <hip/hip_runtime.h>
#include <stdint.h>

#define NN 50000
#define EE 1250000
#define BB 500
#define BN_EPS 1e-5f
#define LOG2E 1.44269504f
#define LN2 0.69314718f

// two-level multisplit: 391 buckets of 128 nodes + per-bucket local sort
#define NBKT 391
#define NPBSH 7
#define NB1 256       // binning blocks
#define BPB 4883      // edges per binning block (256*4883 >= EE)

// x-histogram for BN2 moments (merged into binscat launch; dedicated hpart region)
#define HBLK 88
#define HEPB ((EE + HBLK - 1) / HBLK)   // 14205 edges per hist block
#define FHSC 65536.f                     // fixed-point scale for f, f^2 partials
#define FHIN (1.f / 65536.f)

#define NTB 8192      // table intervals; 8193 knots
#define XLO (-12.0f)
#define XHI (12.0f)
#define XSC ((float)NTB / (XHI - XLO))
#define DXT ((XHI - XLO) / (float)NTB)
#define TPMAX 8191.999f

using u16 = unsigned short;
using u32 = unsigned int;

__device__ __forceinline__ u16 f2bf(float f) {
    u32 u = __float_as_uint(f);
    return (u16)((u + 0x7fffu + ((u >> 16) & 1u)) >> 16);
}
__device__ __forceinline__ u32 pk2(float a, float b) { return (u32)f2bf(a) | ((u32)f2bf(b) << 16); }
// softplus via native v_exp_f32 / v_log_f32
__device__ __forceinline__ float sp(float z) {
    float t = __builtin_amdgcn_exp2f(-fabsf(z) * LOG2E);
    float l = __builtin_amdgcn_logf(1.f + t) * LN2;
    return fmaxf(z, 0.f) + l;
}
// guaranteed v_readlane (VALU)
__device__ __forceinline__ float rl(float v, int l) {
    return __uint_as_float(__builtin_amdgcn_readlane(__float_as_uint(v), l));
}

// ---------------- workspace layout (~65 MB) ----------------
constexpr size_t OFF_ESD  = 0;                                    // int4 [E] {src, et, i, f_bits}
constexpr size_t OFF_ROWP = OFF_ESD + (size_t)EE * 16;            // row_ptr [N+1]
constexpr size_t OFF_HA   = (OFF_ROWP + (size_t)(NN + 1) * 4 + 255) & ~(size_t)255;
constexpr size_t OFF_HB   = OFF_HA + (size_t)NN * 64 * 4;
// esd_tmp (20 MB) aliases hA..hB: live only before k_locsort
constexpr size_t OFF_ZB   = OFF_HB + (size_t)NN * 64 * 4;         // [N,32]
// sort scratch aliases zb (dead before k_o2): T[NB1][NBKT], tot, bbase
constexpr size_t OFF_TMAT = OFF_ZB;
constexpr size_t OFF_TOT  = OFF_TMAT + (size_t)NB1 * NBKT * 4;
constexpr size_t OFF_BBASE= OFF_TOT + (size_t)NBKT * 4;
constexpr size_t OFF_YTAB = OFF_ZB + (size_t)NN * 32 * 4;         // f32 [NTB+1][64]
constexpr size_t OFF_PTAB = OFF_YTAB + (size_t)(NTB + 1) * 64 * 4;// u32 [NTB][64] bf16 (a, b-a), x LOG2E
constexpr size_t OFF_W2T  = OFF_PTAB + (size_t)NTB * 64 * 4;      // w_d2 transposed f32 [64][64]
constexpr size_t OFF_B2F  = OFF_W2T + 4096 * 4;
constexpr size_t OFF_W1T  = OFF_B2F + 256;                        // f32 [128][64] (w_o1^T)
constexpr size_t OFF_W2O  = OFF_W1T + 8192 * 4;                   // f32 [64][32]  (w_o2^T)
constexpr size_t OFF_W3T  = OFF_W2O + 2048 * 4;                   // f32 [32][128] (w_o3^T)
constexpr size_t OFF_BPTR = OFF_W3T + 4096 * 4;                   // int [B+1]
// zero region (one memset): hg | xstat | sty | 5 stat slots
constexpr size_t OFF_HG   = (OFF_BPTR + (BB + 1) * 4 + 255) & ~(size_t)255;
constexpr size_t OFF_XSTAT= OFF_HG + (size_t)BB * 64 * 4;         // 2 doubles
constexpr size_t OFF_STY  = OFF_XSTAT + 16;                       // 128 doubles
constexpr size_t OFF_FST  = OFF_STY + 128 * 8;
constexpr size_t ZERO_END = OFF_FST + 5 * 128 * 8;
constexpr size_t ZERO_BYTES = ZERO_END - OFF_HG;
// hpart: dedicated (coexists with esd_tmp during the merged binscat|hist launch)
constexpr size_t OFF_HPART= (ZERO_END + 255) & ~(size_t)255;      // int [HBLK][3][NTB] (~8.3 MB)

// ---------------- merged prep: w2prep | otprep | xstats | bptr | bincnt ----------------
// blocks [0,16) w2T/b2f  [16,72) w1T/w2T2/w3T  [72,584) xstats  [584,780) bptr  [780,1036) bincnt
__global__ void __launch_bounds__(256) k_prep0(
        const float* __restrict__ w2, const float* __restrict__ b2,
        const float* __restrict__ w1, const float* __restrict__ wo2, const float* __restrict__ w3,
        const float* __restrict__ x, const int* __restrict__ batch, const int* __restrict__ dstv,
        float* __restrict__ w2T, float* __restrict__ b2f,
        float* __restrict__ w1T, float* __restrict__ w2T2, float* __restrict__ w3T,
        double* __restrict__ xstat, int* __restrict__ bptr, int* __restrict__ T) {
    int bx = blockIdx.x, t = threadIdx.x;
    if (bx < 16) {
        int idx = bx * 256 + t;                          // 4096
        int hin = idx >> 6, ho = idx & 63;
        w2T[idx] = w2[ho * 64 + hin];
        if (idx < 64) b2f[idx] = b2[idx];
    } else if (bx < 72) {
        int idx = (bx - 16) * 256 + t;                   // 14336
        if (idx < 8192) {
            int j = idx >> 6, ho = idx & 63;
            w1T[idx] = w1[ho * 128 + j];
        } else if (idx < 8192 + 2048) {
            int q = idx - 8192;
            int j = q >> 5, ho = q & 31;
            w2T2[q] = wo2[ho * 64 + j];
        } else if (idx < 8192 + 2048 + 4096) {
            int q = idx - 8192 - 2048;
            int j = q >> 7, jo = q & 127;
            w3T[q] = w3[jo * 32 + j];
        }
    } else if (bx < 584) {
        __shared__ float ls[256], lq[256];
        float s = 0, q = 0;
        for (int i = (bx - 72) * 256 + t; i < EE; i += 512 * 256) {
            float v = x[i]; s += v; q += v * v;
        }
        ls[t] = s; lq[t] = q; __syncthreads();
        for (int off = 128; off > 0; off >>= 1) {
            if (t < off) { ls[t] += ls[t + off]; lq[t] += lq[t + off]; }
            __syncthreads();
        }
        if (t == 0) { atomicAdd(&xstat[0], (double)ls[0]); atomicAdd(&xstat[1], (double)lq[0]); }
    } else if (bx < 780) {
        int n = (bx - 584) * 256 + t;
        if (n >= NN) return;
        int b = batch[n];
        int pb = (n == 0) ? -1 : batch[n - 1];
        for (int k = pb + 1; k <= b; k++) bptr[k] = n;
        if (n == NN - 1) { for (int k = b + 1; k <= BB; k++) bptr[k] = NN; }
    } else {
        // bincnt: per-block LDS histogram over 391 coarse buckets
        __shared__ int hh[NBKT];
        for (int i = t; i < NBKT; i += 256) hh[i] = 0;
        __syncthreads();
        int bb = bx - 780;
        int e0 = bb * BPB;
        int e1 = e0 + BPB; if (e1 > EE) e1 = EE;
        for (int e = e0 + t; e < e1; e += 256)
            atomicAdd(&hh[dstv[e] >> NPBSH], 1);
        __syncthreads();
        for (int i = t; i < NBKT; i += 256)
            T[(size_t)bb * NBKT + i] = hh[i];
    }
}

// per-bucket exclusive scan over blocks (in-place), bucket totals out
__global__ void k_bscanA(int* __restrict__ T, int* __restrict__ tot) {
    __shared__ int ls[256];
    int b = blockIdx.x, t = threadIdx.x;
    int v = T[(size_t)t * NBKT + b];
    ls[t] = v; __syncthreads();
    for (int off = 1; off < 256; off <<= 1) {
        int a = ls[t]; int add = (t >= off) ? ls[t - off] : 0; __syncthreads();
        ls[t] = a + add; __syncthreads();
    }
    T[(size_t)t * NBKT + b] = ls[t] - v;
    if (t == 255) tot[b] = ls[255];
}

// ---------------- merged: chunked bucket scatter | x histogram ----------------
// blocks [0,NB1): binscat (each block re-derives the 391-bucket exclusive scan from tot
//                 in LDS -- replaces k_bscanB; block 0 publishes bbase for locsort)
// blocks [NB1, NB1+HBLK): 3-component x histogram (int fixed-point, native ds_add)
__global__ void __launch_bounds__(1024) k_binhist(
        const float* __restrict__ x, const int* __restrict__ src,
        const int* __restrict__ dstv, const int* __restrict__ etv,
        const int* __restrict__ T, const int* __restrict__ tot,
        int* __restrict__ bbase_g, int4* __restrict__ esd_tmp, int* __restrict__ hpart) {
    __shared__ int shb[3 * (NTB / 2)];                   // 48 KB, unioned across branches
    int t = threadIdx.x;
    if (blockIdx.x < NB1) {
        int* cur = shb;                                  // [NBKT]
        int* sls = shb + 512;                            // [512] scan buffer
        int v = 0;
        if (t < 512) { v = (t < NBKT) ? tot[t] : 0; sls[t] = v; }
        __syncthreads();
        for (int off = 1; off < 512; off <<= 1) {
            int a = 0;
            if (t < 512) { a = sls[t]; if (t >= off) a += sls[t - off]; }
            __syncthreads();
            if (t < 512) sls[t] = a;
            __syncthreads();
        }
        if (t < NBKT) {
            int base = sls[t] - v;                       // exclusive
            cur[t] = base + T[(size_t)blockIdx.x * NBKT + t];
            if (blockIdx.x == 0) bbase_g[t] = base;
        }
        if (blockIdx.x == 0 && t == 0) bbase_g[NBKT] = EE;
        __syncthreads();
        int e0 = blockIdx.x * BPB;
        int e1 = e0 + BPB; if (e1 > EE) e1 = EE;
        for (int e = e0 + t; e < e1; e += 1024) {
            int d = dstv[e];
            int p = atomicAdd(&cur[d >> NPBSH], 1);
            float tp = fminf(fmaxf((x[e] - XLO) * XSC, 0.f), TPMAX);
            int i = (int)tp; float f = tp - (float)i;
            // local dst (7 bits) rides in spare bits of et (et < 128)
            int4 vv; vv.x = src[e]; vv.y = etv[e] | ((d & 127) << 7); vv.z = i; vv.w = __float_as_int(f);
            esd_tmp[p] = vv;
        }
    } else {
        int* cnt = shb; int* sf = shb + NTB / 2; int* sf2 = shb + NTB;
        int bb = blockIdx.x - NB1;
        int e0 = bb * HEPB;
        int e1 = e0 + HEPB; if (e1 > EE) e1 = EE;
        int* outp = hpart + (size_t)bb * 3 * NTB;
        for (int half = 0; half < 2; half++) {
            for (int i = t; i < NTB / 2; i += 1024) { cnt[i] = 0; sf[i] = 0; sf2[i] = 0; }
            __syncthreads();
            int lo = half * (NTB / 2);
            for (int e = e0 + t; e < e1; e += 1024) {
                float tp = fminf(fmaxf((x[e] - XLO) * XSC, 0.f), TPMAX);
                int i = (int)tp;
                int li = i - lo;
                if ((unsigned)li < (unsigned)(NTB / 2)) {
                    float f = tp - (float)i;
                    atomicAdd(&cnt[li], 1);
                    atomicAdd(&sf[li], (int)(f * FHSC));
                    atomicAdd(&sf2[li], (int)(f * f * FHSC));
                }
            }
            __syncthreads();
            for (int i = t; i < NTB / 2; i += 1024) {
                outp[lo + i] = cnt[i];
                outp[NTB + lo + i] = sf[i];
                outp[2 * NTB + lo + i] = sf2[i];
            }
            __syncthreads();
        }
    }
}

// per-bucket local counting sort (L2-resident region); also emits row_ptr
__global__ void __launch_bounds__(256) k_locsort(
        const int4* __restrict__ esd_tmp, const int* __restrict__ bbase,
        int* __restrict__ row_ptr, int4* __restrict__ esd) {
    __shared__ int hist[128];
    __shared__ int ls[128];
    __shared__ int cur[128];
    int b = blockIdx.x;
    int t = threadIdx.x;
    if (b == 0 && t == 0) row_ptr[NN] = EE;
    int base = bbase[b], end = bbase[b + 1];
    if (t < 128) hist[t] = 0;
    __syncthreads();
    for (int p = base + t; p < end; p += 256)
        atomicAdd(&hist[(esd_tmp[p].y >> 7) & 127], 1);
    __syncthreads();
    int v = 0;
    if (t < 128) { v = hist[t]; ls[t] = v; }
    __syncthreads();
    for (int off = 1; off < 128; off <<= 1) {
        int a = 0;
        if (t < 128) { a = ls[t]; if (t >= off) a += ls[t - off]; }
        __syncthreads();
        if (t < 128) ls[t] = a;
        __syncthreads();
    }
    if (t < 128) {
        int exc = ls[t] - v;
        cur[t] = base + exc;
        int n = (b << NPBSH) + t;
        if (n < NN) row_ptr[n] = base + exc;
    }
    __syncthreads();
    for (int p = base + t; p < end; p += 256) {
        int4 r = esd_tmp[p];
        int ld = (r.y >> 7) & 127;
        r.y &= 127;
        esd[atomicAdd(&cur[ld], 1)] = r;
    }
}

// ---------------- fused table build + BN2 moments ----------------
__global__ void __launch_bounds__(256) k_ytmom(
        const double* __restrict__ xstat, const float* __restrict__ w_d1,
        const float* __restrict__ g_d1, const float* __restrict__ be_d1,
        const float* __restrict__ w2T, const float* __restrict__ b2f,
        const int* __restrict__ hpart, float* __restrict__ ytab, double* __restrict__ sty) {
    __shared__ float kn[65][64];
    __shared__ float hs[192];
    int t = threadIdx.x;
    int lane = t & 63, w = t >> 6;
    int g = blockIdx.x;                                  // 0..127
    double inv = 1.0 / (double)EE;
    double mx = xstat[0] * inv;
    double vx = xstat[1] * inv - mx * mx; if (vx < 0) vx = 0;
    float wd = w_d1[lane];
    float Aw = wd * rsqrtf((float)vx * wd * wd + BN_EPS) * g_d1[lane];
    float Cw = be_d1[lane];
    for (int kk = w; kk < 65; kk += 4) {
        int idx = (g << 6) + kk;
        float xi = XLO + (float)idx * DXT;
        float tt = xi - (float)mx;
        float d1L = sp(fmaf(Aw, tt, Cw));
        float y = b2f[lane];
        #pragma unroll
        for (int hin = 0; hin < 64; hin++)
            y = fmaf(rl(d1L, hin), w2T[hin * 64 + lane], y);
        kn[kk][lane] = y;
        if (kk < 64 || g == 127) ytab[(idx << 6) | lane] = y;
    }
    if (t < 192) {                                       // hsum: c|f1|f2 for this block's 64 bins
        int slot = t >> 6, ii = t & 63;
        float s = 0.f;
        size_t off = (size_t)slot * NTB + (g << 6) + ii;
        for (int b = 0; b < HBLK; b++)
            s += (float)hpart[(size_t)b * 3 * NTB + off];
        hs[t] = (slot == 0) ? s : s * FHIN;
    }
    __syncthreads();
    if (t >= 64) return;                                 // one wave: moment math
    double S = 0.0, Q = 0.0;
    float aprev = kn[0][lane];
    for (int ii = 0; ii < 64; ii++) {
        float c = hs[ii], f1 = hs[64 + ii], f2 = hs[128 + ii];
        float b = kn[ii + 1][lane];
        float a = aprev; aprev = b;
        float d = b - a;
        S += (double)(fmaf(c, a, d * f1));
        Q += (double)(fmaf(c * a, a, fmaf(2.f * a * d, f1, d * d * f2)));
    }
    atomicAdd(&sty[lane], S);
    atomicAdd(&sty[64 + lane], Q);
}

// pack bn2-affined table as bf16 (a, b-a) pairs, pre-scaled by LOG2E (log2-domain agg)
__global__ void k_ypack(const float* __restrict__ ytab, const double* __restrict__ sty,
                        const float* __restrict__ g2, const float* __restrict__ be2,
                        u32* __restrict__ ptab) {
    int tid = blockIdx.x * 256 + threadIdx.x;            // NTB*64
    int f = tid & 63;
    double inv = 1.0 / (double)EE;
    double m = sty[f] * inv;
    double var = sty[64 + f] * inv - m * m; if (var < 0) var = 0;
    float rstd = rsqrtf((float)var + BN_EPS);
    float sc0 = rstd * g2[f];
    float sc = sc0 * LOG2E;
    float sh = (be2[f] - (float)m * sc0) * LOG2E;
    float a = fmaf(ytab[tid], sc, sh);
    float b = fmaf(ytab[tid + 64], sc, sh);
    ptab[tid] = pk2(a, b - a);
}

// per-edge term (log2-scaled): one fmaf lerp + emb mul
__device__ __forceinline__ float edge_term(int4 ed, int lane, const u32* __restrict__ ptab,
                                           const float* __restrict__ emb) {
    u32 pr = ptab[(ed.z << 6) | lane];
    float f = __int_as_float(ed.w);
    float a = __uint_as_float(pr << 16);
    float d = __uint_as_float(pr & 0xffff0000u);
    float y = fmaf(f, d, a);
    return y * emb[(ed.y << 6) | lane];
}
// log2-domain softplus accumulate: z = h*log2e + av; sp(z)/ln2 = max(z,0) + log2(1+2^-|z|)
__device__ __forceinline__ void sp2(float hv, float av, float& accm, float& accl) {
    float z = fmaf(hv, LOG2E, av);
    float t = __builtin_amdgcn_exp2f(-fabsf(z));
    accm += fmaxf(z, 0.f);
    accl += __builtin_amdgcn_logf(1.f + t);
}

// wave-per-node aggregation; 128-thr blocks (2 nodes) to cut degree-imbalance waste
__global__ void __launch_bounds__(128) k_agg(
        const float* __restrict__ h, const int4* __restrict__ esd, const int* __restrict__ row_ptr,
        const u32* __restrict__ ptab, const float* __restrict__ emb, float* __restrict__ hpre) {
    int lane = threadIdx.x & 63;
    int n = __builtin_amdgcn_readfirstlane((int)((blockIdx.x << 1) | (threadIdx.x >> 6)));
    int p0 = row_ptr[n], p1 = row_ptr[n + 1];
    float accm = 0.f, accl = 0.f;
    int p = p0;
    for (; p + 4 <= p1; p += 4) {
        int4 e0 = esd[p], e1 = esd[p + 1], e2 = esd[p + 2], e3 = esd[p + 3];
        float h0 = h[(e0.x << 6) | lane];
        float h1 = h[(e1.x << 6) | lane];
        float h2 = h[(e2.x << 6) | lane];
        float h3 = h[(e3.x << 6) | lane];
        float a0 = edge_term(e0, lane, ptab, emb);
        float a1 = edge_term(e1, lane, ptab, emb);
        float a2 = edge_term(e2, lane, ptab, emb);
        float a3 = edge_term(e3, lane, ptab, emb);
        sp2(h0, a0, accm, accl);
        sp2(h1, a1, accm, accl);
        sp2(h2, a2, accm, accl);
        sp2(h3, a3, accm, accl);
    }
    for (; p < p1; ++p) {
        int4 e0 = esd[p];
        float h0 = h[(e0.x << 6) | lane];
        sp2(h0, edge_term(e0, lane, ptab, emb), accm, accl);
    }
    int o = (n << 6) | lane;
    hpre[o] = fmaf(accm + accl, LN2, h[o]);
}

// gconv1 variant: h comes from node_emb[node_type] (L1-resident)
__global__ void __launch_bounds__(128) k_agg0(
        const int* __restrict__ nt, const float* __restrict__ nemb, const int4* __restrict__ esd,
        const int* __restrict__ row_ptr, const u32* __restrict__ ptab,
        const float* __restrict__ emb, float* __restrict__ hpre) {
    int lane = threadIdx.x & 63;
    int n = __builtin_amdgcn_readfirstlane((int)((blockIdx.x << 1) | (threadIdx.x >> 6)));
    int p0 = row_ptr[n], p1 = row_ptr[n + 1];
    float accm = 0.f, accl = 0.f;
    int p = p0;
    for (; p + 4 <= p1; p += 4) {
        int4 e0 = esd[p], e1 = esd[p + 1], e2 = esd[p + 2], e3 = esd[p + 3];
        float h0 = nemb[(nt[e0.x] << 6) | lane];
        float h1 = nemb[(nt[e1.x] << 6) | lane];
        float h2 = nemb[(nt[e2.x] << 6) | lane];
        float h3 = nemb[(nt[e3.x] << 6) | lane];
        float a0 = edge_term(e0, lane, ptab, emb);
        float a1 = edge_term(e1, lane, ptab, emb);
        float a2 = edge_term(e2, lane, ptab, emb);
        float a3 = edge_term(e3, lane, ptab, emb);
        sp2(h0, a0, accm, accl);
        sp2(h1, a1, accm, accl);
        sp2(h2, a2, accm, accl);
        sp2(h3, a3, accm, accl);
    }
    for (; p < p1; ++p) {
        int4 e0 = esd[p];
        float h0 = nemb[(nt[e0.x] << 6) | lane];
        sp2(h0, edge_term(e0, lane, ptab, emb), accm, accl);
    }
    hpre[(n << 6) | lane] = fmaf(accm + accl, LN2, nemb[(nt[n] << 6) | lane]);
}

// per-feature mean/var partials over [rows, C] (C = 1<<logC), f64 atomics
__global__ void k_fstats(const float* __restrict__ v, int rows, int logC, double* __restrict__ stat) {
    int C = 1 << logC;
    int f = threadIdx.x & (C - 1);
    int r0 = threadIdx.x >> logC;
    int rpb = 256 >> logC;
    float s = 0, q = 0;
    for (int r = blockIdx.x * rpb + r0; r < rows; r += gridDim.x * rpb) {
        float val = v[(size_t)r * C + f];
        s += val; q += val * val;
    }
    __shared__ float lsS[256], lsQ[256];
    lsS[threadIdx.x] = s; lsQ[threadIdx.x] = q; __syncthreads();
    if (threadIdx.x < C) {
        float ss = 0, qq = 0;
        for (int j = 0; j < rpb; j++) { ss += lsS[j * C + threadIdx.x]; qq += lsQ[j * C + threadIdx.x]; }
        atomicAdd(&stat[threadIdx.x], (double)ss);
        atomicAdd(&stat[C + threadIdx.x], (double)qq);
    }
}

// BN apply: per-block hoist of f32 scale/shift
__global__ void __launch_bounds__(256) k_bn(
        const float* __restrict__ in, float* __restrict__ out,
        const double* __restrict__ stat, const float* __restrict__ g,
        const float* __restrict__ be, int rows, int logC, int act) {
    int C = 1 << logC;
    __shared__ float scl[64], shl[64];
    int t = threadIdx.x;
    if (t < C) {
        double inv = 1.0 / (double)rows;
        float m = (float)(stat[t] * inv);
        float var = (float)(stat[C + t] * inv) - m * m; if (var < 0.f) var = 0.f;
        float rstd = rsqrtf(var + BN_EPS);
        float sc = rstd * g[t];
        scl[t] = sc; shl[t] = be[t] - m * sc;
    }
    __syncthreads();
    size_t total = (size_t)rows << logC;
    size_t i = (size_t)blockIdx.x * 256 + t;
    if (i >= total) return;
    int f = (int)(i & (C - 1));
    float val = fmaf(in[i], scl[f], shl[f]);
    out[i] = act ? sp(val) : val;
}

// global pooling: block-per-batch segment sum over sorted batch (no atomics)
__global__ void __launch_bounds__(256) k_hg2(
        const float* __restrict__ h, const int* __restrict__ bptr, float* __restrict__ hg) {
    int b = blockIdx.x;                                  // BB
    int lane = threadIdx.x & 63, w = threadIdx.x >> 6;
    int n0 = bptr[b], n1 = bptr[b + 1];
    float acc = 0.f;
    for (int n = n0 + w; n < n1; n += 4)
        acc += h[(n << 6) | lane];
    __shared__ float ls[256];
    ls[threadIdx.x] = acc; __syncthreads();
    if (threadIdx.x < 64)
        hg[(b << 6) | lane] = ls[lane] + ls[64 + lane] + ls[128 + lane] + ls[192 + lane];
}

// head GEMV 1: 4 nodes/wave, lane = output feature
#define O1NPW 4
__global__ void __launch_bounds__(256) k_o1(
        const float* __restrict__ h, const float* __restrict__ hg, const int* __restrict__ batch,
        const float* __restrict__ w1T, const float* __restrict__ b1, float* __restrict__ z1) {
    int lane = threadIdx.x & 63;
    int wv = (blockIdx.x * 256 + (int)threadIdx.x) >> 6;
    int n0 = __builtin_amdgcn_readfirstlane(wv * O1NPW);
    if (n0 >= NN) return;
    float hl[O1NPW], gl[O1NPW], acc[O1NPW];
    float bl = b1[lane];
    #pragma unroll
    for (int k = 0; k < O1NPW; k++) {
        int n = n0 + k;
        hl[k] = h[(n << 6) | lane];
        gl[k] = hg[(batch[n] << 6) | lane];
        acc[k] = bl;
    }
    #pragma unroll
    for (int j = 0; j < 64; j++) {
        float w = w1T[(j << 6) | lane];
        #pragma unroll
        for (int k = 0; k < O1NPW; k++)
            acc[k] = fmaf(rl(hl[k], j), w, acc[k]);
    }
    #pragma unroll
    for (int j = 0; j < 64; j++) {
        float w = w1T[((64 + j) << 6) | lane];
        #pragma unroll
        for (int k = 0; k < O1NPW; k++)
            acc[k] = fmaf(rl(gl[k], j), w, acc[k]);
    }
    #pragma unroll
    for (int k = 0; k < O1NPW; k++)
        z1[((n0 + k) << 6) | lane] = acc[k];
}

// head GEMV 2: 8 nodes/wave
__global__ void __launch_bounds__(256) k_o2(
        const float* __restrict__ o1v, const float* __restrict__ w2T2,
        const float* __restrict__ b2, float* __restrict__ z2) {
    int lane = threadIdx.x & 63;
    int ho = lane & 31;
    int wv = (blockIdx.x * 256 + (int)threadIdx.x) >> 6;
    int n0 = __builtin_amdgcn_readfirstlane(wv * 8);
    if (n0 >= NN) return;
    float xr[8], acc[4];
    #pragma unroll
    for (int k = 0; k < 8; k++) {
        int n = n0 + k; if (n >= NN) n = NN - 1;
        xr[k] = o1v[(n << 6) | lane];
    }
    float bl = b2[ho];
    #pragma unroll
    for (int k = 0; k < 4; k++) acc[k] = bl;
    #pragma unroll
    for (int j = 0; j < 64; j++) {
        float w = w2T2[(j << 5) | ho];
        #pragma unroll
        for (int k = 0; k < 4; k++) {
            float slo = rl(xr[k], j);
            float shi = rl(xr[4 + k], j);
            float v = (lane < 32) ? slo : shi;
            acc[k] = fmaf(v, w, acc[k]);
        }
    }
    int nbase = n0 + ((lane >> 5) << 2);
    #pragma unroll
    for (int k = 0; k < 4; k++)
        if (nbase + k < NN) z2[((nbase + k) << 5) | ho] = acc[k];
}

// head GEMV 3: 4 nodes per wave per jo-half
__global__ void __launch_bounds__(256) k_o3(
        const float* __restrict__ o2v, const float* __restrict__ w3T,
        const float* __restrict__ b3, float* __restrict__ outp) {
    int lane = threadIdx.x & 63;
    int wv = (blockIdx.x * 256 + (int)threadIdx.x) >> 6;
    int n0 = __builtin_amdgcn_readfirstlane((wv >> 1) << 2);
    int jo = (((wv & 1) << 6) + lane);
    if (n0 >= NN) return;
    float zl[4], acc[4];
    float bl = b3[jo];
    #pragma unroll
    for (int k = 0; k < 4; k++) {
        zl[k] = o2v[((n0 + k) << 5) | (lane & 31)];
        acc[k] = bl;
    }
    #pragma unroll
    for (int j = 0; j < 32; j++) {
        float w = w3T[(j << 7) | jo];
        #pragma unroll
        for (int k = 0; k < 4; k++)
            acc[k] = fmaf(rl(zl[k], j), w, acc[k]);
    }
    #pragma unroll
    for (int k = 0; k < 4; k++) {
        int n = n0 + k;
        size_t dsti = (jo < 64) ? ((size_t)(n << 6) + jo)
                                : ((size_t)NN * 64 + (size_t)(n << 6) + (jo - 64));
        outp[dsti] = acc[k];                             // f32 output
    }
}

extern "C" void kernel_launch(void* const* d_in, const int* in_sizes, int n_in,
                              void* d_out, int out_size, void* d_ws, size_t ws_size,
                              hipStream_t stream) {
    const float* x        = (const float*)d_in[0];
    const int* node_type  = (const int*)d_in[1];
    const int* edge_type  = (const int*)d_in[2];
    const int* edge_index = (const int*)d_in[3];
    const int* batch      = (const int*)d_in[4];
    const float* node_emb = (const float*)d_in[5];
    const float* edge_emb = (const float*)d_in[6];
    const float* w_d1 = (const float*)d_in[7];  const float* b_d1 = (const float*)d_in[8];
    const float* g_d1 = (const float*)d_in[9];  const float* be_d1 = (const float*)d_in[10];
    const float* w_d2 = (const float*)d_in[11]; const float* b_d2 = (const float*)d_in[12];
    const float* g_d2 = (const float*)d_in[13]; const float* be_d2 = (const float*)d_in[14];
    const float* g_c1 = (const float*)d_in[15]; const float* be_c1 = (const float*)d_in[16];
    const float* g_c2 = (const float*)d_in[17]; const float* be_c2 = (const float*)d_in[18];
    const float* g_c3 = (const float*)d_in[19]; const float* be_c3 = (const float*)d_in[20];
    const float* w_o1 = (const float*)d_in[21]; const float* b_o1 = (const float*)d_in[22];
    const float* g_o1 = (const float*)d_in[23]; const float* be_o1 = (const float*)d_in[24];
    const float* w_o2 = (const float*)d_in[25]; const float* b_o2 = (const float*)d_in[26];
    const float* g_o2 = (const float*)d_in[27]; const float* be_o2 = (const float*)d_in[28];
    const float* w_o3 = (const float*)d_in[29]; const float* b_o3 = (const float*)d_in[30];
    (void)b_d1;  // cancels inside BN1 (mean subtraction removes per-feature shift)
    const int* src  = edge_index;
    const int* dstv = edge_index + EE;

    char* ws = (char*)d_ws;
    int4*  esd     = (int4*)(ws + OFF_ESD);
    int*   row_ptr = (int*)(ws + OFF_ROWP);
    float* hA   = (float*)(ws + OFF_HA);
    float* hB   = (float*)(ws + OFF_HB);
    float* zb   = (float*)(ws + OFF_ZB);
    int4*  esd_tmp = (int4*)(ws + OFF_HA);   // aliases hA..hB (live only before k_locsort done)
    int*   hpart = (int*)(ws + OFF_HPART);   // dedicated (coexists with esd_tmp)
    int*   T    = (int*)(ws + OFF_TMAT);     // aliases zb (live only before k_binhist done)
    int*   tot  = (int*)(ws + OFF_TOT);
    int*   bbase= (int*)(ws + OFF_BBASE);
    float* ytab = (float*)(ws + OFF_YTAB);
    u32*   ptab = (u32*)(ws + OFF_PTAB);
    float* w2T  = (float*)(ws + OFF_W2T);
    float* b2f  = (float*)(ws + OFF_B2F);
    float* w1T  = (float*)(ws + OFF_W1T);
    float* w2T2 = (float*)(ws + OFF_W2O);
    float* w3T  = (float*)(ws + OFF_W3T);
    int*   bptr = (int*)(ws + OFF_BPTR);
    float* hg     = (float*)(ws + OFF_HG);
    double* xstat = (double*)(ws + OFF_XSTAT);
    double* sty   = (double*)(ws + OFF_STY);
    double* fst   = (double*)(ws + OFF_FST);
    double* st0 = fst;          double* st1 = fst + 128;  double* st2 = fst + 256;
    double* st3 = fst + 384;    double* st4 = fst + 512;

    hipMemsetAsync(ws + OFF_HG, 0, ZERO_BYTES, stream);

    // merged prep: weights transpose | xstats | bptr | bincnt
    k_prep0<<<1036, 256, 0, stream>>>(w_d2, b_d2, w_o1, w_o2, w_o3, x, batch, dstv,
                                      w2T, b2f, w1T, w2T2, w3T, xstat, bptr, T);
    k_bscanA<<<NBKT, 256, 0, stream>>>(T, tot);
    // merged: bucket scatter (with in-LDS bbase scan) | x histogram (concurrent)
    k_binhist<<<NB1 + HBLK, 1024, 0, stream>>>(x, src, dstv, edge_type, T, tot,
                                               bbase, esd_tmp, hpart);
    k_locsort<<<NBKT, 256, 0, stream>>>(esd_tmp, bbase, row_ptr, esd);
    // fused knot table + BN2 moments; then pack (LOG2E pre-scaled)
    k_ytmom<<<128, 256, 0, stream>>>(xstat, w_d1, g_d1, be_d1, w2T, b2f, hpart, ytab, sty);
    k_ypack<<<NTB * 64 / 256, 256, 0, stream>>>(ytab, sty, g_d2, be_d2, ptab);
    // gconv 1 (h from node_emb[node_type], L1-resident)
    k_agg0<<<25000, 128, 0, stream>>>(node_type, node_emb, esd, row_ptr, ptab, edge_emb, hB);
    k_fstats<<<1024, 256, 0, stream>>>(hB, NN, 6, st0);
    k_bn<<<12500, 256, 0, stream>>>(hB, hB, st0, g_c1, be_c1, NN, 6, 1);
    // gconv 2
    k_agg<<<25000, 128, 0, stream>>>(hB, esd, row_ptr, ptab, edge_emb, hA);
    k_fstats<<<1024, 256, 0, stream>>>(hA, NN, 6, st1);
    k_bn<<<12500, 256, 0, stream>>>(hA, hA, st1, g_c2, be_c2, NN, 6, 1);
    // gconv 3 (no activation)
    k_agg<<<25000, 128, 0, stream>>>(hA, esd, row_ptr, ptab, edge_emb, hB);
    k_fstats<<<1024, 256, 0, stream>>>(hB, NN, 6, st2);
    k_bn<<<12500, 256, 0, stream>>>(hB, hB, st2, g_c3, be_c3, NN, 6, 0);
    // global pool + head
    k_hg2<<<BB, 256, 0, stream>>>(hB, bptr, hg);
    k_o1<<<3125, 256, 0, stream>>>(hB, hg, batch, w1T, b_o1, hA);
    k_fstats<<<1024, 256, 0, stream>>>(hA, NN, 6, st3);
    k_bn<<<12500, 256, 0, stream>>>(hA, hA, st3, g_o1, be_o1, NN, 6, 1);
    k_o2<<<1563, 256, 0, stream>>>(hA, w2T2, b_o2, zb);
    k_fstats<<<1024, 256, 0, stream>>>(zb, NN, 5, st4);
    k_bn<<<6250, 256, 0, stream>>>(zb, zb, st4, g_o2, be_o2, NN, 5, 1);
    k_o3<<<6250, 256, 0, stream>>>(zb, w3T, b_o3, (float*)d_out);
    (void)in_sizes; (void)n_in; (void)out_size; (void)ws_size;
}

// Round 10
// 563.167 us; speedup vs baseline: 1.5201x; 1.1818x over previous
//
#include <hip/hip_runtime.h>
#include <stdint.h>

#define NN 50000
#define EE 1250000
#define BB 500
#define BN_EPS 1e-5f
#define LOG2E 1.44269504f
#define LN2 0.69314718f

// two-level multisplit: 391 buckets of 128 nodes + per-bucket local sort
#define NBKT 391
#define NPBSH 7
#define NB1 256       // binning blocks
#define BPB 4883      // edges per binning block (256*4883 >= EE)

// x-histogram for BN2 moments (merged into binscat launch; dedicated hpart region)
#define HBLK 88
#define HEPB ((EE + HBLK - 1) / HBLK)   // 14205 edges per hist block
#define FHSC 65536.f                     // fixed-point scale for f, f^2 partials
#define FHIN (1.f / 65536.f)

// fused-stats spread slots (f32 atomics, 16-way address spreading)
#define NSL 16

#define NTB 8192      // table intervals; 8193 knots
#define XLO (-12.0f)
#define XHI (12.0f)
#define XSC ((float)NTB / (XHI - XLO))
#define DXT ((XHI - XLO) / (float)NTB)
#define TPMAX 8191.999f

using u16 = unsigned short;
using u32 = unsigned int;

__device__ __forceinline__ u16 f2bf(float f) {
    u32 u = __float_as_uint(f);
    return (u16)((u + 0x7fffu + ((u >> 16) & 1u)) >> 16);
}
__device__ __forceinline__ u32 pk2(float a, float b) { return (u32)f2bf(a) | ((u32)f2bf(b) << 16); }
// softplus via native v_exp_f32 / v_log_f32
__device__ __forceinline__ float sp(float z) {
    float t = __builtin_amdgcn_exp2f(-fabsf(z) * LOG2E);
    float l = __builtin_amdgcn_logf(1.f + t) * LN2;
    return fmaxf(z, 0.f) + l;
}
// guaranteed v_readlane (VALU)
__device__ __forceinline__ float rl(float v, int l) {
    return __uint_as_float(__builtin_amdgcn_readlane(__float_as_uint(v), l));
}

// ---------------- workspace layout (~65 MB) ----------------
constexpr size_t OFF_ESD  = 0;                                    // int4 [E] {src, et, i, f_bits}
constexpr size_t OFF_ROWP = OFF_ESD + (size_t)EE * 16;            // row_ptr [N+1]
constexpr size_t OFF_HA   = (OFF_ROWP + (size_t)(NN + 1) * 4 + 255) & ~(size_t)255;
constexpr size_t OFF_HB   = OFF_HA + (size_t)NN * 64 * 4;
// esd_tmp (20 MB) aliases hA..hB: live only before k_locyt
constexpr size_t OFF_ZB   = OFF_HB + (size_t)NN * 64 * 4;         // [N,32]
// sort scratch aliases zb (dead before k_o2): T[NB1][NBKT], tot, bbase
constexpr size_t OFF_TMAT = OFF_ZB;
constexpr size_t OFF_TOT  = OFF_TMAT + (size_t)NB1 * NBKT * 4;
constexpr size_t OFF_BBASE= OFF_TOT + (size_t)NBKT * 4;
constexpr size_t OFF_YTAB = OFF_ZB + (size_t)NN * 32 * 4;         // f32 [NTB+1][64]
constexpr size_t OFF_PTAB = OFF_YTAB + (size_t)(NTB + 1) * 64 * 4;// u32 [NTB][64] bf16 (a, b-a), x LOG2E
constexpr size_t OFF_W2T  = OFF_PTAB + (size_t)NTB * 64 * 4;      // w_d2 transposed f32 [64][64]
constexpr size_t OFF_B2F  = OFF_W2T + 4096 * 4;
constexpr size_t OFF_W1T  = OFF_B2F + 256;                        // f32 [128][64] (w_o1^T)
constexpr size_t OFF_W2O  = OFF_W1T + 8192 * 4;                   // f32 [64][32]  (w_o2^T)
constexpr size_t OFF_W3T  = OFF_W2O + 2048 * 4;                   // f32 [32][128] (w_o3^T)
constexpr size_t OFF_BPTR = OFF_W3T + 4096 * 4;                   // int [B+1]
// zero region (one memset): hg | xstat | sty | 5 stat slot arrays (f32 [NSL][128] each)
constexpr size_t OFF_HG   = (OFF_BPTR + (BB + 1) * 4 + 255) & ~(size_t)255;
constexpr size_t OFF_XSTAT= OFF_HG + (size_t)BB * 64 * 4;         // 2 doubles
constexpr size_t OFF_STY  = OFF_XSTAT + 16;                       // 128 doubles
constexpr size_t OFF_FST  = OFF_STY + 128 * 8;                    // 5 * NSL * 128 floats
constexpr size_t ZERO_END = OFF_FST + 5 * NSL * 128 * 4;
constexpr size_t ZERO_BYTES = ZERO_END - OFF_HG;
// hpart: dedicated (coexists with esd_tmp during the merged binscat|hist launch)
constexpr size_t OFF_HPART= (ZERO_END + 255) & ~(size_t)255;      // int [HBLK][3][NTB] (~8.3 MB)

// ---------------- merged prep: w2prep | otprep | xstats | bptr | bincnt ----------------
__global__ void __launch_bounds__(256) k_prep0(
        const float* __restrict__ w2, const float* __restrict__ b2,
        const float* __restrict__ w1, const float* __restrict__ wo2, const float* __restrict__ w3,
        const float* __restrict__ x, const int* __restrict__ batch, const int* __restrict__ dstv,
        float* __restrict__ w2T, float* __restrict__ b2f,
        float* __restrict__ w1T, float* __restrict__ w2T2, float* __restrict__ w3T,
        double* __restrict__ xstat, int* __restrict__ bptr, int* __restrict__ T) {
    int bx = blockIdx.x, t = threadIdx.x;
    if (bx < 16) {
        int idx = bx * 256 + t;                          // 4096
        int hin = idx >> 6, ho = idx & 63;
        w2T[idx] = w2[ho * 64 + hin];
        if (idx < 64) b2f[idx] = b2[idx];
    } else if (bx < 72) {
        int idx = (bx - 16) * 256 + t;                   // 14336
        if (idx < 8192) {
            int j = idx >> 6, ho = idx & 63;
            w1T[idx] = w1[ho * 128 + j];
        } else if (idx < 8192 + 2048) {
            int q = idx - 8192;
            int j = q >> 5, ho = q & 31;
            w2T2[q] = wo2[ho * 64 + j];
        } else if (idx < 8192 + 2048 + 4096) {
            int q = idx - 8192 - 2048;
            int j = q >> 7, jo = q & 127;
            w3T[q] = w3[jo * 32 + j];
        }
    } else if (bx < 584) {
        __shared__ float ls[256], lq[256];
        float s = 0, q = 0;
        for (int i = (bx - 72) * 256 + t; i < EE; i += 512 * 256) {
            float v = x[i]; s += v; q += v * v;
        }
        ls[t] = s; lq[t] = q; __syncthreads();
        for (int off = 128; off > 0; off >>= 1) {
            if (t < off) { ls[t] += ls[t + off]; lq[t] += lq[t + off]; }
            __syncthreads();
        }
        if (t == 0) { atomicAdd(&xstat[0], (double)ls[0]); atomicAdd(&xstat[1], (double)lq[0]); }
    } else if (bx < 780) {
        int n = (bx - 584) * 256 + t;
        if (n >= NN) return;
        int b = batch[n];
        int pb = (n == 0) ? -1 : batch[n - 1];
        for (int k = pb + 1; k <= b; k++) bptr[k] = n;
        if (n == NN - 1) { for (int k = b + 1; k <= BB; k++) bptr[k] = NN; }
    } else {
        // bincnt: per-block LDS histogram over 391 coarse buckets
        __shared__ int hh[NBKT];
        for (int i = t; i < NBKT; i += 256) hh[i] = 0;
        __syncthreads();
        int bb = bx - 780;
        int e0 = bb * BPB;
        int e1 = e0 + BPB; if (e1 > EE) e1 = EE;
        for (int e = e0 + t; e < e1; e += 256)
            atomicAdd(&hh[dstv[e] >> NPBSH], 1);
        __syncthreads();
        for (int i = t; i < NBKT; i += 256)
            T[(size_t)bb * NBKT + i] = hh[i];
    }
}

// per-bucket exclusive scan over blocks (in-place), bucket totals out
__global__ void k_bscanA(int* __restrict__ T, int* __restrict__ tot) {
    __shared__ int ls[256];
    int b = blockIdx.x, t = threadIdx.x;
    int v = T[(size_t)t * NBKT + b];
    ls[t] = v; __syncthreads();
    for (int off = 1; off < 256; off <<= 1) {
        int a = ls[t]; int add = (t >= off) ? ls[t - off] : 0; __syncthreads();
        ls[t] = a + add; __syncthreads();
    }
    T[(size_t)t * NBKT + b] = ls[t] - v;
    if (t == 255) tot[b] = ls[255];
}

// ---------------- merged: chunked bucket scatter | x histogram ----------------
__global__ void __launch_bounds__(1024) k_binhist(
        const float* __restrict__ x, const int* __restrict__ src,
        const int* __restrict__ dstv, const int* __restrict__ etv,
        const int* __restrict__ T, const int* __restrict__ tot,
        int* __restrict__ bbase_g, int4* __restrict__ esd_tmp, int* __restrict__ hpart) {
    __shared__ int shb[3 * (NTB / 2)];                   // 48 KB, unioned across branches
    int t = threadIdx.x;
    if (blockIdx.x < NB1) {
        int* cur = shb;                                  // [NBKT]
        int* sls = shb + 512;                            // [512] scan buffer
        int v = 0;
        if (t < 512) { v = (t < NBKT) ? tot[t] : 0; sls[t] = v; }
        __syncthreads();
        for (int off = 1; off < 512; off <<= 1) {
            int a = 0;
            if (t < 512) { a = sls[t]; if (t >= off) a += sls[t - off]; }
            __syncthreads();
            if (t < 512) sls[t] = a;
            __syncthreads();
        }
        if (t < NBKT) {
            int base = sls[t] - v;                       // exclusive
            cur[t] = base + T[(size_t)blockIdx.x * NBKT + t];
            if (blockIdx.x == 0) bbase_g[t] = base;
        }
        if (blockIdx.x == 0 && t == 0) bbase_g[NBKT] = EE;
        __syncthreads();
        int e0 = blockIdx.x * BPB;
        int e1 = e0 + BPB; if (e1 > EE) e1 = EE;
        for (int e = e0 + t; e < e1; e += 1024) {
            int d = dstv[e];
            int p = atomicAdd(&cur[d >> NPBSH], 1);
            float tp = fminf(fmaxf((x[e] - XLO) * XSC, 0.f), TPMAX);
            int i = (int)tp; float f = tp - (float)i;
            // local dst (7 bits) rides in spare bits of et (et < 128)
            int4 vv; vv.x = src[e]; vv.y = etv[e] | ((d & 127) << 7); vv.z = i; vv.w = __float_as_int(f);
            esd_tmp[p] = vv;
        }
    } else {
        int* cnt = shb; int* sf = shb + NTB / 2; int* sf2 = shb + NTB;
        int bb = blockIdx.x - NB1;
        int e0 = bb * HEPB;
        int e1 = e0 + HEPB; if (e1 > EE) e1 = EE;
        int* outp = hpart + (size_t)bb * 3 * NTB;
        for (int half = 0; half < 2; half++) {
            for (int i = t; i < NTB / 2; i += 1024) { cnt[i] = 0; sf[i] = 0; sf2[i] = 0; }
            __syncthreads();
            int lo = half * (NTB / 2);
            for (int e = e0 + t; e < e1; e += 1024) {
                float tp = fminf(fmaxf((x[e] - XLO) * XSC, 0.f), TPMAX);
                int i = (int)tp;
                int li = i - lo;
                if ((unsigned)li < (unsigned)(NTB / 2)) {
                    float f = tp - (float)i;
                    atomicAdd(&cnt[li], 1);
                    atomicAdd(&sf[li], (int)(f * FHSC));
                    atomicAdd(&sf2[li], (int)(f * f * FHSC));
                }
            }
            __syncthreads();
            for (int i = t; i < NTB / 2; i += 1024) {
                outp[lo + i] = cnt[i];
                outp[NTB + lo + i] = sf[i];
                outp[2 * NTB + lo + i] = sf2[i];
            }
            __syncthreads();
        }
    }
}

// ---------------- merged: per-bucket local sort | fused knot table + BN2 moments ----------
// blocks [0,NBKT): locsort (emits row_ptr). blocks [NBKT,NBKT+128): ytmom.
__global__ void __launch_bounds__(256) k_locyt(
        const int4* __restrict__ esd_tmp, const int* __restrict__ bbase,
        int* __restrict__ row_ptr, int4* __restrict__ esd,
        const double* __restrict__ xstat, const float* __restrict__ w_d1,
        const float* __restrict__ g_d1, const float* __restrict__ be_d1,
        const float* __restrict__ w2T, const float* __restrict__ b2f,
        const int* __restrict__ hpart, float* __restrict__ ytab, double* __restrict__ sty) {
    __shared__ char shraw[65 * 64 * 4 + 192 * 4];        // 17.4 KB union
    int t = threadIdx.x;
    if (blockIdx.x < NBKT) {
        int* hist = (int*)shraw;
        int* ls   = hist + 128;
        int* cur  = ls + 128;
        int b = blockIdx.x;
        if (b == 0 && t == 0) row_ptr[NN] = EE;
        int base = bbase[b], end = bbase[b + 1];
        if (t < 128) hist[t] = 0;
        __syncthreads();
        for (int p = base + t; p < end; p += 256)
            atomicAdd(&hist[(esd_tmp[p].y >> 7) & 127], 1);
        __syncthreads();
        int v = 0;
        if (t < 128) { v = hist[t]; ls[t] = v; }
        __syncthreads();
        for (int off = 1; off < 128; off <<= 1) {
            int a = 0;
            if (t < 128) { a = ls[t]; if (t >= off) a += ls[t - off]; }
            __syncthreads();
            if (t < 128) ls[t] = a;
            __syncthreads();
        }
        if (t < 128) {
            int exc = ls[t] - v;
            cur[t] = base + exc;
            int n = (b << NPBSH) + t;
            if (n < NN) row_ptr[n] = base + exc;
        }
        __syncthreads();
        for (int p = base + t; p < end; p += 256) {
            int4 r = esd_tmp[p];
            int ld = (r.y >> 7) & 127;
            r.y &= 127;
            esd[atomicAdd(&cur[ld], 1)] = r;
        }
    } else {
        float (*kn)[64] = (float(*)[64])shraw;
        float* hs = (float*)(shraw + 65 * 64 * 4);
        int lane = t & 63, w = t >> 6;
        int g = blockIdx.x - NBKT;                       // 0..127
        double inv = 1.0 / (double)EE;
        double mx = xstat[0] * inv;
        double vx = xstat[1] * inv - mx * mx; if (vx < 0) vx = 0;
        float wd = w_d1[lane];
        float Aw = wd * rsqrtf((float)vx * wd * wd + BN_EPS) * g_d1[lane];
        float Cw = be_d1[lane];
        for (int kk = w; kk < 65; kk += 4) {
            int idx = (g << 6) + kk;
            float xi = XLO + (float)idx * DXT;
            float tt = xi - (float)mx;
            float d1L = sp(fmaf(Aw, tt, Cw));
            float y = b2f[lane];
            #pragma unroll
            for (int hin = 0; hin < 64; hin++)
                y = fmaf(rl(d1L, hin), w2T[hin * 64 + lane], y);
            kn[kk][lane] = y;
            if (kk < 64 || g == 127) ytab[(idx << 6) | lane] = y;
        }
        if (t < 192) {                                   // hsum: c|f1|f2 for this block's 64 bins
            int slot = t >> 6, ii = t & 63;
            float s = 0.f;
            size_t off = (size_t)slot * NTB + (g << 6) + ii;
            for (int b = 0; b < HBLK; b++)
                s += (float)hpart[(size_t)b * 3 * NTB + off];
            hs[t] = (slot == 0) ? s : s * FHIN;
        }
        __syncthreads();
        if (t >= 64) return;                             // one wave: moment math
        double S = 0.0, Q = 0.0;
        float aprev = kn[0][lane];
        for (int ii = 0; ii < 64; ii++) {
            float c = hs[ii], f1 = hs[64 + ii], f2 = hs[128 + ii];
            float b = kn[ii + 1][lane];
            float a = aprev; aprev = b;
            float d = b - a;
            S += (double)(fmaf(c, a, d * f1));
            Q += (double)(fmaf(c * a, a, fmaf(2.f * a * d, f1, d * d * f2)));
        }
        atomicAdd(&sty[lane], S);
        atomicAdd(&sty[64 + lane], Q);
    }
}

// pack bn2-affined table as bf16 (a, b-a) pairs, pre-scaled by LOG2E (log2-domain agg)
__global__ void k_ypack(const float* __restrict__ ytab, const double* __restrict__ sty,
                        const float* __restrict__ g2, const float* __restrict__ be2,
                        u32* __restrict__ ptab) {
    int tid = blockIdx.x * 256 + threadIdx.x;            // NTB*64
    int f = tid & 63;
    double inv = 1.0 / (double)EE;
    double m = sty[f] * inv;
    double var = sty[64 + f] * inv - m * m; if (var < 0) var = 0;
    float rstd = rsqrtf((float)var + BN_EPS);
    float sc0 = rstd * g2[f];
    float sc = sc0 * LOG2E;
    float sh = (be2[f] - (float)m * sc0) * LOG2E;
    float a = fmaf(ytab[tid], sc, sh);
    float b = fmaf(ytab[tid + 64], sc, sh);
    ptab[tid] = pk2(a, b - a);
}

// per-edge term (log2-scaled): one fmaf lerp + emb mul
__device__ __forceinline__ float edge_term(int4 ed, int lane, const u32* __restrict__ ptab,
                                           const float* __restrict__ emb) {
    u32 pr = ptab[(ed.z << 6) | lane];
    float f = __int_as_float(ed.w);
    float a = __uint_as_float(pr << 16);
    float d = __uint_as_float(pr & 0xffff0000u);
    float y = fmaf(f, d, a);
    return y * emb[(ed.y << 6) | lane];
}
// log2-domain softplus accumulate
__device__ __forceinline__ void sp2(float hv, float av, float& accm, float& accl) {
    float z = fmaf(hv, LOG2E, av);
    float t = __builtin_amdgcn_exp2f(-fabsf(z));
    accm += fmaxf(z, 0.f);
    accl += __builtin_amdgcn_logf(1.f + t);
}

// wave-per-node aggregation; 128-thr blocks (2 nodes); fused per-feature stats
// (LDS reduce over 2 nodes, then 2 f32 atomics/lane into NSL spread slots)
__global__ void __launch_bounds__(128) k_agg(
        const float* __restrict__ h, const int4* __restrict__ esd, const int* __restrict__ row_ptr,
        const u32* __restrict__ ptab, const float* __restrict__ emb, float* __restrict__ hpre,
        float* __restrict__ stat) {
    int lane = threadIdx.x & 63;
    int w = threadIdx.x >> 6;
    int n = __builtin_amdgcn_readfirstlane((int)((blockIdx.x << 1) | w));
    int p0 = row_ptr[n], p1 = row_ptr[n + 1];
    float accm = 0.f, accl = 0.f;
    int p = p0;
    for (; p + 4 <= p1; p += 4) {
        int4 e0 = esd[p], e1 = esd[p + 1], e2 = esd[p + 2], e3 = esd[p + 3];
        float h0 = h[(e0.x << 6) | lane];
        float h1 = h[(e1.x << 6) | lane];
        float h2 = h[(e2.x << 6) | lane];
        float h3 = h[(e3.x << 6) | lane];
        float a0 = edge_term(e0, lane, ptab, emb);
        float a1 = edge_term(e1, lane, ptab, emb);
        float a2 = edge_term(e2, lane, ptab, emb);
        float a3 = edge_term(e3, lane, ptab, emb);
        sp2(h0, a0, accm, accl);
        sp2(h1, a1, accm, accl);
        sp2(h2, a2, accm, accl);
        sp2(h3, a3, accm, accl);
    }
    for (; p < p1; ++p) {
        int4 e0 = esd[p];
        float h0 = h[(e0.x << 6) | lane];
        sp2(h0, edge_term(e0, lane, ptab, emb), accm, accl);
    }
    int o = (n << 6) | lane;
    float val = fmaf(accm + accl, LN2, h[o]);
    hpre[o] = val;
    __shared__ float lsS[2][64], lsQ[2][64];
    lsS[w][lane] = val; lsQ[w][lane] = val * val;
    __syncthreads();
    if (w == 0) {
        int sl = ((int)blockIdx.x & (NSL - 1)) << 7;
        atomicAdd(&stat[sl + lane], lsS[0][lane] + lsS[1][lane]);
        atomicAdd(&stat[sl + 64 + lane], lsQ[0][lane] + lsQ[1][lane]);
    }
}

// gconv1 variant: h comes from node_emb[node_type] (L1-resident); fused stats
__global__ void __launch_bounds__(128) k_agg0(
        const int* __restrict__ nt, const float* __restrict__ nemb, const int4* __restrict__ esd,
        const int* __restrict__ row_ptr, const u32* __restrict__ ptab,
        const float* __restrict__ emb, float* __restrict__ hpre, float* __restrict__ stat) {
    int lane = threadIdx.x & 63;
    int w = threadIdx.x >> 6;
    int n = __builtin_amdgcn_readfirstlane((int)((blockIdx.x << 1) | w));
    int p0 = row_ptr[n], p1 = row_ptr[n + 1];
    float accm = 0.f, accl = 0.f;
    int p = p0;
    for (; p + 4 <= p1; p += 4) {
        int4 e0 = esd[p], e1 = esd[p + 1], e2 = esd[p + 2], e3 = esd[p + 3];
        float h0 = nemb[(nt[e0.x] << 6) | lane];
        float h1 = nemb[(nt[e1.x] << 6) | lane];
        float h2 = nemb[(nt[e2.x] << 6) | lane];
        float h3 = nemb[(nt[e3.x] << 6) | lane];
        float a0 = edge_term(e0, lane, ptab, emb);
        float a1 = edge_term(e1, lane, ptab, emb);
        float a2 = edge_term(e2, lane, ptab, emb);
        float a3 = edge_term(e3, lane, ptab, emb);
        sp2(h0, a0, accm, accl);
        sp2(h1, a1, accm, accl);
        sp2(h2, a2, accm, accl);
        sp2(h3, a3, accm, accl);
    }
    for (; p < p1; ++p) {
        int4 e0 = esd[p];
        float h0 = nemb[(nt[e0.x] << 6) | lane];
        sp2(h0, edge_term(e0, lane, ptab, emb), accm, accl);
    }
    float val = fmaf(accm + accl, LN2, nemb[(nt[n] << 6) | lane]);
    hpre[(n << 6) | lane] = val;
    __shared__ float lsS[2][64], lsQ[2][64];
    lsS[w][lane] = val; lsQ[w][lane] = val * val;
    __syncthreads();
    if (w == 0) {
        int sl = ((int)blockIdx.x & (NSL - 1)) << 7;
        atomicAdd(&stat[sl + lane], lsS[0][lane] + lsS[1][lane]);
        atomicAdd(&stat[sl + 64 + lane], lsQ[0][lane] + lsQ[1][lane]);
    }
}

// BN apply: preamble reduces the NSL spread slots; per-block f32 scale/shift hoist
__global__ void __launch_bounds__(256) k_bn(
        const float* __restrict__ in, float* __restrict__ out,
        const float* __restrict__ stat, const float* __restrict__ g,
        const float* __restrict__ be, int rows, int logC, int act) {
    int C = 1 << logC;
    __shared__ float scl[64], shl[64];
    int t = threadIdx.x;
    if (t < C) {
        float s = 0.f, q = 0.f;
        #pragma unroll
        for (int sl = 0; sl < NSL; sl++) {
            s += stat[(sl << 7) + t];
            q += stat[(sl << 7) + 64 + t];
        }
        float inv = 1.f / (float)rows;
        float m = s * inv;
        float var = q * inv - m * m; if (var < 0.f) var = 0.f;
        float rstd = rsqrtf(var + BN_EPS);
        float sc = rstd * g[t];
        scl[t] = sc; shl[t] = be[t] - m * sc;
    }
    __syncthreads();
    size_t total = (size_t)rows << logC;
    size_t i = (size_t)blockIdx.x * 256 + t;
    if (i >= total) return;
    int f = (int)(i & (C - 1));
    float val = fmaf(in[i], scl[f], shl[f]);
    out[i] = act ? sp(val) : val;
}

// global pooling: block-per-batch segment sum over sorted batch (no atomics)
__global__ void __launch_bounds__(256) k_hg2(
        const float* __restrict__ h, const int* __restrict__ bptr, float* __restrict__ hg) {
    int b = blockIdx.x;                                  // BB
    int lane = threadIdx.x & 63, w = threadIdx.x >> 6;
    int n0 = bptr[b], n1 = bptr[b + 1];
    float acc = 0.f;
    for (int n = n0 + w; n < n1; n += 4)
        acc += h[(n << 6) | lane];
    __shared__ float ls[256];
    ls[threadIdx.x] = acc; __syncthreads();
    if (threadIdx.x < 64)
        hg[(b << 6) | lane] = ls[lane] + ls[64 + lane] + ls[128 + lane] + ls[192 + lane];
}

// head GEMV 1: 4 nodes/wave; fused stats
#define O1NPW 4
__global__ void __launch_bounds__(256) k_o1(
        const float* __restrict__ h, const float* __restrict__ hg, const int* __restrict__ batch,
        const float* __restrict__ w1T, const float* __restrict__ b1, float* __restrict__ z1,
        float* __restrict__ stat) {
    int lane = threadIdx.x & 63;
    int wv = (blockIdx.x * 256 + (int)threadIdx.x) >> 6;
    int n0 = __builtin_amdgcn_readfirstlane(wv * O1NPW);  // grid exact: 3125*4 waves = 50000 nodes
    float hl[O1NPW], gl[O1NPW], acc[O1NPW];
    float bl = b1[lane];
    #pragma unroll
    for (int k = 0; k < O1NPW; k++) {
        int n = n0 + k;
        hl[k] = h[(n << 6) | lane];
        gl[k] = hg[(batch[n] << 6) | lane];
        acc[k] = bl;
    }
    #pragma unroll
    for (int j = 0; j < 64; j++) {
        float w = w1T[(j << 6) | lane];
        #pragma unroll
        for (int k = 0; k < O1NPW; k++)
            acc[k] = fmaf(rl(hl[k], j), w, acc[k]);
    }
    #pragma unroll
    for (int j = 0; j < 64; j++) {
        float w = w1T[((64 + j) << 6) | lane];
        #pragma unroll
        for (int k = 0; k < O1NPW; k++)
            acc[k] = fmaf(rl(gl[k], j), w, acc[k]);
    }
    float s = 0.f, q = 0.f;
    #pragma unroll
    for (int k = 0; k < O1NPW; k++) {
        z1[((n0 + k) << 6) | lane] = acc[k];
        s += acc[k]; q += acc[k] * acc[k];
    }
    __shared__ float lsS[4][64], lsQ[4][64];
    int w = threadIdx.x >> 6;
    lsS[w][lane] = s; lsQ[w][lane] = q; __syncthreads();
    if (threadIdx.x < 128) {
        int f = threadIdx.x & 63; bool isq = threadIdx.x >= 64;
        float r = 0.f;
        #pragma unroll
        for (int j = 0; j < 4; j++) r += isq ? lsQ[j][f] : lsS[j][f];
        int sl = ((int)blockIdx.x & (NSL - 1)) << 7;
        atomicAdd(&stat[sl + (isq ? 64 : 0) + f], r);
    }
}

// head GEMV 2: 8 nodes/wave; fused stats (C=32: s at [f], q at [64+f])
__global__ void __launch_bounds__(256) k_o2(
        const float* __restrict__ o1v, const float* __restrict__ w2T2,
        const float* __restrict__ b2, float* __restrict__ z2, float* __restrict__ stat) {
    int lane = threadIdx.x & 63;
    int ho = lane & 31;
    int wv = (blockIdx.x * 256 + (int)threadIdx.x) >> 6;
    int n0 = __builtin_amdgcn_readfirstlane(wv * 8);
    float xr[8], acc[4];
    #pragma unroll
    for (int k = 0; k < 8; k++) {
        int n = n0 + k; if (n >= NN) n = NN - 1;
        xr[k] = o1v[(n << 6) | lane];
    }
    float bl = b2[ho];
    #pragma unroll
    for (int k = 0; k < 4; k++) acc[k] = bl;
    #pragma unroll
    for (int j = 0; j < 64; j++) {
        float w = w2T2[(j << 5) | ho];
        #pragma unroll
        for (int k = 0; k < 4; k++) {
            float slo = rl(xr[k], j);
            float shi = rl(xr[4 + k], j);
            float v = (lane < 32) ? slo : shi;
            acc[k] = fmaf(v, w, acc[k]);
        }
    }
    int nbase = n0 + ((lane >> 5) << 2);
    float s = 0.f, q = 0.f;
    #pragma unroll
    for (int k = 0; k < 4; k++) {
        if (nbase + k < NN) {
            z2[((nbase + k) << 5) | ho] = acc[k];
            s += acc[k]; q += acc[k] * acc[k];
        }
    }
    __shared__ float lsS[4][64], lsQ[4][64];
    int w = threadIdx.x >> 6;
    lsS[w][lane] = s; lsQ[w][lane] = q; __syncthreads();
    if (threadIdx.x < 64) {
        int f = threadIdx.x & 31; bool isq = threadIdx.x >= 32;
        float r = 0.f;
        #pragma unroll
        for (int j = 0; j < 4; j++)
            r += isq ? (lsQ[j][f] + lsQ[j][32 + f]) : (lsS[j][f] + lsS[j][32 + f]);
        int sl = ((int)blockIdx.x & (NSL - 1)) << 7;
        atomicAdd(&stat[sl + (isq ? 64 : 0) + f], r);
    }
}

// head GEMV 3: 4 nodes per wave per jo-half
__global__ void __launch_bounds__(256) k_o3(
        const float* __restrict__ o2v, const float* __restrict__ w3T,
        const float* __restrict__ b3, float* __restrict__ outp) {
    int lane = threadIdx.x & 63;
    int wv = (blockIdx.x * 256 + (int)threadIdx.x) >> 6;
    int n0 = __builtin_amdgcn_readfirstlane((wv >> 1) << 2);
    int jo = (((wv & 1) << 6) + lane);
    if (n0 >= NN) return;
    float zl[4], acc[4];
    float bl = b3[jo];
    #pragma unroll
    for (int k = 0; k < 4; k++) {
        zl[k] = o2v[((n0 + k) << 5) | (lane & 31)];
        acc[k] = bl;
    }
    #pragma unroll
    for (int j = 0; j < 32; j++) {
        float w = w3T[(j << 7) | jo];
        #pragma unroll
        for (int k = 0; k < 4; k++)
            acc[k] = fmaf(rl(zl[k], j), w, acc[k]);
    }
    #pragma unroll
    for (int k = 0; k < 4; k++) {
        int n = n0 + k;
        size_t dsti = (jo < 64) ? ((size_t)(n << 6) + jo)
                                : ((size_t)NN * 64 + (size_t)(n << 6) + (jo - 64));
        outp[dsti] = acc[k];                             // f32 output
    }
}

extern "C" void kernel_launch(void* const* d_in, const int* in_sizes, int n_in,
                              void* d_out, int out_size, void* d_ws, size_t ws_size,
                              hipStream_t stream) {
    const float* x        = (const float*)d_in[0];
    const int* node_type  = (const int*)d_in[1];
    const int* edge_type  = (const int*)d_in[2];
    const int* edge_index = (const int*)d_in[3];
    const int* batch      = (const int*)d_in[4];
    const float* node_emb = (const float*)d_in[5];
    const float* edge_emb = (const float*)d_in[6];
    const float* w_d1 = (const float*)d_in[7];  const float* b_d1 = (const float*)d_in[8];
    const float* g_d1 = (const float*)d_in[9];  const float* be_d1 = (const float*)d_in[10];
    const float* w_d2 = (const float*)d_in[11]; const float* b_d2 = (const float*)d_in[12];
    const float* g_d2 = (const float*)d_in[13]; const float* be_d2 = (const float*)d_in[14];
    const float* g_c1 = (const float*)d_in[15]; const float* be_c1 = (const float*)d_in[16];
    const float* g_c2 = (const float*)d_in[17]; const float* be_c2 = (const float*)d_in[18];
    const float* g_c3 = (const float*)d_in[19]; const float* be_c3 = (const float*)d_in[20];
    const float* w_o1 = (const float*)d_in[21]; const float* b_o1 = (const float*)d_in[22];
    const float* g_o1 = (const float*)d_in[23]; const float* be_o1 = (const float*)d_in[24];
    const float* w_o2 = (const float*)d_in[25]; const float* b_o2 = (const float*)d_in[26];
    const float* g_o2 = (const float*)d_in[27]; const float* be_o2 = (const float*)d_in[28];
    const float* w_o3 = (const float*)d_in[29]; const float* b_o3 = (const float*)d_in[30];
    (void)b_d1;  // cancels inside BN1 (mean subtraction removes per-feature shift)
    const int* src  = edge_index;
    const int* dstv = edge_index + EE;

    char* ws = (char*)d_ws;
    int4*  esd     = (int4*)(ws + OFF_ESD);
    int*   row_ptr = (int*)(ws + OFF_ROWP);
    float* hA   = (float*)(ws + OFF_HA);
    float* hB   = (float*)(ws + OFF_HB);
    float* zb   = (float*)(ws + OFF_ZB);
    int4*  esd_tmp = (int4*)(ws + OFF_HA);   // aliases hA..hB (live only before k_locyt done)
    int*   hpart = (int*)(ws + OFF_HPART);   // dedicated (coexists with esd_tmp)
    int*   T    = (int*)(ws + OFF_TMAT);     // aliases zb (live only before k_binhist done)
    int*   tot  = (int*)(ws + OFF_TOT);
    int*   bbase= (int*)(ws + OFF_BBASE);
    float* ytab = (float*)(ws + OFF_YTAB);
    u32*   ptab = (u32*)(ws + OFF_PTAB);
    float* w2T  = (float*)(ws + OFF_W2T);
    float* b2f  = (float*)(ws + OFF_B2F);
    float* w1T  = (float*)(ws + OFF_W1T);
    float* w2T2 = (float*)(ws + OFF_W2O);
    float* w3T  = (float*)(ws + OFF_W3T);
    int*   bptr = (int*)(ws + OFF_BPTR);
    float* hg     = (float*)(ws + OFF_HG);
    double* xstat = (double*)(ws + OFF_XSTAT);
    double* sty   = (double*)(ws + OFF_STY);
    float* fst    = (float*)(ws + OFF_FST);
    float* st0 = fst;               float* st1 = fst + NSL * 128;
    float* st2 = fst + 2 * NSL * 128;
    float* st3 = fst + 3 * NSL * 128;
    float* st4 = fst + 4 * NSL * 128;

    hipMemsetAsync(ws + OFF_HG, 0, ZERO_BYTES, stream);

    // merged prep: weights transpose | xstats | bptr | bincnt
    k_prep0<<<1036, 256, 0, stream>>>(w_d2, b_d2, w_o1, w_o2, w_o3, x, batch, dstv,
                                      w2T, b2f, w1T, w2T2, w3T, xstat, bptr, T);
    k_bscanA<<<NBKT, 256, 0, stream>>>(T, tot);
    // merged: bucket scatter (with in-LDS bbase scan) | x histogram (concurrent)
    k_binhist<<<NB1 + HBLK, 1024, 0, stream>>>(x, src, dstv, edge_type, T, tot,
                                               bbase, esd_tmp, hpart);
    // merged: per-bucket local sort (emits row_ptr) | knot table + BN2 moments
    k_locyt<<<NBKT + 128, 256, 0, stream>>>(esd_tmp, bbase, row_ptr, esd,
                                            xstat, w_d1, g_d1, be_d1, w2T, b2f,
                                            hpart, ytab, sty);
    k_ypack<<<NTB * 64 / 256, 256, 0, stream>>>(ytab, sty, g_d2, be_d2, ptab);
    // gconv 1 (h from node_emb[node_type], L1-resident); stats fused
    k_agg0<<<25000, 128, 0, stream>>>(node_type, node_emb, esd, row_ptr, ptab, edge_emb, hB, st0);
    k_bn<<<12500, 256, 0, stream>>>(hB, hB, st0, g_c1, be_c1, NN, 6, 1);
    // gconv 2
    k_agg<<<25000, 128, 0, stream>>>(hB, esd, row_ptr, ptab, edge_emb, hA, st1);
    k_bn<<<12500, 256, 0, stream>>>(hA, hA, st1, g_c2, be_c2, NN, 6, 1);
    // gconv 3 (no activation)
    k_agg<<<25000, 128, 0, stream>>>(hA, esd, row_ptr, ptab, edge_emb, hB, st2);
    k_bn<<<12500, 256, 0, stream>>>(hB, hB, st2, g_c3, be_c3, NN, 6, 0);
    // global pool + head (stats fused into o1/o2)
    k_hg2<<<BB, 256, 0, stream>>>(hB, bptr, hg);
    k_o1<<<3125, 256, 0, stream>>>(hB, hg, batch, w1T, b_o1, hA, st3);
    k_bn<<<12500, 256, 0, stream>>>(hA, hA, st3, g_o1, be_o1, NN, 6, 1);
    k_o2<<<1563, 256, 0, stream>>>(hA, w2T2, b_o2, zb, st4);
    k_bn<<<6250, 256, 0, stream>>>(zb, zb, st4, g_o2, be_o2, NN, 5, 1);
    k_o3<<<6250, 256, 0, stream>>>(zb, w3T, b_o3, (float*)d_out);
    (void)in_sizes; (void)n_in; (void)out_size; (void)ws_size;
}

// Round 11
// 558.017 us; speedup vs baseline: 1.5342x; 1.0092x over previous
//
#include <hip/hip_runtime.h>
#include <stdint.h>

#define NN 50000
#define EE 1250000
#define BB 500
#define BN_EPS 1e-5f
#define LOG2E 1.44269504f
#define LN2 0.69314718f

// two-level multisplit: 391 buckets of 128 nodes + per-bucket local sort
#define NBKT 391
#define NPBSH 7
#define NB1 256       // binning blocks
#define BPB 4883      // edges per binning block (256*4883 >= EE)

// x-histogram for BN2 moments (merged into binscat launch; dedicated hpart region)
#define HBLK 88
#define HEPB ((EE + HBLK - 1) / HBLK)   // 14205 edges per hist block
#define FHSC 65536.f                     // fixed-point scale for f, f^2 partials
#define FHIN (1.f / 65536.f)

// fused-stats spread slots (native f32 atomics via unsafeAtomicAdd, 16-way spreading)
#define NSL 16

#define NTB 8192      // table intervals; 8193 knots
#define XLO (-12.0f)
#define XHI (12.0f)
#define XSC ((float)NTB / (XHI - XLO))
#define DXT ((XHI - XLO) / (float)NTB)
#define TPMAX 8191.999f

using u16 = unsigned short;
using u32 = unsigned int;

__device__ __forceinline__ u16 f2bf(float f) {
    u32 u = __float_as_uint(f);
    return (u16)((u + 0x7fffu + ((u >> 16) & 1u)) >> 16);
}
__device__ __forceinline__ u32 pk2(float a, float b) { return (u32)f2bf(a) | ((u32)f2bf(b) << 16); }
// softplus via native v_exp_f32 / v_log_f32
__device__ __forceinline__ float sp(float z) {
    float t = __builtin_amdgcn_exp2f(-fabsf(z) * LOG2E);
    float l = __builtin_amdgcn_logf(1.f + t) * LN2;
    return fmaxf(z, 0.f) + l;
}
// guaranteed v_readlane (VALU)
__device__ __forceinline__ float rl(float v, int l) {
    return __uint_as_float(__builtin_amdgcn_readlane(__float_as_uint(v), l));
}

// ---------------- workspace layout (~65 MB) ----------------
constexpr size_t OFF_ESD  = 0;                                    // int4 [E] {src, et, i, f_bits}
constexpr size_t OFF_ROWP = OFF_ESD + (size_t)EE * 16;            // row_ptr [N+1]
constexpr size_t OFF_HA   = (OFF_ROWP + (size_t)(NN + 1) * 4 + 255) & ~(size_t)255;
constexpr size_t OFF_HB   = OFF_HA + (size_t)NN * 64 * 4;
// esd_tmp (20 MB) aliases hA..hB: live only before k_locyt
constexpr size_t OFF_ZB   = OFF_HB + (size_t)NN * 64 * 4;         // [N,32]
// sort scratch aliases zb (dead before k_o2): T[NB1][NBKT], tot, bbase
constexpr size_t OFF_TMAT = OFF_ZB;
constexpr size_t OFF_TOT  = OFF_TMAT + (size_t)NB1 * NBKT * 4;
constexpr size_t OFF_BBASE= OFF_TOT + (size_t)NBKT * 4;
constexpr size_t OFF_YTAB = OFF_ZB + (size_t)NN * 32 * 4;         // f32 [NTB+1][64]
constexpr size_t OFF_PTAB = OFF_YTAB + (size_t)(NTB + 1) * 64 * 4;// u32 [NTB][64] bf16 (a, b-a), x LOG2E
constexpr size_t OFF_W2T  = OFF_PTAB + (size_t)NTB * 64 * 4;      // w_d2 transposed f32 [64][64]
constexpr size_t OFF_B2F  = OFF_W2T + 4096 * 4;
constexpr size_t OFF_W1T  = OFF_B2F + 256;                        // f32 [128][64] (w_o1^T)
constexpr size_t OFF_W2O  = OFF_W1T + 8192 * 4;                   // f32 [64][32]  (w_o2^T)
constexpr size_t OFF_W3T  = OFF_W2O + 2048 * 4;                   // f32 [32][128] (w_o3^T)
constexpr size_t OFF_BPTR = OFF_W3T + 4096 * 4;                   // int [B+1]
// zero region (one memset): hg | xstat | sty | 5 stat slot arrays (f32 [NSL][128] each)
constexpr size_t OFF_HG   = (OFF_BPTR + (BB + 1) * 4 + 255) & ~(size_t)255;
constexpr size_t OFF_XSTAT= OFF_HG + (size_t)BB * 64 * 4;         // 2 doubles
constexpr size_t OFF_STY  = OFF_XSTAT + 16;                       // 128 doubles
constexpr size_t OFF_FST  = OFF_STY + 128 * 8;                    // 5 * NSL * 128 floats
constexpr size_t ZERO_END = OFF_FST + 5 * NSL * 128 * 4;
constexpr size_t ZERO_BYTES = ZERO_END - OFF_HG;
// hpart: dedicated (coexists with esd_tmp during the merged binscat|hist launch)
constexpr size_t OFF_HPART= (ZERO_END + 255) & ~(size_t)255;      // int [HBLK][3][NTB] (~8.3 MB)

// ---------------- merged prep: w2prep | otprep | xstats | bptr | bincnt ----------------
__global__ void __launch_bounds__(256) k_prep0(
        const float* __restrict__ w2, const float* __restrict__ b2,
        const float* __restrict__ w1, const float* __restrict__ wo2, const float* __restrict__ w3,
        const float* __restrict__ x, const int* __restrict__ batch, const int* __restrict__ dstv,
        float* __restrict__ w2T, float* __restrict__ b2f,
        float* __restrict__ w1T, float* __restrict__ w2T2, float* __restrict__ w3T,
        double* __restrict__ xstat, int* __restrict__ bptr, int* __restrict__ T) {
    int bx = blockIdx.x, t = threadIdx.x;
    if (bx < 16) {
        int idx = bx * 256 + t;                          // 4096
        int hin = idx >> 6, ho = idx & 63;
        w2T[idx] = w2[ho * 64 + hin];
        if (idx < 64) b2f[idx] = b2[idx];
    } else if (bx < 72) {
        int idx = (bx - 16) * 256 + t;                   // 14336
        if (idx < 8192) {
            int j = idx >> 6, ho = idx & 63;
            w1T[idx] = w1[ho * 128 + j];
        } else if (idx < 8192 + 2048) {
            int q = idx - 8192;
            int j = q >> 5, ho = q & 31;
            w2T2[q] = wo2[ho * 64 + j];
        } else if (idx < 8192 + 2048 + 4096) {
            int q = idx - 8192 - 2048;
            int j = q >> 7, jo = q & 127;
            w3T[q] = w3[jo * 32 + j];
        }
    } else if (bx < 584) {
        __shared__ float ls[256], lq[256];
        float s = 0, q = 0;
        for (int i = (bx - 72) * 256 + t; i < EE; i += 512 * 256) {
            float v = x[i]; s += v; q += v * v;
        }
        ls[t] = s; lq[t] = q; __syncthreads();
        for (int off = 128; off > 0; off >>= 1) {
            if (t < off) { ls[t] += ls[t + off]; lq[t] += lq[t + off]; }
            __syncthreads();
        }
        if (t == 0) { atomicAdd(&xstat[0], (double)ls[0]); atomicAdd(&xstat[1], (double)lq[0]); }
    } else if (bx < 780) {
        int n = (bx - 584) * 256 + t;
        if (n >= NN) return;
        int b = batch[n];
        int pb = (n == 0) ? -1 : batch[n - 1];
        for (int k = pb + 1; k <= b; k++) bptr[k] = n;
        if (n == NN - 1) { for (int k = b + 1; k <= BB; k++) bptr[k] = NN; }
    } else {
        // bincnt: per-block LDS histogram over 391 coarse buckets
        __shared__ int hh[NBKT];
        for (int i = t; i < NBKT; i += 256) hh[i] = 0;
        __syncthreads();
        int bb = bx - 780;
        int e0 = bb * BPB;
        int e1 = e0 + BPB; if (e1 > EE) e1 = EE;
        for (int e = e0 + t; e < e1; e += 256)
            atomicAdd(&hh[dstv[e] >> NPBSH], 1);
        __syncthreads();
        for (int i = t; i < NBKT; i += 256)
            T[(size_t)bb * NBKT + i] = hh[i];
    }
}

// per-bucket exclusive scan over blocks (in-place), bucket totals out
__global__ void k_bscanA(int* __restrict__ T, int* __restrict__ tot) {
    __shared__ int ls[256];
    int b = blockIdx.x, t = threadIdx.x;
    int v = T[(size_t)t * NBKT + b];
    ls[t] = v; __syncthreads();
    for (int off = 1; off < 256; off <<= 1) {
        int a = ls[t]; int add = (t >= off) ? ls[t - off] : 0; __syncthreads();
        ls[t] = a + add; __syncthreads();
    }
    T[(size_t)t * NBKT + b] = ls[t] - v;
    if (t == 255) tot[b] = ls[255];
}

// ---------------- merged: chunked bucket scatter | x histogram ----------------
__global__ void __launch_bounds__(1024) k_binhist(
        const float* __restrict__ x, const int* __restrict__ src,
        const int* __restrict__ dstv, const int* __restrict__ etv,
        const int* __restrict__ T, const int* __restrict__ tot,
        int* __restrict__ bbase_g, int4* __restrict__ esd_tmp, int* __restrict__ hpart) {
    __shared__ int shb[3 * (NTB / 2)];                   // 48 KB, unioned across branches
    int t = threadIdx.x;
    if (blockIdx.x < NB1) {
        int* cur = shb;                                  // [NBKT]
        int* sls = shb + 512;                            // [512] scan buffer
        int v = 0;
        if (t < 512) { v = (t < NBKT) ? tot[t] : 0; sls[t] = v; }
        __syncthreads();
        for (int off = 1; off < 512; off <<= 1) {
            int a = 0;
            if (t < 512) { a = sls[t]; if (t >= off) a += sls[t - off]; }
            __syncthreads();
            if (t < 512) sls[t] = a;
            __syncthreads();
        }
        if (t < NBKT) {
            int base = sls[t] - v;                       // exclusive
            cur[t] = base + T[(size_t)blockIdx.x * NBKT + t];
            if (blockIdx.x == 0) bbase_g[t] = base;
        }
        if (blockIdx.x == 0 && t == 0) bbase_g[NBKT] = EE;
        __syncthreads();
        int e0 = blockIdx.x * BPB;
        int e1 = e0 + BPB; if (e1 > EE) e1 = EE;
        for (int e = e0 + t; e < e1; e += 1024) {
            int d = dstv[e];
            int p = atomicAdd(&cur[d >> NPBSH], 1);
            float tp = fminf(fmaxf((x[e] - XLO) * XSC, 0.f), TPMAX);
            int i = (int)tp; float f = tp - (float)i;
            // local dst (7 bits) rides in spare bits of et (et < 128)
            int4 vv; vv.x = src[e]; vv.y = etv[e] | ((d & 127) << 7); vv.z = i; vv.w = __float_as_int(f);
            esd_tmp[p] = vv;
        }
    } else {
        int* cnt = shb; int* sf = shb + NTB / 2; int* sf2 = shb + NTB;
        int bb = blockIdx.x - NB1;
        int e0 = bb * HEPB;
        int e1 = e0 + HEPB; if (e1 > EE) e1 = EE;
        int* outp = hpart + (size_t)bb * 3 * NTB;
        for (int half = 0; half < 2; half++) {
            for (int i = t; i < NTB / 2; i += 1024) { cnt[i] = 0; sf[i] = 0; sf2[i] = 0; }
            __syncthreads();
            int lo = half * (NTB / 2);
            for (int e = e0 + t; e < e1; e += 1024) {
                float tp = fminf(fmaxf((x[e] - XLO) * XSC, 0.f), TPMAX);
                int i = (int)tp;
                int li = i - lo;
                if ((unsigned)li < (unsigned)(NTB / 2)) {
                    float f = tp - (float)i;
                    atomicAdd(&cnt[li], 1);
                    atomicAdd(&sf[li], (int)(f * FHSC));
                    atomicAdd(&sf2[li], (int)(f * f * FHSC));
                }
            }
            __syncthreads();
            for (int i = t; i < NTB / 2; i += 1024) {
                outp[lo + i] = cnt[i];
                outp[NTB + lo + i] = sf[i];
                outp[2 * NTB + lo + i] = sf2[i];
            }
            __syncthreads();
        }
    }
}

// ---------------- merged: per-bucket local sort | fused knot table + BN2 moments ----------
// blocks [0,NBKT): locsort (emits row_ptr). blocks [NBKT,NBKT+128): ytmom.
__global__ void __launch_bounds__(256) k_locyt(
        const int4* __restrict__ esd_tmp, const int* __restrict__ bbase,
        int* __restrict__ row_ptr, int4* __restrict__ esd,
        const double* __restrict__ xstat, const float* __restrict__ w_d1,
        const float* __restrict__ g_d1, const float* __restrict__ be_d1,
        const float* __restrict__ w2T, const float* __restrict__ b2f,
        const int* __restrict__ hpart, float* __restrict__ ytab, double* __restrict__ sty) {
    __shared__ char shraw[65 * 64 * 4 + 192 * 4];        // 17.4 KB union
    int t = threadIdx.x;
    if (blockIdx.x < NBKT) {
        int* hist = (int*)shraw;
        int* ls   = hist + 128;
        int* cur  = ls + 128;
        int b = blockIdx.x;
        if (b == 0 && t == 0) row_ptr[NN] = EE;
        int base = bbase[b], end = bbase[b + 1];
        if (t < 128) hist[t] = 0;
        __syncthreads();
        for (int p = base + t; p < end; p += 256)
            atomicAdd(&hist[(esd_tmp[p].y >> 7) & 127], 1);
        __syncthreads();
        int v = 0;
        if (t < 128) { v = hist[t]; ls[t] = v; }
        __syncthreads();
        for (int off = 1; off < 128; off <<= 1) {
            int a = 0;
            if (t < 128) { a = ls[t]; if (t >= off) a += ls[t - off]; }
            __syncthreads();
            if (t < 128) ls[t] = a;
            __syncthreads();
        }
        if (t < 128) {
            int exc = ls[t] - v;
            cur[t] = base + exc;
            int n = (b << NPBSH) + t;
            if (n < NN) row_ptr[n] = base + exc;
        }
        __syncthreads();
        for (int p = base + t; p < end; p += 256) {
            int4 r = esd_tmp[p];
            int ld = (r.y >> 7) & 127;
            r.y &= 127;
            esd[atomicAdd(&cur[ld], 1)] = r;
        }
    } else {
        float (*kn)[64] = (float(*)[64])shraw;
        float* hs = (float*)(shraw + 65 * 64 * 4);
        int lane = t & 63, w = t >> 6;
        int g = blockIdx.x - NBKT;                       // 0..127
        double inv = 1.0 / (double)EE;
        double mx = xstat[0] * inv;
        double vx = xstat[1] * inv - mx * mx; if (vx < 0) vx = 0;
        float wd = w_d1[lane];
        float Aw = wd * rsqrtf((float)vx * wd * wd + BN_EPS) * g_d1[lane];
        float Cw = be_d1[lane];
        for (int kk = w; kk < 65; kk += 4) {
            int idx = (g << 6) + kk;
            float xi = XLO + (float)idx * DXT;
            float tt = xi - (float)mx;
            float d1L = sp(fmaf(Aw, tt, Cw));
            float y = b2f[lane];
            #pragma unroll
            for (int hin = 0; hin < 64; hin++)
                y = fmaf(rl(d1L, hin), w2T[hin * 64 + lane], y);
            kn[kk][lane] = y;
            if (kk < 64 || g == 127) ytab[(idx << 6) | lane] = y;
        }
        if (t < 192) {                                   // hsum: c|f1|f2 for this block's 64 bins
            int slot = t >> 6, ii = t & 63;
            float s = 0.f;
            size_t off = (size_t)slot * NTB + (g << 6) + ii;
            for (int b = 0; b < HBLK; b++)
                s += (float)hpart[(size_t)b * 3 * NTB + off];
            hs[t] = (slot == 0) ? s : s * FHIN;
        }
        __syncthreads();
        if (t >= 64) return;                             // one wave: moment math
        double S = 0.0, Q = 0.0;
        float aprev = kn[0][lane];
        for (int ii = 0; ii < 64; ii++) {
            float c = hs[ii], f1 = hs[64 + ii], f2 = hs[128 + ii];
            float b = kn[ii + 1][lane];
            float a = aprev; aprev = b;
            float d = b - a;
            S += (double)(fmaf(c, a, d * f1));
            Q += (double)(fmaf(c * a, a, fmaf(2.f * a * d, f1, d * d * f2)));
        }
        atomicAdd(&sty[lane], S);
        atomicAdd(&sty[64 + lane], Q);
    }
}

// pack bn2-affined table as bf16 (a, b-a) pairs, pre-scaled by LOG2E (log2-domain agg)
__global__ void k_ypack(const float* __restrict__ ytab, const double* __restrict__ sty,
                        const float* __restrict__ g2, const float* __restrict__ be2,
                        u32* __restrict__ ptab) {
    int tid = blockIdx.x * 256 + threadIdx.x;            // NTB*64
    int f = tid & 63;
    double inv = 1.0 / (double)EE;
    double m = sty[f] * inv;
    double var = sty[64 + f] * inv - m * m; if (var < 0) var = 0;
    float rstd = rsqrtf((float)var + BN_EPS);
    float sc0 = rstd * g2[f];
    float sc = sc0 * LOG2E;
    float sh = (be2[f] - (float)m * sc0) * LOG2E;
    float a = fmaf(ytab[tid], sc, sh);
    float b = fmaf(ytab[tid + 64], sc, sh);
    ptab[tid] = pk2(a, b - a);
}

// per-edge term (log2-scaled): one fmaf lerp + emb mul
__device__ __forceinline__ float edge_term(int4 ed, int lane, const u32* __restrict__ ptab,
                                           const float* __restrict__ emb) {
    u32 pr = ptab[(ed.z << 6) | lane];
    float f = __int_as_float(ed.w);
    float a = __uint_as_float(pr << 16);
    float d = __uint_as_float(pr & 0xffff0000u);
    float y = fmaf(f, d, a);
    return y * emb[(ed.y << 6) | lane];
}
// log2-domain softplus accumulate
__device__ __forceinline__ void sp2(float hv, float av, float& accm, float& accl) {
    float z = fmaf(hv, LOG2E, av);
    float t = __builtin_amdgcn_exp2f(-fabsf(z));
    accm += fmaxf(z, 0.f);
    accl += __builtin_amdgcn_logf(1.f + t);
}

// wave-per-node aggregation; 128-thr blocks (2 nodes); unroll-8 for deeper MLP of
// outstanding h-gathers; fused per-feature stats via NATIVE f32 atomics
__global__ void __launch_bounds__(128) k_agg(
        const float* __restrict__ h, const int4* __restrict__ esd, const int* __restrict__ row_ptr,
        const u32* __restrict__ ptab, const float* __restrict__ emb, float* __restrict__ hpre,
        float* __restrict__ stat) {
    int lane = threadIdx.x & 63;
    int w = threadIdx.x >> 6;
    int n = __builtin_amdgcn_readfirstlane((int)((blockIdx.x << 1) | w));
    int p0 = row_ptr[n], p1 = row_ptr[n + 1];
    float accm = 0.f, accl = 0.f;
    int p = p0;
    for (; p + 8 <= p1; p += 8) {
        int4 e[8];
        #pragma unroll
        for (int k = 0; k < 8; k++) e[k] = esd[p + k];
        float hv[8], av[8];
        #pragma unroll
        for (int k = 0; k < 8; k++) hv[k] = h[(e[k].x << 6) | lane];
        #pragma unroll
        for (int k = 0; k < 8; k++) av[k] = edge_term(e[k], lane, ptab, emb);
        #pragma unroll
        for (int k = 0; k < 8; k++) sp2(hv[k], av[k], accm, accl);
    }
    for (; p + 4 <= p1; p += 4) {
        int4 e0 = esd[p], e1 = esd[p + 1], e2 = esd[p + 2], e3 = esd[p + 3];
        float h0 = h[(e0.x << 6) | lane];
        float h1 = h[(e1.x << 6) | lane];
        float h2 = h[(e2.x << 6) | lane];
        float h3 = h[(e3.x << 6) | lane];
        float a0 = edge_term(e0, lane, ptab, emb);
        float a1 = edge_term(e1, lane, ptab, emb);
        float a2 = edge_term(e2, lane, ptab, emb);
        float a3 = edge_term(e3, lane, ptab, emb);
        sp2(h0, a0, accm, accl);
        sp2(h1, a1, accm, accl);
        sp2(h2, a2, accm, accl);
        sp2(h3, a3, accm, accl);
    }
    for (; p < p1; ++p) {
        int4 e0 = esd[p];
        float h0 = h[(e0.x << 6) | lane];
        sp2(h0, edge_term(e0, lane, ptab, emb), accm, accl);
    }
    int o = (n << 6) | lane;
    float val = fmaf(accm + accl, LN2, h[o]);
    hpre[o] = val;
    __shared__ float lsS[2][64], lsQ[2][64];
    lsS[w][lane] = val; lsQ[w][lane] = val * val;
    __syncthreads();
    if (w == 0) {
        int sl = ((int)blockIdx.x & (NSL - 1)) << 7;
        unsafeAtomicAdd(&stat[sl + lane], lsS[0][lane] + lsS[1][lane]);
        unsafeAtomicAdd(&stat[sl + 64 + lane], lsQ[0][lane] + lsQ[1][lane]);
    }
}

// gconv1 variant: h comes from node_emb[node_type] (L1-resident); fused stats
__global__ void __launch_bounds__(128) k_agg0(
        const int* __restrict__ nt, const float* __restrict__ nemb, const int4* __restrict__ esd,
        const int* __restrict__ row_ptr, const u32* __restrict__ ptab,
        const float* __restrict__ emb, float* __restrict__ hpre, float* __restrict__ stat) {
    int lane = threadIdx.x & 63;
    int w = threadIdx.x >> 6;
    int n = __builtin_amdgcn_readfirstlane((int)((blockIdx.x << 1) | w));
    int p0 = row_ptr[n], p1 = row_ptr[n + 1];
    float accm = 0.f, accl = 0.f;
    int p = p0;
    for (; p + 8 <= p1; p += 8) {
        int4 e[8];
        #pragma unroll
        for (int k = 0; k < 8; k++) e[k] = esd[p + k];
        float hv[8], av[8];
        #pragma unroll
        for (int k = 0; k < 8; k++) hv[k] = nemb[(nt[e[k].x] << 6) | lane];
        #pragma unroll
        for (int k = 0; k < 8; k++) av[k] = edge_term(e[k], lane, ptab, emb);
        #pragma unroll
        for (int k = 0; k < 8; k++) sp2(hv[k], av[k], accm, accl);
    }
    for (; p + 4 <= p1; p += 4) {
        int4 e0 = esd[p], e1 = esd[p + 1], e2 = esd[p + 2], e3 = esd[p + 3];
        float h0 = nemb[(nt[e0.x] << 6) | lane];
        float h1 = nemb[(nt[e1.x] << 6) | lane];
        float h2 = nemb[(nt[e2.x] << 6) | lane];
        float h3 = nemb[(nt[e3.x] << 6) | lane];
        float a0 = edge_term(e0, lane, ptab, emb);
        float a1 = edge_term(e1, lane, ptab, emb);
        float a2 = edge_term(e2, lane, ptab, emb);
        float a3 = edge_term(e3, lane, ptab, emb);
        sp2(h0, a0, accm, accl);
        sp2(h1, a1, accm, accl);
        sp2(h2, a2, accm, accl);
        sp2(h3, a3, accm, accl);
    }
    for (; p < p1; ++p) {
        int4 e0 = esd[p];
        float h0 = nemb[(nt[e0.x] << 6) | lane];
        sp2(h0, edge_term(e0, lane, ptab, emb), accm, accl);
    }
    float val = fmaf(accm + accl, LN2, nemb[(nt[n] << 6) | lane]);
    hpre[(n << 6) | lane] = val;
    __shared__ float lsS[2][64], lsQ[2][64];
    lsS[w][lane] = val; lsQ[w][lane] = val * val;
    __syncthreads();
    if (w == 0) {
        int sl = ((int)blockIdx.x & (NSL - 1)) << 7;
        unsafeAtomicAdd(&stat[sl + lane], lsS[0][lane] + lsS[1][lane]);
        unsafeAtomicAdd(&stat[sl + 64 + lane], lsQ[0][lane] + lsQ[1][lane]);
    }
}

// BN apply: preamble reduces the NSL spread slots; per-block f32 scale/shift hoist
__global__ void __launch_bounds__(256) k_bn(
        const float* __restrict__ in, float* __restrict__ out,
        const float* __restrict__ stat, const float* __restrict__ g,
        const float* __restrict__ be, int rows, int logC, int act) {
    int C = 1 << logC;
    __shared__ float scl[64], shl[64];
    int t = threadIdx.x;
    if (t < C) {
        float s = 0.f, q = 0.f;
        #pragma unroll
        for (int sl = 0; sl < NSL; sl++) {
            s += stat[(sl << 7) + t];
            q += stat[(sl << 7) + 64 + t];
        }
        float inv = 1.f / (float)rows;
        float m = s * inv;
        float var = q * inv - m * m; if (var < 0.f) var = 0.f;
        float rstd = rsqrtf(var + BN_EPS);
        float sc = rstd * g[t];
        scl[t] = sc; shl[t] = be[t] - m * sc;
    }
    __syncthreads();
    size_t total = (size_t)rows << logC;
    size_t i = (size_t)blockIdx.x * 256 + t;
    if (i >= total) return;
    int f = (int)(i & (C - 1));
    float val = fmaf(in[i], scl[f], shl[f]);
    out[i] = act ? sp(val) : val;
}

// global pooling: block-per-batch segment sum over sorted batch (no atomics)
__global__ void __launch_bounds__(256) k_hg2(
        const float* __restrict__ h, const int* __restrict__ bptr, float* __restrict__ hg) {
    int b = blockIdx.x;                                  // BB
    int lane = threadIdx.x & 63, w = threadIdx.x >> 6;
    int n0 = bptr[b], n1 = bptr[b + 1];
    float acc = 0.f;
    for (int n = n0 + w; n < n1; n += 4)
        acc += h[(n << 6) | lane];
    __shared__ float ls[256];
    ls[threadIdx.x] = acc; __syncthreads();
    if (threadIdx.x < 64)
        hg[(b << 6) | lane] = ls[lane] + ls[64 + lane] + ls[128 + lane] + ls[192 + lane];
}

// head GEMV 1: 4 nodes/wave; fused stats (native f32 atomics)
#define O1NPW 4
__global__ void __launch_bounds__(256) k_o1(
        const float* __restrict__ h, const float* __restrict__ hg, const int* __restrict__ batch,
        const float* __restrict__ w1T, const float* __restrict__ b1, float* __restrict__ z1,
        float* __restrict__ stat) {
    int lane = threadIdx.x & 63;
    int wv = (blockIdx.x * 256 + (int)threadIdx.x) >> 6;
    int n0 = __builtin_amdgcn_readfirstlane(wv * O1NPW);  // grid exact: 3125*4 waves = 50000 nodes
    float hl[O1NPW], gl[O1NPW], acc[O1NPW];
    float bl = b1[lane];
    #pragma unroll
    for (int k = 0; k < O1NPW; k++) {
        int n = n0 + k;
        hl[k] = h[(n << 6) | lane];
        gl[k] = hg[(batch[n] << 6) | lane];
        acc[k] = bl;
    }
    #pragma unroll
    for (int j = 0; j < 64; j++) {
        float w = w1T[(j << 6) | lane];
        #pragma unroll
        for (int k = 0; k < O1NPW; k++)
            acc[k] = fmaf(rl(hl[k], j), w, acc[k]);
    }
    #pragma unroll
    for (int j = 0; j < 64; j++) {
        float w = w1T[((64 + j) << 6) | lane];
        #pragma unroll
        for (int k = 0; k < O1NPW; k++)
            acc[k] = fmaf(rl(gl[k], j), w, acc[k]);
    }
    float s = 0.f, q = 0.f;
    #pragma unroll
    for (int k = 0; k < O1NPW; k++) {
        z1[((n0 + k) << 6) | lane] = acc[k];
        s += acc[k]; q += acc[k] * acc[k];
    }
    __shared__ float lsS[4][64], lsQ[4][64];
    int w = threadIdx.x >> 6;
    lsS[w][lane] = s; lsQ[w][lane] = q; __syncthreads();
    if (threadIdx.x < 128) {
        int f = threadIdx.x & 63; bool isq = threadIdx.x >= 64;
        float r = 0.f;
        #pragma unroll
        for (int j = 0; j < 4; j++) r += isq ? lsQ[j][f] : lsS[j][f];
        int sl = ((int)blockIdx.x & (NSL - 1)) << 7;
        unsafeAtomicAdd(&stat[sl + (isq ? 64 : 0) + f], r);
    }
}

// head GEMV 2: 8 nodes/wave; fused stats (C=32: s at [f], q at [64+f])
__global__ void __launch_bounds__(256) k_o2(
        const float* __restrict__ o1v, const float* __restrict__ w2T2,
        const float* __restrict__ b2, float* __restrict__ z2, float* __restrict__ stat) {
    int lane = threadIdx.x & 63;
    int ho = lane & 31;
    int wv = (blockIdx.x * 256 + (int)threadIdx.x) >> 6;
    int n0 = __builtin_amdgcn_readfirstlane(wv * 8);
    float xr[8], acc[4];
    #pragma unroll
    for (int k = 0; k < 8; k++) {
        int n = n0 + k; if (n >= NN) n = NN - 1;
        xr[k] = o1v[(n << 6) | lane];
    }
    float bl = b2[ho];
    #pragma unroll
    for (int k = 0; k < 4; k++) acc[k] = bl;
    #pragma unroll
    for (int j = 0; j < 64; j++) {
        float w = w2T2[(j << 5) | ho];
        #pragma unroll
        for (int k = 0; k < 4; k++) {
            float slo = rl(xr[k], j);
            float shi = rl(xr[4 + k], j);
            float v = (lane < 32) ? slo : shi;
            acc[k] = fmaf(v, w, acc[k]);
        }
    }
    int nbase = n0 + ((lane >> 5) << 2);
    float s = 0.f, q = 0.f;
    #pragma unroll
    for (int k = 0; k < 4; k++) {
        if (nbase + k < NN) {
            z2[((nbase + k) << 5) | ho] = acc[k];
            s += acc[k]; q += acc[k] * acc[k];
        }
    }
    __shared__ float lsS[4][64], lsQ[4][64];
    int w = threadIdx.x >> 6;
    lsS[w][lane] = s; lsQ[w][lane] = q; __syncthreads();
    if (threadIdx.x < 64) {
        int f = threadIdx.x & 31; bool isq = threadIdx.x >= 32;
        float r = 0.f;
        #pragma unroll
        for (int j = 0; j < 4; j++)
            r += isq ? (lsQ[j][f] + lsQ[j][32 + f]) : (lsS[j][f] + lsS[j][32 + f]);
        int sl = ((int)blockIdx.x & (NSL - 1)) << 7;
        unsafeAtomicAdd(&stat[sl + (isq ? 64 : 0) + f], r);
    }
}

// head GEMV 3: 4 nodes per wave per jo-half
__global__ void __launch_bounds__(256) k_o3(
        const float* __restrict__ o2v, const float* __restrict__ w3T,
        const float* __restrict__ b3, float* __restrict__ outp) {
    int lane = threadIdx.x & 63;
    int wv = (blockIdx.x * 256 + (int)threadIdx.x) >> 6;
    int n0 = __builtin_amdgcn_readfirstlane((wv >> 1) << 2);
    int jo = (((wv & 1) << 6) + lane);
    if (n0 >= NN) return;
    float zl[4], acc[4];
    float bl = b3[jo];
    #pragma unroll
    for (int k = 0; k < 4; k++) {
        zl[k] = o2v[((n0 + k) << 5) | (lane & 31)];
        acc[k] = bl;
    }
    #pragma unroll
    for (int j = 0; j < 32; j++) {
        float w = w3T[(j << 7) | jo];
        #pragma unroll
        for (int k = 0; k < 4; k++)
            acc[k] = fmaf(rl(zl[k], j), w, acc[k]);
    }
    #pragma unroll
    for (int k = 0; k < 4; k++) {
        int n = n0 + k;
        size_t dsti = (jo < 64) ? ((size_t)(n << 6) + jo)
                                : ((size_t)NN * 64 + (size_t)(n << 6) + (jo - 64));
        outp[dsti] = acc[k];                             // f32 output
    }
}

extern "C" void kernel_launch(void* const* d_in, const int* in_sizes, int n_in,
                              void* d_out, int out_size, void* d_ws, size_t ws_size,
                              hipStream_t stream) {
    const float* x        = (const float*)d_in[0];
    const int* node_type  = (const int*)d_in[1];
    const int* edge_type  = (const int*)d_in[2];
    const int* edge_index = (const int*)d_in[3];
    const int* batch      = (const int*)d_in[4];
    const float* node_emb = (const float*)d_in[5];
    const float* edge_emb = (const float*)d_in[6];
    const float* w_d1 = (const float*)d_in[7];  const float* b_d1 = (const float*)d_in[8];
    const float* g_d1 = (const float*)d_in[9];  const float* be_d1 = (const float*)d_in[10];
    const float* w_d2 = (const float*)d_in[11]; const float* b_d2 = (const float*)d_in[12];
    const float* g_d2 = (const float*)d_in[13]; const float* be_d2 = (const float*)d_in[14];
    const float* g_c1 = (const float*)d_in[15]; const float* be_c1 = (const float*)d_in[16];
    const float* g_c2 = (const float*)d_in[17]; const float* be_c2 = (const float*)d_in[18];
    const float* g_c3 = (const float*)d_in[19]; const float* be_c3 = (const float*)d_in[20];
    const float* w_o1 = (const float*)d_in[21]; const float* b_o1 = (const float*)d_in[22];
    const float* g_o1 = (const float*)d_in[23]; const float* be_o1 = (const float*)d_in[24];
    const float* w_o2 = (const float*)d_in[25]; const float* b_o2 = (const float*)d_in[26];
    const float* g_o2 = (const float*)d_in[27]; const float* be_o2 = (const float*)d_in[28];
    const float* w_o3 = (const float*)d_in[29]; const float* b_o3 = (const float*)d_in[30];
    (void)b_d1;  // cancels inside BN1 (mean subtraction removes per-feature shift)
    const int* src  = edge_index;
    const int* dstv = edge_index + EE;

    char* ws = (char*)d_ws;
    int4*  esd     = (int4*)(ws + OFF_ESD);
    int*   row_ptr = (int*)(ws + OFF_ROWP);
    float* hA   = (float*)(ws + OFF_HA);
    float* hB   = (float*)(ws + OFF_HB);
    float* zb   = (float*)(ws + OFF_ZB);
    int4*  esd_tmp = (int4*)(ws + OFF_HA);   // aliases hA..hB (live only before k_locyt done)
    int*   hpart = (int*)(ws + OFF_HPART);   // dedicated (coexists with esd_tmp)
    int*   T    = (int*)(ws + OFF_TMAT);     // aliases zb (live only before k_binhist done)
    int*   tot  = (int*)(ws + OFF_TOT);
    int*   bbase= (int*)(ws + OFF_BBASE);
    float* ytab = (float*)(ws + OFF_YTAB);
    u32*   ptab = (u32*)(ws + OFF_PTAB);
    float* w2T  = (float*)(ws + OFF_W2T);
    float* b2f  = (float*)(ws + OFF_B2F);
    float* w1T  = (float*)(ws + OFF_W1T);
    float* w2T2 = (float*)(ws + OFF_W2O);
    float* w3T  = (float*)(ws + OFF_W3T);
    int*   bptr = (int*)(ws + OFF_BPTR);
    float* hg     = (float*)(ws + OFF_HG);
    double* xstat = (double*)(ws + OFF_XSTAT);
    double* sty   = (double*)(ws + OFF_STY);
    float* fst    = (float*)(ws + OFF_FST);
    float* st0 = fst;               float* st1 = fst + NSL * 128;
    float* st2 = fst + 2 * NSL * 128;
    float* st3 = fst + 3 * NSL * 128;
    float* st4 = fst + 4 * NSL * 128;

    hipMemsetAsync(ws + OFF_HG, 0, ZERO_BYTES, stream);

    // merged prep: weights transpose | xstats | bptr | bincnt
    k_prep0<<<1036, 256, 0, stream>>>(w_d2, b_d2, w_o1, w_o2, w_o3, x, batch, dstv,
                                      w2T, b2f, w1T, w2T2, w3T, xstat, bptr, T);
    k_bscanA<<<NBKT, 256, 0, stream>>>(T, tot);
    // merged: bucket scatter (with in-LDS bbase scan) | x histogram (concurrent)
    k_binhist<<<NB1 + HBLK, 1024, 0, stream>>>(x, src, dstv, edge_type, T, tot,
                                               bbase, esd_tmp, hpart);
    // merged: per-bucket local sort (emits row_ptr) | knot table + BN2 moments
    k_locyt<<<NBKT + 128, 256, 0, stream>>>(esd_tmp, bbase, row_ptr, esd,
                                            xstat, w_d1, g_d1, be_d1, w2T, b2f,
                                            hpart, ytab, sty);
    k_ypack<<<NTB * 64 / 256, 256, 0, stream>>>(ytab, sty, g_d2, be_d2, ptab);
    // gconv 1 (h from node_emb[node_type], L1-resident); stats fused
    k_agg0<<<25000, 128, 0, stream>>>(node_type, node_emb, esd, row_ptr, ptab, edge_emb, hB, st0);
    k_bn<<<12500, 256, 0, stream>>>(hB, hB, st0, g_c1, be_c1, NN, 6, 1);
    // gconv 2
    k_agg<<<25000, 128, 0, stream>>>(hB, esd, row_ptr, ptab, edge_emb, hA, st1);
    k_bn<<<12500, 256, 0, stream>>>(hA, hA, st1, g_c2, be_c2, NN, 6, 1);
    // gconv 3 (no activation)
    k_agg<<<25000, 128, 0, stream>>>(hA, esd, row_ptr, ptab, edge_emb, hB, st2);
    k_bn<<<12500, 256, 0, stream>>>(hB, hB, st2, g_c3, be_c3, NN, 6, 0);
    // global pool + head (stats fused into o1/o2)
    k_hg2<<<BB, 256, 0, stream>>>(hB, bptr, hg);
    k_o1<<<3125, 256, 0, stream>>>(hB, hg, batch, w1T, b_o1, hA, st3);
    k_bn<<<12500, 256, 0, stream>>>(hA, hA, st3, g_o1, be_o1, NN, 6, 1);
    k_o2<<<1563, 256, 0, stream>>>(hA, w2T2, b_o2, zb, st4);
    k_bn<<<6250, 256, 0, stream>>>(zb, zb, st4, g_o2, be_o2, NN, 5, 1);
    k_o3<<<6250, 256, 0, stream>>>(zb, w3T, b_o3, (float*)d_out);
    (void)in_sizes; (void)n_in; (void)out_size; (void)ws_size;
}

// Round 12
// 508.399 us; speedup vs baseline: 1.6839x; 1.0976x over previous
//
#include <hip/hip_runtime.h>
#include <stdint.h>

#define NN 50000
#define EE 1250000
#define BB 500
#define BN_EPS 1e-5f
#define LOG2E 1.44269504f
#define LN2 0.69314718f

// two-level multisplit: 391 buckets of 128 nodes + per-bucket local sort
#define NBKT 391
#define NPBSH 7
#define NB1 256       // binning blocks
#define BPB 4883      // edges per binning block (256*4883 >= EE)

// x-histogram for BN2 moments (merged into binscat launch; dedicated hpart region)
#define HBLK 88
#define HEPB ((EE + HBLK - 1) / HBLK)   // 14205 edges per hist block
#define FHSC 65536.f                     // fixed-point scale for f, f^2 partials
#define FHIN (1.f / 65536.f)

// stats spread slots (native f32 atomics via unsafeAtomicAdd, 16-way spreading)
#define NSL 16

#define NTB 8192      // table intervals; 8193 knots
#define XLO (-12.0f)
#define XHI (12.0f)
#define XSC ((float)NTB / (XHI - XLO))
#define DXT ((XHI - XLO) / (float)NTB)
#define TPMAX 8191.999f

using u16 = unsigned short;
using u32 = unsigned int;

__device__ __forceinline__ u16 f2bf(float f) {
    u32 u = __float_as_uint(f);
    return (u16)((u + 0x7fffu + ((u >> 16) & 1u)) >> 16);
}
__device__ __forceinline__ u32 pk2(float a, float b) { return (u32)f2bf(a) | ((u32)f2bf(b) << 16); }
// softplus via native v_exp_f32 / v_log_f32
__device__ __forceinline__ float sp(float z) {
    float t = __builtin_amdgcn_exp2f(-fabsf(z) * LOG2E);
    float l = __builtin_amdgcn_logf(1.f + t) * LN2;
    return fmaxf(z, 0.f) + l;
}
// guaranteed v_readlane (VALU)
__device__ __forceinline__ float rl(float v, int l) {
    return __uint_as_float(__builtin_amdgcn_readlane(__float_as_uint(v), l));
}

// ---------------- workspace layout (~65 MB) ----------------
constexpr size_t OFF_ESD  = 0;                                    // int4 [E] {src, et, i, f_bits}
constexpr size_t OFF_ROWP = OFF_ESD + (size_t)EE * 16;            // row_ptr [N+1]
constexpr size_t OFF_HA   = (OFF_ROWP + (size_t)(NN + 1) * 4 + 255) & ~(size_t)255;
constexpr size_t OFF_HB   = OFF_HA + (size_t)NN * 64 * 4;
// esd_tmp (20 MB) aliases hA..hB: live only before k_locyt
constexpr size_t OFF_ZB   = OFF_HB + (size_t)NN * 64 * 4;         // [N,32]
// sort scratch aliases zb (dead before k_o2): T[NB1][NBKT], tot, bbase
constexpr size_t OFF_TMAT = OFF_ZB;
constexpr size_t OFF_TOT  = OFF_TMAT + (size_t)NB1 * NBKT * 4;
constexpr size_t OFF_BBASE= OFF_TOT + (size_t)NBKT * 4;
constexpr size_t OFF_YTAB = OFF_ZB + (size_t)NN * 32 * 4;         // f32 [NTB+1][64]
constexpr size_t OFF_PTAB = OFF_YTAB + (size_t)(NTB + 1) * 64 * 4;// u32 [NTB][64] bf16 (a, b-a), x LOG2E
constexpr size_t OFF_W2T  = OFF_PTAB + (size_t)NTB * 64 * 4;      // w_d2 transposed f32 [64][64]
constexpr size_t OFF_B2F  = OFF_W2T + 4096 * 4;
constexpr size_t OFF_W1T  = OFF_B2F + 256;                        // f32 [128][64] (w_o1^T)
constexpr size_t OFF_W2O  = OFF_W1T + 8192 * 4;                   // f32 [64][32]  (w_o2^T)
constexpr size_t OFF_W3T  = OFF_W2O + 2048 * 4;                   // f32 [32][128] (w_o3^T)
constexpr size_t OFF_BPTR = OFF_W3T + 4096 * 4;                   // int [B+1]
// zero region (one memset): hg | xstat | sty | 5 stat slot arrays (f32 [NSL][128] each)
constexpr size_t OFF_HG   = (OFF_BPTR + (BB + 1) * 4 + 255) & ~(size_t)255;
constexpr size_t OFF_XSTAT= OFF_HG + (size_t)BB * 64 * 4;         // 2 doubles
constexpr size_t OFF_STY  = OFF_XSTAT + 16;                       // 128 doubles
constexpr size_t OFF_FST  = OFF_STY + 128 * 8;                    // 5 * NSL * 128 floats
constexpr size_t ZERO_END = OFF_FST + 5 * NSL * 128 * 4;
constexpr size_t ZERO_BYTES = ZERO_END - OFF_HG;
// hpart: dedicated (coexists with esd_tmp during the merged binscat|hist launch)
constexpr size_t OFF_HPART= (ZERO_END + 255) & ~(size_t)255;      // int [HBLK][3][NTB] (~8.3 MB)

// ---------------- merged prep: w2prep | otprep | xstats | bptr | bincnt ----------------
__global__ void __launch_bounds__(256) k_prep0(
        const float* __restrict__ w2, const float* __restrict__ b2,
        const float* __restrict__ w1, const float* __restrict__ wo2, const float* __restrict__ w3,
        const float* __restrict__ x, const int* __restrict__ batch, const int* __restrict__ dstv,
        float* __restrict__ w2T, float* __restrict__ b2f,
        float* __restrict__ w1T, float* __restrict__ w2T2, float* __restrict__ w3T,
        double* __restrict__ xstat, int* __restrict__ bptr, int* __restrict__ T) {
    int bx = blockIdx.x, t = threadIdx.x;
    if (bx < 16) {
        int idx = bx * 256 + t;                          // 4096
        int hin = idx >> 6, ho = idx & 63;
        w2T[idx] = w2[ho * 64 + hin];
        if (idx < 64) b2f[idx] = b2[idx];
    } else if (bx < 72) {
        int idx = (bx - 16) * 256 + t;                   // 14336
        if (idx < 8192) {
            int j = idx >> 6, ho = idx & 63;
            w1T[idx] = w1[ho * 128 + j];
        } else if (idx < 8192 + 2048) {
            int q = idx - 8192;
            int j = q >> 5, ho = q & 31;
            w2T2[q] = wo2[ho * 64 + j];
        } else if (idx < 8192 + 2048 + 4096) {
            int q = idx - 8192 - 2048;
            int j = q >> 7, jo = q & 127;
            w3T[q] = w3[jo * 32 + j];
        }
    } else if (bx < 584) {
        __shared__ float ls[256], lq[256];
        float s = 0, q = 0;
        for (int i = (bx - 72) * 256 + t; i < EE; i += 512 * 256) {
            float v = x[i]; s += v; q += v * v;
        }
        ls[t] = s; lq[t] = q; __syncthreads();
        for (int off = 128; off > 0; off >>= 1) {
            if (t < off) { ls[t] += ls[t + off]; lq[t] += lq[t + off]; }
            __syncthreads();
        }
        if (t == 0) { atomicAdd(&xstat[0], (double)ls[0]); atomicAdd(&xstat[1], (double)lq[0]); }
    } else if (bx < 780) {
        int n = (bx - 584) * 256 + t;
        if (n >= NN) return;
        int b = batch[n];
        int pb = (n == 0) ? -1 : batch[n - 1];
        for (int k = pb + 1; k <= b; k++) bptr[k] = n;
        if (n == NN - 1) { for (int k = b + 1; k <= BB; k++) bptr[k] = NN; }
    } else {
        // bincnt: per-block LDS histogram over 391 coarse buckets
        __shared__ int hh[NBKT];
        for (int i = t; i < NBKT; i += 256) hh[i] = 0;
        __syncthreads();
        int bb = bx - 780;
        int e0 = bb * BPB;
        int e1 = e0 + BPB; if (e1 > EE) e1 = EE;
        for (int e = e0 + t; e < e1; e += 256)
            atomicAdd(&hh[dstv[e] >> NPBSH], 1);
        __syncthreads();
        for (int i = t; i < NBKT; i += 256)
            T[(size_t)bb * NBKT + i] = hh[i];
    }
}

// per-bucket exclusive scan over blocks (in-place), bucket totals out
__global__ void k_bscanA(int* __restrict__ T, int* __restrict__ tot) {
    __shared__ int ls[256];
    int b = blockIdx.x, t = threadIdx.x;
    int v = T[(size_t)t * NBKT + b];
    ls[t] = v; __syncthreads();
    for (int off = 1; off < 256; off <<= 1) {
        int a = ls[t]; int add = (t >= off) ? ls[t - off] : 0; __syncthreads();
        ls[t] = a + add; __syncthreads();
    }
    T[(size_t)t * NBKT + b] = ls[t] - v;
    if (t == 255) tot[b] = ls[255];
}

// ---------------- merged: chunked bucket scatter | x histogram ----------------
__global__ void __launch_bounds__(1024) k_binhist(
        const float* __restrict__ x, const int* __restrict__ src,
        const int* __restrict__ dstv, const int* __restrict__ etv,
        const int* __restrict__ T, const int* __restrict__ tot,
        int* __restrict__ bbase_g, int4* __restrict__ esd_tmp, int* __restrict__ hpart) {
    __shared__ int shb[3 * (NTB / 2)];                   // 48 KB, unioned across branches
    int t = threadIdx.x;
    if (blockIdx.x < NB1) {
        int* cur = shb;                                  // [NBKT]
        int* sls = shb + 512;                            // [512] scan buffer
        int v = 0;
        if (t < 512) { v = (t < NBKT) ? tot[t] : 0; sls[t] = v; }
        __syncthreads();
        for (int off = 1; off < 512; off <<= 1) {
            int a = 0;
            if (t < 512) { a = sls[t]; if (t >= off) a += sls[t - off]; }
            __syncthreads();
            if (t < 512) sls[t] = a;
            __syncthreads();
        }
        if (t < NBKT) {
            int base = sls[t] - v;                       // exclusive
            cur[t] = base + T[(size_t)blockIdx.x * NBKT + t];
            if (blockIdx.x == 0) bbase_g[t] = base;
        }
        if (blockIdx.x == 0 && t == 0) bbase_g[NBKT] = EE;
        __syncthreads();
        int e0 = blockIdx.x * BPB;
        int e1 = e0 + BPB; if (e1 > EE) e1 = EE;
        for (int e = e0 + t; e < e1; e += 1024) {
            int d = dstv[e];
            int p = atomicAdd(&cur[d >> NPBSH], 1);
            float tp = fminf(fmaxf((x[e] - XLO) * XSC, 0.f), TPMAX);
            int i = (int)tp; float f = tp - (float)i;
            // local dst (7 bits) rides in spare bits of et (et < 128)
            int4 vv; vv.x = src[e]; vv.y = etv[e] | ((d & 127) << 7); vv.z = i; vv.w = __float_as_int(f);
            esd_tmp[p] = vv;
        }
    } else {
        int* cnt = shb; int* sf = shb + NTB / 2; int* sf2 = shb + NTB;
        int bb = blockIdx.x - NB1;
        int e0 = bb * HEPB;
        int e1 = e0 + HEPB; if (e1 > EE) e1 = EE;
        int* outp = hpart + (size_t)bb * 3 * NTB;
        for (int half = 0; half < 2; half++) {
            for (int i = t; i < NTB / 2; i += 1024) { cnt[i] = 0; sf[i] = 0; sf2[i] = 0; }
            __syncthreads();
            int lo = half * (NTB / 2);
            for (int e = e0 + t; e < e1; e += 1024) {
                float tp = fminf(fmaxf((x[e] - XLO) * XSC, 0.f), TPMAX);
                int i = (int)tp;
                int li = i - lo;
                if ((unsigned)li < (unsigned)(NTB / 2)) {
                    float f = tp - (float)i;
                    atomicAdd(&cnt[li], 1);
                    atomicAdd(&sf[li], (int)(f * FHSC));
                    atomicAdd(&sf2[li], (int)(f * f * FHSC));
                }
            }
            __syncthreads();
            for (int i = t; i < NTB / 2; i += 1024) {
                outp[lo + i] = cnt[i];
                outp[NTB + lo + i] = sf[i];
                outp[2 * NTB + lo + i] = sf2[i];
            }
            __syncthreads();
        }
    }
}

// ---------------- merged: per-bucket local sort | fused knot table + BN2 moments ----------
// blocks [0,NBKT): locsort (emits row_ptr). blocks [NBKT,NBKT+128): ytmom.
__global__ void __launch_bounds__(256) k_locyt(
        const int4* __restrict__ esd_tmp, const int* __restrict__ bbase,
        int* __restrict__ row_ptr, int4* __restrict__ esd,
        const double* __restrict__ xstat, const float* __restrict__ w_d1,
        const float* __restrict__ g_d1, const float* __restrict__ be_d1,
        const float* __restrict__ w2T, const float* __restrict__ b2f,
        const int* __restrict__ hpart, float* __restrict__ ytab, double* __restrict__ sty) {
    __shared__ char shraw[65 * 64 * 4 + 192 * 4];        // 17.4 KB union
    int t = threadIdx.x;
    if (blockIdx.x < NBKT) {
        int* hist = (int*)shraw;
        int* ls   = hist + 128;
        int* cur  = ls + 128;
        int b = blockIdx.x;
        if (b == 0 && t == 0) row_ptr[NN] = EE;
        int base = bbase[b], end = bbase[b + 1];
        if (t < 128) hist[t] = 0;
        __syncthreads();
        for (int p = base + t; p < end; p += 256)
            atomicAdd(&hist[(esd_tmp[p].y >> 7) & 127], 1);
        __syncthreads();
        int v = 0;
        if (t < 128) { v = hist[t]; ls[t] = v; }
        __syncthreads();
        for (int off = 1; off < 128; off <<= 1) {
            int a = 0;
            if (t < 128) { a = ls[t]; if (t >= off) a += ls[t - off]; }
            __syncthreads();
            if (t < 128) ls[t] = a;
            __syncthreads();
        }
        if (t < 128) {
            int exc = ls[t] - v;
            cur[t] = base + exc;
            int n = (b << NPBSH) + t;
            if (n < NN) row_ptr[n] = base + exc;
        }
        __syncthreads();
        for (int p = base + t; p < end; p += 256) {
            int4 r = esd_tmp[p];
            int ld = (r.y >> 7) & 127;
            r.y &= 127;
            esd[atomicAdd(&cur[ld], 1)] = r;
        }
    } else {
        float (*kn)[64] = (float(*)[64])shraw;
        float* hs = (float*)(shraw + 65 * 64 * 4);
        int lane = t & 63, w = t >> 6;
        int g = blockIdx.x - NBKT;                       // 0..127
        double inv = 1.0 / (double)EE;
        double mx = xstat[0] * inv;
        double vx = xstat[1] * inv - mx * mx; if (vx < 0) vx = 0;
        float wd = w_d1[lane];
        float Aw = wd * rsqrtf((float)vx * wd * wd + BN_EPS) * g_d1[lane];
        float Cw = be_d1[lane];
        for (int kk = w; kk < 65; kk += 4) {
            int idx = (g << 6) + kk;
            float xi = XLO + (float)idx * DXT;
            float tt = xi - (float)mx;
            float d1L = sp(fmaf(Aw, tt, Cw));
            float y = b2f[lane];
            #pragma unroll
            for (int hin = 0; hin < 64; hin++)
                y = fmaf(rl(d1L, hin), w2T[hin * 64 + lane], y);
            kn[kk][lane] = y;
            if (kk < 64 || g == 127) ytab[(idx << 6) | lane] = y;
        }
        if (t < 192) {                                   // hsum: c|f1|f2 for this block's 64 bins
            int slot = t >> 6, ii = t & 63;
            float s = 0.f;
            size_t off = (size_t)slot * NTB + (g << 6) + ii;
            for (int b = 0; b < HBLK; b++)
                s += (float)hpart[(size_t)b * 3 * NTB + off];
            hs[t] = (slot == 0) ? s : s * FHIN;
        }
        __syncthreads();
        if (t >= 64) return;                             // one wave: moment math
        double S = 0.0, Q = 0.0;
        float aprev = kn[0][lane];
        for (int ii = 0; ii < 64; ii++) {
            float c = hs[ii], f1 = hs[64 + ii], f2 = hs[128 + ii];
            float b = kn[ii + 1][lane];
            float a = aprev; aprev = b;
            float d = b - a;
            S += (double)(fmaf(c, a, d * f1));
            Q += (double)(fmaf(c * a, a, fmaf(2.f * a * d, f1, d * d * f2)));
        }
        atomicAdd(&sty[lane], S);
        atomicAdd(&sty[64 + lane], Q);
    }
}

// pack bn2-affined table as bf16 (a, b-a) pairs, pre-scaled by LOG2E (log2-domain agg)
__global__ void k_ypack(const float* __restrict__ ytab, const double* __restrict__ sty,
                        const float* __restrict__ g2, const float* __restrict__ be2,
                        u32* __restrict__ ptab) {
    int tid = blockIdx.x * 256 + threadIdx.x;            // NTB*64
    int f = tid & 63;
    double inv = 1.0 / (double)EE;
    double m = sty[f] * inv;
    double var = sty[64 + f] * inv - m * m; if (var < 0) var = 0;
    float rstd = rsqrtf((float)var + BN_EPS);
    float sc0 = rstd * g2[f];
    float sc = sc0 * LOG2E;
    float sh = (be2[f] - (float)m * sc0) * LOG2E;
    float a = fmaf(ytab[tid], sc, sh);
    float b = fmaf(ytab[tid + 64], sc, sh);
    ptab[tid] = pk2(a, b - a);
}

// per-edge term (log2-scaled): one fmaf lerp + emb mul
__device__ __forceinline__ float edge_term(int4 ed, int lane, const u32* __restrict__ ptab,
                                           const float* __restrict__ emb) {
    u32 pr = ptab[(ed.z << 6) | lane];
    float f = __int_as_float(ed.w);
    float a = __uint_as_float(pr << 16);
    float d = __uint_as_float(pr & 0xffff0000u);
    float y = fmaf(f, d, a);
    return y * emb[(ed.y << 6) | lane];
}
// log2-domain softplus accumulate
__device__ __forceinline__ void sp2(float hv, float av, float& accm, float& accl) {
    float z = fmaf(hv, LOG2E, av);
    float t = __builtin_amdgcn_exp2f(-fabsf(z));
    accm += fmaxf(z, 0.f);
    accl += __builtin_amdgcn_logf(1.f + t);
}

// wave-per-node aggregation; 128-thr blocks (2 nodes); NO epilogue/syncthreads
// (R10/R11's fused-stats epilogue regressed this kernel 63 -> 107 us; reverted)
__global__ void __launch_bounds__(128) k_agg(
        const float* __restrict__ h, const int4* __restrict__ esd, const int* __restrict__ row_ptr,
        const u32* __restrict__ ptab, const float* __restrict__ emb, float* __restrict__ hpre) {
    int lane = threadIdx.x & 63;
    int n = __builtin_amdgcn_readfirstlane((int)((blockIdx.x << 1) | (threadIdx.x >> 6)));
    int p0 = row_ptr[n], p1 = row_ptr[n + 1];
    float accm = 0.f, accl = 0.f;
    int p = p0;
    for (; p + 4 <= p1; p += 4) {
        int4 e0 = esd[p], e1 = esd[p + 1], e2 = esd[p + 2], e3 = esd[p + 3];
        float h0 = h[(e0.x << 6) | lane];
        float h1 = h[(e1.x << 6) | lane];
        float h2 = h[(e2.x << 6) | lane];
        float h3 = h[(e3.x << 6) | lane];
        float a0 = edge_term(e0, lane, ptab, emb);
        float a1 = edge_term(e1, lane, ptab, emb);
        float a2 = edge_term(e2, lane, ptab, emb);
        float a3 = edge_term(e3, lane, ptab, emb);
        sp2(h0, a0, accm, accl);
        sp2(h1, a1, accm, accl);
        sp2(h2, a2, accm, accl);
        sp2(h3, a3, accm, accl);
    }
    for (; p < p1; ++p) {
        int4 e0 = esd[p];
        float h0 = h[(e0.x << 6) | lane];
        sp2(h0, edge_term(e0, lane, ptab, emb), accm, accl);
    }
    int o = (n << 6) | lane;
    hpre[o] = fmaf(accm + accl, LN2, h[o]);
}

// gconv1 variant: h comes from node_emb[node_type] (L1-resident)
__global__ void __launch_bounds__(128) k_agg0(
        const int* __restrict__ nt, const float* __restrict__ nemb, const int4* __restrict__ esd,
        const int* __restrict__ row_ptr, const u32* __restrict__ ptab,
        const float* __restrict__ emb, float* __restrict__ hpre) {
    int lane = threadIdx.x & 63;
    int n = __builtin_amdgcn_readfirstlane((int)((blockIdx.x << 1) | (threadIdx.x >> 6)));
    int p0 = row_ptr[n], p1 = row_ptr[n + 1];
    float accm = 0.f, accl = 0.f;
    int p = p0;
    for (; p + 4 <= p1; p += 4) {
        int4 e0 = esd[p], e1 = esd[p + 1], e2 = esd[p + 2], e3 = esd[p + 3];
        float h0 = nemb[(nt[e0.x] << 6) | lane];
        float h1 = nemb[(nt[e1.x] << 6) | lane];
        float h2 = nemb[(nt[e2.x] << 6) | lane];
        float h3 = nemb[(nt[e3.x] << 6) | lane];
        float a0 = edge_term(e0, lane, ptab, emb);
        float a1 = edge_term(e1, lane, ptab, emb);
        float a2 = edge_term(e2, lane, ptab, emb);
        float a3 = edge_term(e3, lane, ptab, emb);
        sp2(h0, a0, accm, accl);
        sp2(h1, a1, accm, accl);
        sp2(h2, a2, accm, accl);
        sp2(h3, a3, accm, accl);
    }
    for (; p < p1; ++p) {
        int4 e0 = esd[p];
        float h0 = nemb[(nt[e0.x] << 6) | lane];
        sp2(h0, edge_term(e0, lane, ptab, emb), accm, accl);
    }
    hpre[(n << 6) | lane] = fmaf(accm + accl, LN2, nemb[(nt[n] << 6) | lane]);
}

// per-feature mean/var partials over [rows, 64]; f32 NSL-slot output (native atomics)
__global__ void __launch_bounds__(256) k_fstats(
        const float* __restrict__ v, int rows, float* __restrict__ stat) {
    int f = threadIdx.x & 63;
    int r0 = threadIdx.x >> 6;                           // 4 rows per block stride
    float s = 0.f, q = 0.f;
    for (int r = blockIdx.x * 4 + r0; r < rows; r += gridDim.x * 4) {
        float val = v[(size_t)r * 64 + f];
        s += val; q += val * val;
    }
    __shared__ float lsS[4][64], lsQ[4][64];
    lsS[r0][f] = s; lsQ[r0][f] = q; __syncthreads();
    if (threadIdx.x < 128) {
        int ff = threadIdx.x & 63; bool isq = threadIdx.x >= 64;
        float r = 0.f;
        #pragma unroll
        for (int j = 0; j < 4; j++) r += isq ? lsQ[j][ff] : lsS[j][ff];
        int sl = ((int)blockIdx.x & (NSL - 1)) << 7;
        unsafeAtomicAdd(&stat[sl + (isq ? 64 : 0) + ff], r);
    }
}

// BN apply: preamble reduces the NSL spread slots; per-block f32 scale/shift hoist
__global__ void __launch_bounds__(256) k_bn(
        const float* __restrict__ in, float* __restrict__ out,
        const float* __restrict__ stat, const float* __restrict__ g,
        const float* __restrict__ be, int rows, int logC, int act) {
    int C = 1 << logC;
    __shared__ float scl[64], shl[64];
    int t = threadIdx.x;
    if (t < C) {
        float s = 0.f, q = 0.f;
        #pragma unroll
        for (int sl = 0; sl < NSL; sl++) {
            s += stat[(sl << 7) + t];
            q += stat[(sl << 7) + 64 + t];
        }
        float inv = 1.f / (float)rows;
        float m = s * inv;
        float var = q * inv - m * m; if (var < 0.f) var = 0.f;
        float rstd = rsqrtf(var + BN_EPS);
        float sc = rstd * g[t];
        scl[t] = sc; shl[t] = be[t] - m * sc;
    }
    __syncthreads();
    size_t total = (size_t)rows << logC;
    size_t i = (size_t)blockIdx.x * 256 + t;
    if (i >= total) return;
    int f = (int)(i & (C - 1));
    float val = fmaf(in[i], scl[f], shl[f]);
    out[i] = act ? sp(val) : val;
}

// global pooling: block-per-batch segment sum over sorted batch (no atomics)
__global__ void __launch_bounds__(256) k_hg2(
        const float* __restrict__ h, const int* __restrict__ bptr, float* __restrict__ hg) {
    int b = blockIdx.x;                                  // BB
    int lane = threadIdx.x & 63, w = threadIdx.x >> 6;
    int n0 = bptr[b], n1 = bptr[b + 1];
    float acc = 0.f;
    for (int n = n0 + w; n < n1; n += 4)
        acc += h[(n << 6) | lane];
    __shared__ float ls[256];
    ls[threadIdx.x] = acc; __syncthreads();
    if (threadIdx.x < 64)
        hg[(b << 6) | lane] = ls[lane] + ls[64 + lane] + ls[128 + lane] + ls[192 + lane];
}

// head GEMV 1: 4 nodes/wave; fused stats (native f32 atomics)
#define O1NPW 4
__global__ void __launch_bounds__(256) k_o1(
        const float* __restrict__ h, const float* __restrict__ hg, const int* __restrict__ batch,
        const float* __restrict__ w1T, const float* __restrict__ b1, float* __restrict__ z1,
        float* __restrict__ stat) {
    int lane = threadIdx.x & 63;
    int wv = (blockIdx.x * 256 + (int)threadIdx.x) >> 6;
    int n0 = __builtin_amdgcn_readfirstlane(wv * O1NPW);  // grid exact: 3125*4 waves = 50000 nodes
    float hl[O1NPW], gl[O1NPW], acc[O1NPW];
    float bl = b1[lane];
    #pragma unroll
    for (int k = 0; k < O1NPW; k++) {
        int n = n0 + k;
        hl[k] = h[(n << 6) | lane];
        gl[k] = hg[(batch[n] << 6) | lane];
        acc[k] = bl;
    }
    #pragma unroll
    for (int j = 0; j < 64; j++) {
        float w = w1T[(j << 6) | lane];
        #pragma unroll
        for (int k = 0; k < O1NPW; k++)
            acc[k] = fmaf(rl(hl[k], j), w, acc[k]);
    }
    #pragma unroll
    for (int j = 0; j < 64; j++) {
        float w = w1T[((64 + j) << 6) | lane];
        #pragma unroll
        for (int k = 0; k < O1NPW; k++)
            acc[k] = fmaf(rl(gl[k], j), w, acc[k]);
    }
    float s = 0.f, q = 0.f;
    #pragma unroll
    for (int k = 0; k < O1NPW; k++) {
        z1[((n0 + k) << 6) | lane] = acc[k];
        s += acc[k]; q += acc[k] * acc[k];
    }
    __shared__ float lsS[4][64], lsQ[4][64];
    int w = threadIdx.x >> 6;
    lsS[w][lane] = s; lsQ[w][lane] = q; __syncthreads();
    if (threadIdx.x < 128) {
        int f = threadIdx.x & 63; bool isq = threadIdx.x >= 64;
        float r = 0.f;
        #pragma unroll
        for (int j = 0; j < 4; j++) r += isq ? lsQ[j][f] : lsS[j][f];
        int sl = ((int)blockIdx.x & (NSL - 1)) << 7;
        unsafeAtomicAdd(&stat[sl + (isq ? 64 : 0) + f], r);
    }
}

// head GEMV 2: 8 nodes/wave; fused stats (C=32: s at [f], q at [64+f])
__global__ void __launch_bounds__(256) k_o2(
        const float* __restrict__ o1v, const float* __restrict__ w2T2,
        const float* __restrict__ b2, float* __restrict__ z2, float* __restrict__ stat) {
    int lane = threadIdx.x & 63;
    int ho = lane & 31;
    int wv = (blockIdx.x * 256 + (int)threadIdx.x) >> 6;
    int n0 = __builtin_amdgcn_readfirstlane(wv * 8);
    float xr[8], acc[4];
    #pragma unroll
    for (int k = 0; k < 8; k++) {
        int n = n0 + k; if (n >= NN) n = NN - 1;
        xr[k] = o1v[(n << 6) | lane];
    }
    float bl = b2[ho];
    #pragma unroll
    for (int k = 0; k < 4; k++) acc[k] = bl;
    #pragma unroll
    for (int j = 0; j < 64; j++) {
        float w = w2T2[(j << 5) | ho];
        #pragma unroll
        for (int k = 0; k < 4; k++) {
            float slo = rl(xr[k], j);
            float shi = rl(xr[4 + k], j);
            float v = (lane < 32) ? slo : shi;
            acc[k] = fmaf(v, w, acc[k]);
        }
    }
    int nbase = n0 + ((lane >> 5) << 2);
    float s = 0.f, q = 0.f;
    #pragma unroll
    for (int k = 0; k < 4; k++) {
        if (nbase + k < NN) {
            z2[((nbase + k) << 5) | ho] = acc[k];
            s += acc[k]; q += acc[k] * acc[k];
        }
    }
    __shared__ float lsS[4][64], lsQ[4][64];
    int w = threadIdx.x >> 6;
    lsS[w][lane] = s; lsQ[w][lane] = q; __syncthreads();
    if (threadIdx.x < 64) {
        int f = threadIdx.x & 31; bool isq = threadIdx.x >= 32;
        float r = 0.f;
        #pragma unroll
        for (int j = 0; j < 4; j++)
            r += isq ? (lsQ[j][f] + lsQ[j][32 + f]) : (lsS[j][f] + lsS[j][32 + f]);
        int sl = ((int)blockIdx.x & (NSL - 1)) << 7;
        unsafeAtomicAdd(&stat[sl + (isq ? 64 : 0) + f], r);
    }
}

// head GEMV 3: 4 nodes per wave per jo-half
__global__ void __launch_bounds__(256) k_o3(
        const float* __restrict__ o2v, const float* __restrict__ w3T,
        const float* __restrict__ b3, float* __restrict__ outp) {
    int lane = threadIdx.x & 63;
    int wv = (blockIdx.x * 256 + (int)threadIdx.x) >> 6;
    int n0 = __builtin_amdgcn_readfirstlane((wv >> 1) << 2);
    int jo = (((wv & 1) << 6) + lane);
    if (n0 >= NN) return;
    float zl[4], acc[4];
    float bl = b3[jo];
    #pragma unroll
    for (int k = 0; k < 4; k++) {
        zl[k] = o2v[((n0 + k) << 5) | (lane & 31)];
        acc[k] = bl;
    }
    #pragma unroll
    for (int j = 0; j < 32; j++) {
        float w = w3T[(j << 7) | jo];
        #pragma unroll
        for (int k = 0; k < 4; k++)
            acc[k] = fmaf(rl(zl[k], j), w, acc[k]);
    }
    #pragma unroll
    for (int k = 0; k < 4; k++) {
        int n = n0 + k;
        size_t dsti = (jo < 64) ? ((size_t)(n << 6) + jo)
                                : ((size_t)NN * 64 + (size_t)(n << 6) + (jo - 64));
        outp[dsti] = acc[k];                             // f32 output
    }
}

extern "C" void kernel_launch(void* const* d_in, const int* in_sizes, int n_in,
                              void* d_out, int out_size, void* d_ws, size_t ws_size,
                              hipStream_t stream) {
    const float* x        = (const float*)d_in[0];
    const int* node_type  = (const int*)d_in[1];
    const int* edge_type  = (const int*)d_in[2];
    const int* edge_index = (const int*)d_in[3];
    const int* batch      = (const int*)d_in[4];
    const float* node_emb = (const float*)d_in[5];
    const float* edge_emb = (const float*)d_in[6];
    const float* w_d1 = (const float*)d_in[7];  const float* b_d1 = (const float*)d_in[8];
    const float* g_d1 = (const float*)d_in[9];  const float* be_d1 = (const float*)d_in[10];
    const float* w_d2 = (const float*)d_in[11]; const float* b_d2 = (const float*)d_in[12];
    const float* g_d2 = (const float*)d_in[13]; const float* be_d2 = (const float*)d_in[14];
    const float* g_c1 = (const float*)d_in[15]; const float* be_c1 = (const float*)d_in[16];
    const float* g_c2 = (const float*)d_in[17]; const float* be_c2 = (const float*)d_in[18];
    const float* g_c3 = (const float*)d_in[19]; const float* be_c3 = (const float*)d_in[20];
    const float* w_o1 = (const float*)d_in[21]; const float* b_o1 = (const float*)d_in[22];
    const float* g_o1 = (const float*)d_in[23]; const float* be_o1 = (const float*)d_in[24];
    const float* w_o2 = (const float*)d_in[25]; const float* b_o2 = (const float*)d_in[26];
    const float* g_o2 = (const float*)d_in[27]; const float* be_o2 = (const float*)d_in[28];
    const float* w_o3 = (const float*)d_in[29]; const float* b_o3 = (const float*)d_in[30];
    (void)b_d1;  // cancels inside BN1 (mean subtraction removes per-feature shift)
    const int* src  = edge_index;
    const int* dstv = edge_index + EE;

    char* ws = (char*)d_ws;
    int4*  esd     = (int4*)(ws + OFF_ESD);
    int*   row_ptr = (int*)(ws + OFF_ROWP);
    float* hA   = (float*)(ws + OFF_HA);
    float* hB   = (float*)(ws + OFF_HB);
    float* zb   = (float*)(ws + OFF_ZB);
    int4*  esd_tmp = (int4*)(ws + OFF_HA);   // aliases hA..hB (live only before k_locyt done)
    int*   hpart = (int*)(ws + OFF_HPART);   // dedicated (coexists with esd_tmp)
    int*   T    = (int*)(ws + OFF_TMAT);     // aliases zb (live only before k_binhist done)
    int*   tot  = (int*)(ws + OFF_TOT);
    int*   bbase= (int*)(ws + OFF_BBASE);
    float* ytab = (float*)(ws + OFF_YTAB);
    u32*   ptab = (u32*)(ws + OFF_PTAB);
    float* w2T  = (float*)(ws + OFF_W2T);
    float* b2f  = (float*)(ws + OFF_B2F);
    float* w1T  = (float*)(ws + OFF_W1T);
    float* w2T2 = (float*)(ws + OFF_W2O);
    float* w3T  = (float*)(ws + OFF_W3T);
    int*   bptr = (int*)(ws + OFF_BPTR);
    float* hg     = (float*)(ws + OFF_HG);
    double* xstat = (double*)(ws + OFF_XSTAT);
    double* sty   = (double*)(ws + OFF_STY);
    float* fst    = (float*)(ws + OFF_FST);
    float* st0 = fst;               float* st1 = fst + NSL * 128;
    float* st2 = fst + 2 * NSL * 128;
    float* st3 = fst + 3 * NSL * 128;
    float* st4 = fst + 4 * NSL * 128;

    hipMemsetAsync(ws + OFF_HG, 0, ZERO_BYTES, stream);

    // merged prep: weights transpose | xstats | bptr | bincnt
    k_prep0<<<1036, 256, 0, stream>>>(w_d2, b_d2, w_o1, w_o2, w_o3, x, batch, dstv,
                                      w2T, b2f, w1T, w2T2, w3T, xstat, bptr, T);
    k_bscanA<<<NBKT, 256, 0, stream>>>(T, tot);
    // merged: bucket scatter (with in-LDS bbase scan) | x histogram (concurrent)
    k_binhist<<<NB1 + HBLK, 1024, 0, stream>>>(x, src, dstv, edge_type, T, tot,
                                               bbase, esd_tmp, hpart);
    // merged: per-bucket local sort (emits row_ptr) | knot table + BN2 moments
    k_locyt<<<NBKT + 128, 256, 0, stream>>>(esd_tmp, bbase, row_ptr, esd,
                                            xstat, w_d1, g_d1, be_d1, w2T, b2f,
                                            hpart, ytab, sty);
    k_ypack<<<NTB * 64 / 256, 256, 0, stream>>>(ytab, sty, g_d2, be_d2, ptab);
    // gconv 1 (h from node_emb[node_type], L1-resident)
    k_agg0<<<25000, 128, 0, stream>>>(node_type, node_emb, esd, row_ptr, ptab, edge_emb, hB);
    k_fstats<<<1024, 256, 0, stream>>>(hB, NN, st0);
    k_bn<<<12500, 256, 0, stream>>>(hB, hB, st0, g_c1, be_c1, NN, 6, 1);
    // gconv 2
    k_agg<<<25000, 128, 0, stream>>>(hB, esd, row_ptr, ptab, edge_emb, hA);
    k_fstats<<<1024, 256, 0, stream>>>(hA, NN, st1);
    k_bn<<<12500, 256, 0, stream>>>(hA, hA, st1, g_c2, be_c2, NN, 6, 1);
    // gconv 3 (no activation)
    k_agg<<<25000, 128, 0, stream>>>(hA, esd, row_ptr, ptab, edge_emb, hB);
    k_fstats<<<1024, 256, 0, stream>>>(hB, NN, st2);
    k_bn<<<12500, 256, 0, stream>>>(hB, hB, st2, g_c3, be_c3, NN, 6, 0);
    // global pool + head (stats fused into o1/o2)
    k_hg2<<<BB, 256, 0, stream>>>(hB, bptr, hg);
    k_o1<<<3125, 256, 0, stream>>>(hB, hg, batch, w1T, b_o1, hA, st3);
    k_bn<<<12500, 256, 0, stream>>>(hA, hA, st3, g_o1, be_o1, NN, 6, 1);
    k_o2<<<1563, 256, 0, stream>>>(hA, w2T2, b_o2, zb, st4);
    k_bn<<<6250, 256, 0, stream>>>(zb, zb, st4, g_o2, be_o2, NN, 5, 1);
    k_o3<<<6250, 256, 0, stream>>>(zb, w3T, b_o3, (float*)d_out);
    (void)in_sizes; (void)n_in; (void)out_size; (void)ws_size;
}